// Round 3
// baseline (6112.170 us; speedup 1.0000x reference)
//
#include <hip/hip_runtime.h>
#include <hip/hip_bf16.h>

// ---------- types / helpers ----------
typedef __bf16 bf16x8 __attribute__((ext_vector_type(8)));
typedef float  f32x4  __attribute__((ext_vector_type(4)));

__device__ __forceinline__ unsigned short f2b(float f) {
    union { float f; unsigned u; } w; w.f = f;
    unsigned u = w.u + 0x7FFF + ((w.u >> 16) & 1);
    return (unsigned short)(u >> 16);
}
__device__ __forceinline__ float b2f(unsigned short s) {
    union { unsigned u; float f; } w; w.u = ((unsigned)s) << 16; return w.f;
}
__device__ __forceinline__ float tanhfast(float x) {
    float e = __expf(2.0f * x);
    return 1.0f - 2.0f / (e + 1.0f);
}

// coherent (cross-XCD) accesses for small mutable state: sc0/sc1 path to L3,
// no cache invalidation anywhere -> weights stay L2-resident across steps.
__device__ __forceinline__ unsigned ldU(const unsigned* p) {
    return __hip_atomic_load((unsigned*)p, __ATOMIC_RELAXED, __HIP_MEMORY_SCOPE_SYSTEM);
}
__device__ __forceinline__ float ldF(const float* p) {
    return __hip_atomic_load((float*)p, __ATOMIC_RELAXED, __HIP_MEMORY_SCOPE_SYSTEM);
}
__device__ __forceinline__ void stU(unsigned* p, unsigned v) {
    __hip_atomic_store(p, v, __ATOMIC_RELAXED, __HIP_MEMORY_SCOPE_SYSTEM);
}
__device__ __forceinline__ void stF(float* p, float v) {
    __hip_atomic_store(p, v, __ATOMIC_RELAXED, __HIP_MEMORY_SCOPE_SYSTEM);
}
__device__ __forceinline__ bf16x8 ldA8(const unsigned short* p) {
    union { unsigned u[4]; bf16x8 v; } r;
#pragma unroll
    for (int i = 0; i < 4; ++i) r.u[i] = ldU((const unsigned*)p + i);
    return r.v;
}

#define GLD16(g, l) __builtin_amdgcn_global_load_lds( \
    (const __attribute__((address_space(1))) void*)(g), \
    (__attribute__((address_space(3))) void*)(l), 16, 0, 0)

#define NBLK 64

// fence-free grid barrier: per-wave vmcnt drain happens at __syncthreads;
// arrival/poll are relaxed system atomics (serialized at L3) -> no buffer_inv.
__device__ __forceinline__ void gbar(int* cnt, int* gen, int target) {
    asm volatile("s_waitcnt vmcnt(0)" ::: "memory");
    __syncthreads();
    if (threadIdx.x == 0) {
        int v = __hip_atomic_fetch_add(cnt, 1, __ATOMIC_RELAXED, __HIP_MEMORY_SCOPE_SYSTEM);
        if (v == NBLK - 1) {
            __hip_atomic_store(cnt, 0, __ATOMIC_RELAXED, __HIP_MEMORY_SCOPE_SYSTEM);
            asm volatile("s_waitcnt vmcnt(0)" ::: "memory");
            __hip_atomic_store(gen, target, __ATOMIC_RELAXED, __HIP_MEMORY_SCOPE_SYSTEM);
        } else {
            while (__hip_atomic_load(gen, __ATOMIC_RELAXED, __HIP_MEMORY_SCOPE_SYSTEM) < target)
                __builtin_amdgcn_s_sleep(2);
        }
    }
    __syncthreads();
}

// ---------- elementwise / conversion kernels ----------

__global__ void k_gather(const float* __restrict__ emb, const int* __restrict__ tok,
                         unsigned short* __restrict__ out, int L, int ldtok) {
    long total = (long)L * 64 * 128;
    for (long i = (long)blockIdx.x * blockDim.x + threadIdx.x; i < total;
         i += (long)gridDim.x * blockDim.x) {
        int  e4 = (int)(i & 127);
        long r  = i >> 7;
        int  t  = (int)(r >> 6), b = (int)(r & 63);
        int  tk = tok[b * ldtok + t];
        float4 v = *(const float4*)(emb + (long)tk * 512 + e4 * 4);
        ushort4 o; o.x = f2b(v.x); o.y = f2b(v.y); o.z = f2b(v.z); o.w = f2b(v.w);
        *(ushort4*)(out + r * 512 + e4 * 4) = o;
    }
}

__global__ void k_conv(const float* __restrict__ in, unsigned short* __restrict__ out,
                       long N_, int K_, int ldin, int col0, int ldout, int outcol0, int reorder) {
    long total = N_ * (K_ >> 2);
    int kq = K_ >> 2;
    for (long i = (long)blockIdx.x * blockDim.x + threadIdx.x; i < total;
         i += (long)gridDim.x * blockDim.x) {
        long n = i / kq;
        int  k4 = (int)(i - n * kq) * 4;
        long row = reorder ? (long)((n & 3) * 1024 + (n >> 2)) : n;
        float4 v = *(const float4*)(in + row * ldin + col0 + k4);
        ushort4 o; o.x = f2b(v.x); o.y = f2b(v.y); o.z = f2b(v.z); o.w = f2b(v.w);
        *(ushort4*)(out + n * ldout + outcol0 + k4) = o;
    }
}

__global__ void k_bias(const float* __restrict__ b1, const float* __restrict__ b2,
                       float* __restrict__ out) {
    int n = blockIdx.x * blockDim.x + threadIdx.x;
    if (n < 4096) {
        int row = (n & 3) * 1024 + (n >> 2);
        out[n] = b1[row] + b2[row];
    }
}

__global__ void k_zero0(float* __restrict__ out) {
    long total = 64L * 8000;
    for (long i = (long)blockIdx.x * blockDim.x + threadIdx.x; i < total;
         i += (long)gridDim.x * blockDim.x) {
        int b = (int)(i / 8000), q = (int)(i % 8000);
        float4 z = {0.f, 0.f, 0.f, 0.f};
        *(float4*)(out + (long)b * 1024000 + q * 4) = z;
    }
}

// ---------- big-GEMM core (prep + fc) ----------
template<int BM, int BN, int WGM, int WGN, int FM, int FN>
__device__ __forceinline__ void gemm_core(
    const unsigned short* __restrict__ A, int lda,
    const unsigned short* __restrict__ B, int ldb,
    long m0, long n0, int K,
    unsigned short* As, unsigned short* Bs,
    f32x4 (&acc)[FM][FN])
{
    const int tid  = threadIdx.x;
    const int lane = tid & 63;
    const int wave = tid >> 6;
    const int wm = wave / WGN;
    const int wn = wave % WGN;
    const int srow = lane >> 2;
    const int scol = (lane & 3) * 8;
    const int frow = lane & 15;
    const int fcol = (lane >> 4) * 8;

    for (int k0 = 0; k0 < K; k0 += 32) {
        __syncthreads();
        for (int c = wave; c < BM / 16; c += 4) {
            const unsigned short* g = A + (m0 + c * 16 + srow) * (long)lda + k0 + scol;
            GLD16(g, As + c * 512);
        }
        for (int c = wave; c < BN / 16; c += 4) {
            const unsigned short* g = B + (n0 + c * 16 + srow) * (long)ldb + k0 + scol;
            GLD16(g, Bs + c * 512);
        }
        __syncthreads();
        bf16x8 af[FM], bfr[FN];
#pragma unroll
        for (int m = 0; m < FM; ++m)
            af[m] = *(const bf16x8*)(As + ((wm * FM + m) * 16 + frow) * 32 + fcol);
#pragma unroll
        for (int n = 0; n < FN; ++n)
            bfr[n] = *(const bf16x8*)(Bs + ((wn * FN + n) * 16 + frow) * 32 + fcol);
#pragma unroll
        for (int m = 0; m < FM; ++m)
#pragma unroll
            for (int n = 0; n < FN; ++n)
                acc[m][n] = __builtin_amdgcn_mfma_f32_16x16x32_bf16(af[m], bfr[n], acc[m][n], 0, 0, 0);
    }
}

template<int BM, int BN, int WGM, int WGN, int FM, int FN, int MODE>
__global__ __launch_bounds__(256) void k_gemm(
    const unsigned short* __restrict__ A, int lda,
    const unsigned short* __restrict__ B, int ldb,
    float* __restrict__ C, long ldc, const float* __restrict__ bias,
    int M, int N, int K, int Mreal)
{
    __shared__ __align__(16) unsigned short As[BM * 32];
    __shared__ __align__(16) unsigned short Bs[BN * 32];
    long m0 = (long)blockIdx.y * BM;
    long n0 = (long)blockIdx.x * BN;
    f32x4 acc[FM][FN] = {};
    gemm_core<BM, BN, WGM, WGN, FM, FN>(A, lda, B, ldb, m0, n0, K, As, Bs, acc);

    const int lane = threadIdx.x & 63;
    const int wave = threadIdx.x >> 6;
    const int wm = wave / WGN, wn = wave % WGN;
#pragma unroll
    for (int n = 0; n < FN; ++n) {
        long col = n0 + wn * FN * 16 + n * 16 + (lane & 15);
        float bv = bias ? bias[col] : 0.0f;
#pragma unroll
        for (int m = 0; m < FM; ++m) {
            int rl = wm * FM * 16 + m * 16 + (lane >> 4) * 4;
#pragma unroll
            for (int q = 0; q < 4; ++q) {
                long r = m0 + rl + q;
                float val = acc[m][n][q] + bv;
                if (MODE == 0) {
                    C[r * ldc + col] = val;
                } else {
                    if (r < Mreal) {
                        long orow = (r & 63) * 32 + (r >> 6) + 1;
                        C[orow * ldc + col] = val;
                    }
                }
            }
        }
    }
}

// ---------- streamed recurrent GEMM: frags straight from global, no LDS ----------
// A-frags via coherent loads (mutable h/ctx), B-frags via normal loads (L2-warm
// weights). Chunk-8 double-buffered A prefetch (~32 loads in flight).
template<int NB, int NK>
__device__ __forceinline__ void sgemm(const unsigned short* Arow,
                                      const unsigned short* const (&Bb)[NB],
                                      f32x4 (&acc)[NB])
{
    bf16x8 aX[8], aY[8];
#pragma unroll
    for (int kk = 0; kk < 8; ++kk) aX[kk] = ldA8(Arow + kk * 32);
#pragma unroll
    for (int c = 0; c < NK / 8; c += 2) {
#pragma unroll
        for (int kk = 0; kk < 8; ++kk) aY[kk] = ldA8(Arow + ((c + 1) * 8 + kk) * 32);
#pragma unroll
        for (int kk = 0; kk < 8; ++kk) {
            const int k0 = (c * 8 + kk) * 32;
#pragma unroll
            for (int nt = 0; nt < NB; ++nt)
                acc[nt] = __builtin_amdgcn_mfma_f32_16x16x32_bf16(
                    aX[kk], *(const bf16x8*)(Bb[nt] + k0), acc[nt], 0, 0, 0);
        }
        if (c + 2 < NK / 8) {
#pragma unroll
            for (int kk = 0; kk < 8; ++kk) aX[kk] = ldA8(Arow + ((c + 2) * 8 + kk) * 32);
        }
#pragma unroll
        for (int kk = 0; kk < 8; ++kk) {
            const int k0 = ((c + 1) * 8 + kk) * 32;
#pragma unroll
            for (int nt = 0; nt < NB; ++nt)
                acc[nt] = __builtin_amdgcn_mfma_f32_16x16x32_bf16(
                    aY[kk], *(const bf16x8*)(Bb[nt] + k0), acc[nt], 0, 0, 0);
        }
    }
}

// ---------- persistent encoder: 64 LSTM steps, 1 barrier each ----------
__global__ __launch_bounds__(256, 1) void k_enc(
    const unsigned short* __restrict__ W,    // weWhh 4096x1024 gate-interleaved
    const float* __restrict__ pre,           // [64][64][4096]
    unsigned short* __restrict__ h0,         // ping (zeroed)
    unsigned short* __restrict__ h1,         // pong
    unsigned short* __restrict__ enc_out,    // [b*64+t][1024]
    unsigned short* __restrict__ eoT,        // [b][h][t]
    unsigned short* __restrict__ hf,         // dcat0 h-half, stride 2048
    float* __restrict__ cspill,
    int* cnt, int* gen)
{
    __shared__ float gs[64 * 64];
    __shared__ float cs[64 * 16];
    const int blk = blockIdx.x, tid = threadIdx.x;
    const int lane = tid & 63, wave = tid >> 6;
    const int n0 = blk * 64, j0 = blk * 16;
    const int bcol = lane & 15, kch = (lane >> 4) * 8;
    const int arow = wave * 16 + bcol;
    for (int i = tid; i < 1024; i += 256) cs[i] = 0.f;
    const unsigned short* Bb[4];
#pragma unroll
    for (int nt = 0; nt < 4; ++nt) Bb[nt] = W + (long)(n0 + nt * 16 + bcol) * 1024 + kch;
    __syncthreads();
    int bt = 0;
    for (int t = 0; t < 64; ++t) {
        const unsigned short* A = ((t & 1) ? h1 : h0) + (long)arow * 1024 + kch;
        unsigned short* hw = (t & 1) ? h0 : h1;
        f32x4 acc[4] = {};
        sgemm<4, 32>(A, Bb, acc);
#pragma unroll
        for (int nt = 0; nt < 4; ++nt)
#pragma unroll
            for (int q = 0; q < 4; ++q)
                gs[(wave * 16 + (lane >> 4) * 4 + q) * 64 + nt * 16 + bcol] = acc[nt][q];
        __syncthreads();
        const float* pt = pre + (long)t * 64 * 4096;
#pragma unroll
        for (int i = 0; i < 2; ++i) {
            int p = tid + i * 256;           // 0..511 = 64 b x 8 j-pairs
            int b = p >> 3, jl = (p & 7) * 2;
            float4 gA = *(const float4*)(gs + b * 64 + jl * 4);
            float4 gB = *(const float4*)(gs + b * 64 + jl * 4 + 4);
            const float* prr = pt + (long)b * 4096 + n0 + jl * 4;
            float4 pA = *(const float4*)(prr);
            float4 pB = *(const float4*)(prr + 4);
            float c0 = cs[b * 16 + jl], c1 = cs[b * 16 + jl + 1];
            float h0v, h1v;
            {
                float gi = gA.x + pA.x, gf = gA.y + pA.y, gg = gA.z + pA.z, go = gA.w + pA.w;
                float i_ = 1.f / (1.f + __expf(-gi)), f_ = 1.f / (1.f + __expf(-gf));
                float g_ = tanhfast(gg), o_ = 1.f / (1.f + __expf(-go));
                c0 = f_ * c0 + i_ * g_; h0v = o_ * tanhfast(c0);
            }
            {
                float gi = gB.x + pB.x, gf = gB.y + pB.y, gg = gB.z + pB.z, go = gB.w + pB.w;
                float i_ = 1.f / (1.f + __expf(-gi)), f_ = 1.f / (1.f + __expf(-gf));
                float g_ = tanhfast(gg), o_ = 1.f / (1.f + __expf(-go));
                c1 = f_ * c1 + i_ * g_; h1v = o_ * tanhfast(c1);
            }
            cs[b * 16 + jl] = c0; cs[b * 16 + jl + 1] = c1;
            unsigned short hb0 = f2b(h0v), hb1 = f2b(h1v);
            unsigned pk = (unsigned)hb0 | ((unsigned)hb1 << 16);
            stU((unsigned*)(hw + (long)b * 1024 + j0 + jl), pk);
            *(unsigned*)(enc_out + ((long)b * 64 + t) * 1024 + j0 + jl) = pk;
            eoT[(long)b * 65536 + (long)(j0 + jl) * 64 + t] = hb0;
            eoT[(long)b * 65536 + (long)(j0 + jl + 1) * 64 + t] = hb1;
            if (t == 63) {
                *(unsigned*)(hf + (long)b * 2048 + j0 + jl) = pk;
                cspill[(long)b * 1024 + j0 + jl] = c0;
                cspill[(long)b * 1024 + j0 + jl + 1] = c1;
            }
        }
        gbar(cnt, gen, ++bt);
    }
}

// ---------- persistent decoder: 31 steps x 3 phases ----------
__global__ __launch_bounds__(256, 1) void k_dec(
    const unsigned short* __restrict__ Wh,   // 1024x1024
    const unsigned short* __restrict__ Wc,   // 4096x2048 gate-interleaved
    const float* __restrict__ pre,           // [31][64][4096]
    const float* __restrict__ proj,          // [b*64+s][1024] (attn_b folded)
    const unsigned short* __restrict__ eoT,  // [b][h][s]
    const float* __restrict__ v,
    const float* __restrict__ cspill,
    unsigned short* __restrict__ dcat0, unsigned short* __restrict__ dcat1,
    float* __restrict__ qbuf,
    unsigned short* __restrict__ fccat,
    int* cnt, int* gen)
{
    __shared__ float gs[64 * 64];
    __shared__ float cs[64 * 16];
    __shared__ float qv[1024], vv[1024];
    __shared__ float sc[64], al[64];
    const int blk = blockIdx.x, tid = threadIdx.x;
    const int lane = tid & 63, wave = tid >> 6;
    const int n0 = blk * 64, j0 = blk * 16, q0 = blk * 16;
    const int bcol = lane & 15, kch = (lane >> 4) * 8;
    const int arow = wave * 16 + bcol;
    for (int i = tid; i < 1024; i += 256) {
        cs[i] = cspill[(long)(i >> 4) * 1024 + j0 + (i & 15)];
        vv[i] = v[i];
    }
    const unsigned short* Bq[1] = { Wh + (long)(q0 + bcol) * 1024 + kch };
    const unsigned short* Bc[4];
#pragma unroll
    for (int nt = 0; nt < 4; ++nt) Bc[nt] = Wc + (long)(n0 + nt * 16 + bcol) * 2048 + kch;
    __syncthreads();
    int bt = 0;
    for (int t = 0; t < 31; ++t) {
        unsigned short* dr = (t & 1) ? dcat1 : dcat0;
        unsigned short* dw = (t & 1) ? dcat0 : dcat1;
        // ---- phase 1: q[:, q0:q0+16] = h @ Wh^T
        {
            f32x4 qa[1] = {};
            sgemm<1, 32>(dr + (long)arow * 2048 + kch, Bq, qa);
            int col = q0 + bcol;
#pragma unroll
            for (int q = 0; q < 4; ++q) {
                int b = wave * 16 + (lane >> 4) * 4 + q;
                stF(qbuf + (long)b * 1024 + col, qa[0][q]);
            }
        }
        gbar(cnt, gen, ++bt);
        // ---- phase 2: attention for b = blk
        {
            const int b = blk;
            for (int i = tid; i < 1024; i += 256) qv[i] = ldF(qbuf + (long)b * 1024 + i);
            __syncthreads();
            int s = tid >> 2, part = tid & 3;
            const float* pr = proj + ((long)b * 64 + s) * 1024 + part * 256;
            float a_ = 0.f;
            for (int i = 0; i < 256; i += 4) {
                float4 p4 = *(const float4*)(pr + i);
                int hh = part * 256 + i;
                a_ += vv[hh + 0] * tanhfast(qv[hh + 0] + p4.x);
                a_ += vv[hh + 1] * tanhfast(qv[hh + 1] + p4.y);
                a_ += vv[hh + 2] * tanhfast(qv[hh + 2] + p4.z);
                a_ += vv[hh + 3] * tanhfast(qv[hh + 3] + p4.w);
            }
            a_ += __shfl_xor(a_, 1);
            a_ += __shfl_xor(a_, 2);
            if (part == 0) sc[s] = a_;
            __syncthreads();
            if (tid < 64) {
                float x = sc[tid], mx = x;
                for (int o = 32; o; o >>= 1) mx = fmaxf(mx, __shfl_xor(mx, o));
                float e = __expf(x - mx), su = e;
                for (int o = 32; o; o >>= 1) su += __shfl_xor(su, o);
                al[tid] = e / su;
            }
            __syncthreads();
            float cacc[4];
            const unsigned short* eb = eoT + (long)b * 65536 + (long)tid * 4 * 64;
#pragma unroll
            for (int r = 0; r < 4; ++r) {
                const bf16x8* pp = (const bf16x8*)(eb + r * 64);
                float sacc = 0.f;
#pragma unroll
                for (int c8 = 0; c8 < 8; ++c8) {
                    bf16x8 v8 = pp[c8];
#pragma unroll
                    for (int jj = 0; jj < 8; ++jj)
                        sacc += al[c8 * 8 + jj] * (float)v8[jj];
                }
                cacc[r] = sacc;
            }
#pragma unroll
            for (int r = 0; r < 4; r += 2) {
                unsigned pk = (unsigned)f2b(cacc[r]) | ((unsigned)f2b(cacc[r + 1]) << 16);
                int hh = tid * 4 + r;
                stU((unsigned*)(dr + (long)b * 2048 + 1024 + hh), pk);
                *(unsigned*)(fccat + ((long)t * 64 + b) * 2048 + 1024 + hh) = pk;
            }
        }
        gbar(cnt, gen, ++bt);
        // ---- phase 3: gates = [h|ctx] @ Wc^T + pre; LSTM pointwise
        {
            f32x4 acc[4] = {};
            sgemm<4, 64>(dr + (long)arow * 2048 + kch, Bc, acc);
#pragma unroll
            for (int nt = 0; nt < 4; ++nt)
#pragma unroll
                for (int q = 0; q < 4; ++q)
                    gs[(wave * 16 + (lane >> 4) * 4 + q) * 64 + nt * 16 + bcol] = acc[nt][q];
            __syncthreads();
            const float* pt = pre + (long)t * 64 * 4096;
#pragma unroll
            for (int i = 0; i < 2; ++i) {
                int p = tid + i * 256;
                int b = p >> 3, jl = (p & 7) * 2;
                float4 gA = *(const float4*)(gs + b * 64 + jl * 4);
                float4 gB = *(const float4*)(gs + b * 64 + jl * 4 + 4);
                const float* prr = pt + (long)b * 4096 + n0 + jl * 4;
                float4 pA = *(const float4*)(prr);
                float4 pB = *(const float4*)(prr + 4);
                float c0 = cs[b * 16 + jl], c1 = cs[b * 16 + jl + 1];
                float h0v, h1v;
                {
                    float gi = gA.x + pA.x, gf = gA.y + pA.y, gg = gA.z + pA.z, go = gA.w + pA.w;
                    float i_ = 1.f / (1.f + __expf(-gi)), f_ = 1.f / (1.f + __expf(-gf));
                    float g_ = tanhfast(gg), o_ = 1.f / (1.f + __expf(-go));
                    c0 = f_ * c0 + i_ * g_; h0v = o_ * tanhfast(c0);
                }
                {
                    float gi = gB.x + pB.x, gf = gB.y + pB.y, gg = gB.z + pB.z, go = gB.w + pB.w;
                    float i_ = 1.f / (1.f + __expf(-gi)), f_ = 1.f / (1.f + __expf(-gf));
                    float g_ = tanhfast(gg), o_ = 1.f / (1.f + __expf(-go));
                    c1 = f_ * c1 + i_ * g_; h1v = o_ * tanhfast(c1);
                }
                cs[b * 16 + jl] = c0; cs[b * 16 + jl + 1] = c1;
                unsigned pk = (unsigned)f2b(h0v) | ((unsigned)f2b(h1v) << 16);
                stU((unsigned*)(dw + (long)b * 2048 + j0 + jl), pk);
                *(unsigned*)(fccat + ((long)t * 64 + b) * 2048 + j0 + jl) = pk;
            }
        }
        gbar(cnt, gen, ++bt);
    }
}

// ---------- launch ----------
extern "C" void kernel_launch(void* const* d_in, const int* in_sizes, int n_in,
                              void* d_out, int out_size, void* d_ws, size_t ws_size,
                              hipStream_t stream) {
    const int*   src     = (const int*)d_in[0];
    const int*   tgt     = (const int*)d_in[1];
    const float* enc_emb = (const float*)d_in[2];
    const float* dec_emb = (const float*)d_in[3];
    const float* enc_Wih = (const float*)d_in[4];
    const float* enc_Whh = (const float*)d_in[5];
    const float* enc_bih = (const float*)d_in[6];
    const float* enc_bhh = (const float*)d_in[7];
    const float* dec_Wih = (const float*)d_in[8];
    const float* dec_Whh = (const float*)d_in[9];
    const float* dec_bih = (const float*)d_in[10];
    const float* dec_bhh = (const float*)d_in[11];
    const float* attn_W  = (const float*)d_in[12];
    const float* attn_b  = (const float*)d_in[13];
    const float* vvec    = (const float*)d_in[14];
    const float* fc_W    = (const float*)d_in[15];
    const float* fc_b    = (const float*)d_in[16];
    float* out = (float*)d_out;

    char* ws = (char*)d_ws;
    size_t off = 0;
    auto alloc = [&](size_t bytes) -> char* {
        off = (off + 255) & ~(size_t)255;
        char* p = ws + off; off += bytes; return p;
    };
    unsigned short* wX      = (unsigned short*)alloc(4096UL * 512 * 2);
    unsigned short* weWih   = (unsigned short*)alloc(4096UL * 512 * 2);
    unsigned short* weWhh   = (unsigned short*)alloc(4096UL * 1024 * 2);
    float*          ebias   = (float*)alloc(4096UL * 4);
    float*          pre_enc = (float*)alloc(4096UL * 4096 * 4);
    unsigned short* enc_out = (unsigned short*)alloc(4096UL * 1024 * 2);
    unsigned short* eoT     = (unsigned short*)alloc(64UL * 1024 * 64 * 2);
    unsigned short* wWe     = (unsigned short*)alloc(1024UL * 1024 * 2);
    unsigned short* wWh     = (unsigned short*)alloc(1024UL * 1024 * 2);
    float*          proj    = (float*)alloc(4096UL * 1024 * 4);
    unsigned short* dcat0   = (unsigned short*)alloc(64UL * 2048 * 2);
    unsigned short* dcat1   = (unsigned short*)alloc(64UL * 2048 * 2);
    float*          cbuf    = (float*)alloc(64UL * 1024 * 4);
    float*          qbuf    = (float*)alloc(64UL * 1024 * 4);
    unsigned short* demb    = (unsigned short*)alloc(2048UL * 512 * 2);
    unsigned short* wDemb   = (unsigned short*)alloc(4096UL * 512 * 2);
    unsigned short* wCat    = (unsigned short*)alloc(4096UL * 2048 * 2);
    float*          dbias   = (float*)alloc(4096UL * 4);
    float*          pre_dec = (float*)alloc(2048UL * 4096 * 4);
    unsigned short* fccat   = (unsigned short*)alloc(2048UL * 2048 * 2);
    unsigned short* wFc     = (unsigned short*)alloc(32000UL * 2048 * 2);
    unsigned short* hbuf0   = (unsigned short*)alloc(64UL * 1024 * 2);
    unsigned short* hbuf1   = (unsigned short*)alloc(64UL * 1024 * 2);
    int*            bar     = (int*)alloc(256);
    (void)ws_size; (void)in_sizes; (void)n_in; (void)out_size;

    hipMemsetAsync(bar, 0, 256, stream);
    hipMemsetAsync(hbuf0, 0, 64UL * 1024 * 2, stream);
    k_zero0<<<512, 256, 0, stream>>>(out);

    k_gather<<<2048, 256, 0, stream>>>(enc_emb, src, wX, 64, 64);
    k_gather<<<1024, 256, 0, stream>>>(dec_emb, tgt, demb, 31, 32);
    k_conv<<<2048, 256, 0, stream>>>(enc_Wih, weWih, 4096, 512, 512, 0, 512, 0, 1);
    k_conv<<<2048, 256, 0, stream>>>(enc_Whh, weWhh, 4096, 1024, 1024, 0, 1024, 0, 1);
    k_conv<<<2048, 256, 0, stream>>>(dec_Wih, wDemb, 4096, 512, 1536, 0, 512, 0, 1);
    k_conv<<<2048, 256, 0, stream>>>(dec_Whh, wCat, 4096, 1024, 1024, 0, 2048, 0, 1);
    k_conv<<<2048, 256, 0, stream>>>(dec_Wih, wCat, 4096, 1024, 1536, 512, 2048, 1024, 1);
    k_conv<<<2048, 256, 0, stream>>>(attn_W, wWh, 1024, 1024, 2048, 0, 1024, 0, 0);
    k_conv<<<2048, 256, 0, stream>>>(attn_W, wWe, 1024, 1024, 2048, 1024, 1024, 0, 0);
    k_conv<<<4096, 256, 0, stream>>>(fc_W, wFc, 32000, 2048, 2048, 0, 2048, 0, 0);
    k_bias<<<16, 256, 0, stream>>>(enc_bih, enc_bhh, ebias);
    k_bias<<<16, 256, 0, stream>>>(dec_bih, dec_bhh, dbias);

    // pre-gates GEMMs
    k_gemm<128,128,2,2,4,4,0><<<dim3(32, 32), 256, 0, stream>>>(
        wX, 512, weWih, 512, pre_enc, 4096, ebias, 4096, 4096, 512, 4096);
    k_gemm<128,128,2,2,4,4,0><<<dim3(32, 16), 256, 0, stream>>>(
        demb, 512, wDemb, 512, pre_dec, 4096, dbias, 2048, 4096, 512, 2048);

    // persistent encoder
    k_enc<<<NBLK, 256, 0, stream>>>(weWhh, pre_enc, hbuf0, hbuf1, enc_out, eoT,
                                    dcat0, cbuf, bar + 0, bar + 1);

    // enc_proj (+attn_b)
    k_gemm<128,128,2,2,4,4,0><<<dim3(8, 32), 256, 0, stream>>>(
        enc_out, 1024, wWe, 1024, proj, 1024, attn_b, 4096, 1024, 1024, 4096);

    // persistent decoder
    k_dec<<<NBLK, 256, 0, stream>>>(wWh, wCat, pre_dec, proj, eoT, vvec, cbuf,
                                    dcat0, dcat1, qbuf, fccat, bar + 2, bar + 3);

    // batched fc GEMM -> out (remapped rows), rows b*32 zeroed by k_zero0
    k_gemm<128,128,2,2,4,4,1><<<dim3(250, 16), 256, 0, stream>>>(
        fccat, 2048, wFc, 2048, out, 32000, fc_b, 2048, 32000, 2048, 1984);
}

// Round 4
// 5935.545 us; speedup vs baseline: 1.0298x; 1.0298x over previous
//
#include <hip/hip_runtime.h>
#include <hip/hip_bf16.h>

// ---------- types / helpers ----------
typedef __bf16 bf16x8 __attribute__((ext_vector_type(8)));
typedef float  f32x4  __attribute__((ext_vector_type(4)));
typedef _Float16 h16x2 __attribute__((ext_vector_type(2)));

__device__ __forceinline__ unsigned short f2b(float f) {
    union { float f; unsigned u; } w; w.f = f;
    unsigned u = w.u + 0x7FFF + ((w.u >> 16) & 1);
    return (unsigned short)(u >> 16);
}
__device__ __forceinline__ float tanhfast(float x) {
    float e = __expf(2.0f * x);
    return 1.0f - 2.0f / (e + 1.0f);
}

// coherent (cross-XCD) ops for small mutable state; read-only weights use
// normal loads and stay L2-resident (no fences anywhere).
__device__ __forceinline__ unsigned long long ldU64(const void* p) {
    return __hip_atomic_load((const unsigned long long*)p, __ATOMIC_RELAXED,
                             __HIP_MEMORY_SCOPE_SYSTEM);
}
__device__ __forceinline__ float ldF(const float* p) {
    return __hip_atomic_load((float*)p, __ATOMIC_RELAXED, __HIP_MEMORY_SCOPE_SYSTEM);
}
__device__ __forceinline__ void stU(unsigned* p, unsigned v) {
    __hip_atomic_store(p, v, __ATOMIC_RELAXED, __HIP_MEMORY_SCOPE_SYSTEM);
}
__device__ __forceinline__ void stF(float* p, float v) {
    __hip_atomic_store(p, v, __ATOMIC_RELAXED, __HIP_MEMORY_SCOPE_SYSTEM);
}
__device__ __forceinline__ bf16x8 ldA8(const unsigned short* p) {
    union { unsigned long long u[2]; bf16x8 v; } r;
    r.u[0] = ldU64(p);
    r.u[1] = ldU64(p + 4);
    return r.v;
}

#define GLD16(g, l) __builtin_amdgcn_global_load_lds( \
    (const __attribute__((address_space(1))) void*)(g), \
    (__attribute__((address_space(3))) void*)(l), 16, 0, 0)

#define NBLK 64

// fence-free grid barrier (no cache invalidation; weights stay cached)
__device__ __forceinline__ void gbar(int* cnt, int* gen, int target) {
    asm volatile("s_waitcnt vmcnt(0)" ::: "memory");
    __syncthreads();
    if (threadIdx.x == 0) {
        int v = __hip_atomic_fetch_add(cnt, 1, __ATOMIC_RELAXED, __HIP_MEMORY_SCOPE_SYSTEM);
        if (v == NBLK - 1) {
            __hip_atomic_store(cnt, 0, __ATOMIC_RELAXED, __HIP_MEMORY_SCOPE_SYSTEM);
            __hip_atomic_store(gen, target, __ATOMIC_RELAXED, __HIP_MEMORY_SCOPE_SYSTEM);
        } else {
            while (__hip_atomic_load(gen, __ATOMIC_RELAXED, __HIP_MEMORY_SCOPE_SYSTEM) < target)
                __builtin_amdgcn_s_sleep(2);
        }
    }
    __syncthreads();
}

// streamed MFMA batch: 8 K-chunks (K=256), A coherent, B normal (L2)
template<int NB>
__device__ __forceinline__ void sgemm8(const unsigned short* Ab,
                                       const unsigned short* const (&Bb)[NB],
                                       int coff, f32x4 (&acc)[NB]) {
    bf16x8 a[8];
#pragma unroll
    for (int kk = 0; kk < 8; ++kk) a[kk] = ldA8(Ab + (coff + kk) * 32);
#pragma unroll
    for (int kk = 0; kk < 8; ++kk)
#pragma unroll
        for (int nt = 0; nt < NB; ++nt)
            acc[nt] = __builtin_amdgcn_mfma_f32_16x16x32_bf16(
                a[kk], *(const bf16x8*)(Bb[nt] + (coff + kk) * 32), acc[nt], 0, 0, 0);
}

// ---------- elementwise / conversion kernels ----------

__global__ void k_gather(const float* __restrict__ emb, const int* __restrict__ tok,
                         unsigned short* __restrict__ out, int L, int ldtok) {
    long total = (long)L * 64 * 128;
    for (long i = (long)blockIdx.x * blockDim.x + threadIdx.x; i < total;
         i += (long)gridDim.x * blockDim.x) {
        int  e4 = (int)(i & 127);
        long r  = i >> 7;
        int  t  = (int)(r >> 6), b = (int)(r & 63);
        int  tk = tok[b * ldtok + t];
        float4 v = *(const float4*)(emb + (long)tk * 512 + e4 * 4);
        ushort4 o; o.x = f2b(v.x); o.y = f2b(v.y); o.z = f2b(v.z); o.w = f2b(v.w);
        *(ushort4*)(out + r * 512 + e4 * 4) = o;
    }
}

__global__ void k_conv(const float* __restrict__ in, unsigned short* __restrict__ out,
                       long N_, int K_, int ldin, int col0, int ldout, int outcol0, int reorder) {
    long total = N_ * (K_ >> 2);
    int kq = K_ >> 2;
    for (long i = (long)blockIdx.x * blockDim.x + threadIdx.x; i < total;
         i += (long)gridDim.x * blockDim.x) {
        long n = i / kq;
        int  k4 = (int)(i - n * kq) * 4;
        long row = reorder ? (long)((n & 3) * 1024 + (n >> 2)) : n;
        float4 v = *(const float4*)(in + row * ldin + col0 + k4);
        ushort4 o; o.x = f2b(v.x); o.y = f2b(v.y); o.z = f2b(v.z); o.w = f2b(v.w);
        *(ushort4*)(out + n * ldout + outcol0 + k4) = o;
    }
}

__global__ void k_bias(const float* __restrict__ b1, const float* __restrict__ b2,
                       float* __restrict__ out) {
    int n = blockIdx.x * blockDim.x + threadIdx.x;
    if (n < 4096) {
        int row = (n & 3) * 1024 + (n >> 2);
        out[n] = b1[row] + b2[row];
    }
}

__global__ void k_zero0(float* __restrict__ out) {
    long total = 64L * 8000;
    for (long i = (long)blockIdx.x * blockDim.x + threadIdx.x; i < total;
         i += (long)gridDim.x * blockDim.x) {
        int b = (int)(i / 8000), q = (int)(i % 8000);
        float4 z = {0.f, 0.f, 0.f, 0.f};
        *(float4*)(out + (long)b * 1024000 + q * 4) = z;
    }
}

// ---------- big-GEMM (prep + fc), m97 structure ----------
template<int BM, int BN, int WGM, int WGN, int FM, int FN>
__device__ __forceinline__ void gemm_core(
    const unsigned short* __restrict__ A, int lda,
    const unsigned short* __restrict__ B, int ldb,
    long m0, long n0, int K,
    unsigned short* As, unsigned short* Bs,
    f32x4 (&acc)[FM][FN])
{
    const int tid  = threadIdx.x;
    const int lane = tid & 63;
    const int wave = tid >> 6;
    const int wm = wave / WGN;
    const int wn = wave % WGN;
    const int srow = lane >> 2;
    const int scol = (lane & 3) * 8;
    const int frow = lane & 15;
    const int fcol = (lane >> 4) * 8;

    for (int k0 = 0; k0 < K; k0 += 32) {
        __syncthreads();
        for (int c = wave; c < BM / 16; c += 4) {
            const unsigned short* g = A + (m0 + c * 16 + srow) * (long)lda + k0 + scol;
            GLD16(g, As + c * 512);
        }
        for (int c = wave; c < BN / 16; c += 4) {
            const unsigned short* g = B + (n0 + c * 16 + srow) * (long)ldb + k0 + scol;
            GLD16(g, Bs + c * 512);
        }
        __syncthreads();
        bf16x8 af[FM], bfr[FN];
#pragma unroll
        for (int m = 0; m < FM; ++m)
            af[m] = *(const bf16x8*)(As + ((wm * FM + m) * 16 + frow) * 32 + fcol);
#pragma unroll
        for (int n = 0; n < FN; ++n)
            bfr[n] = *(const bf16x8*)(Bs + ((wn * FN + n) * 16 + frow) * 32 + fcol);
#pragma unroll
        for (int m = 0; m < FM; ++m)
#pragma unroll
            for (int n = 0; n < FN; ++n)
                acc[m][n] = __builtin_amdgcn_mfma_f32_16x16x32_bf16(af[m], bfr[n], acc[m][n], 0, 0, 0);
    }
}

template<int BM, int BN, int WGM, int WGN, int FM, int FN, int MODE>
__global__ __launch_bounds__(256) void k_gemm(
    const unsigned short* __restrict__ A, int lda,
    const unsigned short* __restrict__ B, int ldb,
    float* __restrict__ C, long ldc, const float* __restrict__ bias,
    int M, int N, int K, int Mreal)
{
    __shared__ __align__(16) unsigned short As[BM * 32];
    __shared__ __align__(16) unsigned short Bs[BN * 32];
    long m0 = (long)blockIdx.y * BM;
    long n0 = (long)blockIdx.x * BN;
    f32x4 acc[FM][FN] = {};
    gemm_core<BM, BN, WGM, WGN, FM, FN>(A, lda, B, ldb, m0, n0, K, As, Bs, acc);

    const int lane = threadIdx.x & 63;
    const int wave = threadIdx.x >> 6;
    const int wm = wave / WGN, wn = wave % WGN;
#pragma unroll
    for (int n = 0; n < FN; ++n) {
        long col = n0 + wn * FN * 16 + n * 16 + (lane & 15);
        float bv = bias ? bias[col] : 0.0f;
#pragma unroll
        for (int m = 0; m < FM; ++m) {
            int rl = wm * FM * 16 + m * 16 + (lane >> 4) * 4;
#pragma unroll
            for (int q = 0; q < 4; ++q) {
                long r = m0 + rl + q;
                float val = acc[m][n][q] + bv;
                if (MODE == 0) {
                    C[r * ldc + col] = val;
                } else {
                    if (r < Mreal) {
                        long orow = (r & 63) * 32 + (r >> 6) + 1;
                        C[orow * ldc + col] = val;
                    }
                }
            }
        }
    }
}

// ---------- persistent encoder: 64 blocks x 1024 thr, 1 barrier/step ----------
__global__ __launch_bounds__(1024, 4) void k_enc(
    const unsigned short* __restrict__ W,    // weWhh 4096x1024 gate-interleaved
    const float* __restrict__ pre,           // [64][64][4096]
    unsigned short* __restrict__ h0,
    unsigned short* __restrict__ h1,
    unsigned short* __restrict__ enc_out,    // [b*64+t][1024]
    unsigned short* __restrict__ eoT,        // [b][h][t]
    unsigned short* __restrict__ hf,         // dcat0 h-half, stride 2048
    float* __restrict__ cspill,
    int* cnt, int* gen)
{
    __shared__ float gs[64 * 64];
    const int blk = blockIdx.x, tid = threadIdx.x;
    const int lane = tid & 63, wave = tid >> 6;
    const int rowg = wave >> 2, kq = wave & 3;
    const int n0 = blk * 64, j0 = blk * 16;
    const int arow = rowg * 16 + (lane & 15);
    const int kch = (lane >> 4) * 8;
    // persistent c-state in registers (threads < 512: b=tid>>3, jl2=(tid&7)*2)
    float creg0 = 0.f, creg1 = 0.f;
    const int pb = tid >> 3, pj = (tid & 7) * 2;
    const unsigned short* Bb[4];
#pragma unroll
    for (int nt = 0; nt < 4; ++nt)
        Bb[nt] = W + (long)(n0 + nt * 16 + (lane & 15)) * 1024 + kq * 256 + kch;
    int bt = 0;
    for (int t = 0; t < 64; ++t) {
        const unsigned short* A = ((t & 1) ? h1 : h0);
        unsigned short* hw = (t & 1) ? h0 : h1;
        // init gs = pre slice
        {
            const float* pt = pre + (long)t * 64 * 4096;
            int b = tid >> 4, c4 = (tid & 15) * 4;
            *(float4*)(gs + b * 64 + c4) = *(const float4*)(pt + (long)b * 4096 + n0 + c4);
        }
        __syncthreads();
        f32x4 acc[4] = {};
        sgemm8<4>(A + (long)arow * 1024 + kq * 256 + kch, Bb, 0, acc);
#pragma unroll
        for (int nt = 0; nt < 4; ++nt)
#pragma unroll
            for (int q = 0; q < 4; ++q)
                atomicAdd(&gs[(rowg * 16 + (lane >> 4) * 4 + q) * 64 + nt * 16 + (lane & 15)],
                          acc[nt][q]);
        __syncthreads();
        if (tid < 512) {
            float4 gA = *(const float4*)(gs + pb * 64 + pj * 4);
            float4 gB = *(const float4*)(gs + pb * 64 + pj * 4 + 4);
            float h0v, h1v;
            {
                float i_ = 1.f / (1.f + __expf(-gA.x)), f_ = 1.f / (1.f + __expf(-gA.y));
                float g_ = tanhfast(gA.z), o_ = 1.f / (1.f + __expf(-gA.w));
                creg0 = f_ * creg0 + i_ * g_; h0v = o_ * tanhfast(creg0);
            }
            {
                float i_ = 1.f / (1.f + __expf(-gB.x)), f_ = 1.f / (1.f + __expf(-gB.y));
                float g_ = tanhfast(gB.z), o_ = 1.f / (1.f + __expf(-gB.w));
                creg1 = f_ * creg1 + i_ * g_; h1v = o_ * tanhfast(creg1);
            }
            unsigned short hb0 = f2b(h0v), hb1 = f2b(h1v);
            unsigned pk = (unsigned)hb0 | ((unsigned)hb1 << 16);
            stU((unsigned*)(hw + (long)pb * 1024 + j0 + pj), pk);
            *(unsigned*)(enc_out + ((long)pb * 64 + t) * 1024 + j0 + pj) = pk;
            eoT[(long)pb * 65536 + (long)(j0 + pj) * 64 + t] = hb0;
            eoT[(long)pb * 65536 + (long)(j0 + pj + 1) * 64 + t] = hb1;
            if (t == 63) {
                *(unsigned*)(hf + (long)pb * 2048 + j0 + pj) = pk;
                cspill[(long)pb * 1024 + j0 + pj]     = creg0;
                cspill[(long)pb * 1024 + j0 + pj + 1] = creg1;
            }
        }
        gbar(cnt, gen, ++bt);
    }
}

// ---------- persistent decoder: 64 blocks x 1024 thr, 3 phases/step ----------
// proj pinned in LDS as fp16 for the whole kernel (removes 16 MB/step of reads)
__global__ __launch_bounds__(1024, 4) void k_dec(
    const unsigned short* __restrict__ Wh,   // 1024x1024
    const unsigned short* __restrict__ Wc,   // 4096x2048 gate-interleaved
    const float* __restrict__ pre,           // [31][64][4096]
    const float* __restrict__ proj,          // [b*64+s][1024] f32 (attn_b folded)
    const unsigned short* __restrict__ eoT,  // [b][h][s]
    const float* __restrict__ v,
    const float* __restrict__ cspill,
    unsigned short* __restrict__ dcat0, unsigned short* __restrict__ dcat1,
    float* __restrict__ qbuf,
    unsigned short* __restrict__ fccat,
    int* cnt, int* gen)
{
    __shared__ _Float16 projs[64 * 1024];    // 128 KB
    __shared__ float gs[64 * 64];            // 16 KB
    __shared__ float vv[1024];               // 4 KB
    __shared__ float qv[1024];               // 4 KB
    __shared__ float sc[64], al[64];
    const int blk = blockIdx.x, tid = threadIdx.x;
    const int lane = tid & 63, wave = tid >> 6;
    const int rowg = wave >> 2, kq = wave & 3;
    const int n0 = blk * 64, j0 = blk * 16, q0 = blk * 16;
    const int arow = rowg * 16 + (lane & 15);
    const int kch = (lane >> 4) * 8;
    const int pb = tid >> 3, pj = (tid & 7) * 2;
    // stage proj (fp32 -> fp16 LDS) + vv; init c-regs
    for (int i4 = tid; i4 < 16384; i4 += 1024) {
        int s = i4 >> 8, h4 = (i4 & 255) * 4;
        float4 w4 = *(const float4*)(proj + ((long)blk * 64 + s) * 1024 + h4);
        h16x2 p0 = { (_Float16)w4.x, (_Float16)w4.y };
        h16x2 p1 = { (_Float16)w4.z, (_Float16)w4.w };
        *(h16x2*)(projs + s * 1024 + h4)     = p0;
        *(h16x2*)(projs + s * 1024 + h4 + 2) = p1;
    }
    if (tid < 1024) vv[tid] = v[tid];
    float creg0 = 0.f, creg1 = 0.f;
    if (tid < 512) {
        creg0 = cspill[(long)pb * 1024 + j0 + pj];
        creg1 = cspill[(long)pb * 1024 + j0 + pj + 1];
    }
    const unsigned short* Bq[1] = { Wh + (long)(q0 + (lane & 15)) * 1024 + kq * 256 + kch };
    const unsigned short* Bc[4];
#pragma unroll
    for (int nt = 0; nt < 4; ++nt)
        Bc[nt] = Wc + (long)(n0 + nt * 16 + (lane & 15)) * 2048 + kq * 512 + kch;
    __syncthreads();
    int bt = 0;
    for (int t = 0; t < 31; ++t) {
        unsigned short* dr = (t & 1) ? dcat1 : dcat0;
        unsigned short* dw = (t & 1) ? dcat0 : dcat1;
        // ---- phase 1: q[:, q0:q0+16] = h @ Wh^T (K split 4-ways, LDS reduce)
        {
            gs[tid] = 0.f;
            __syncthreads();
            f32x4 qa[1] = {};
            sgemm8<1>(dr + (long)arow * 2048 + kq * 256 + kch, Bq, 0, qa);
#pragma unroll
            for (int q = 0; q < 4; ++q)
                atomicAdd(&gs[(rowg * 16 + (lane >> 4) * 4 + q) * 16 + (lane & 15)], qa[0][q]);
            __syncthreads();
            stF(qbuf + (long)(tid >> 4) * 1024 + q0 + (tid & 15), gs[tid]);
        }
        gbar(cnt, gen, ++bt);
        // ---- phase 2: attention for b = blk (proj from LDS fp16)
        {
            const int b = blk;
            qv[tid] = ldF(qbuf + (long)b * 1024 + tid);
            __syncthreads();
            int s = tid >> 4, part = tid & 15;
            const h16x2* pj2 = (const h16x2*)(projs + s * 1024);
            float a_ = 0.f;
            int base = part * 32;
#pragma unroll 8
            for (int d = 0; d < 32; ++d) {
                int dd = (d + lane) & 31;                 // bank-spread rotation
                h16x2 pv = pj2[base + dd];
                int h = part * 64 + dd * 2;
                float2 q2 = *(const float2*)(qv + h);
                float2 v2 = *(const float2*)(vv + h);
                a_ += v2.x * tanhfast(q2.x + (float)pv[0]);
                a_ += v2.y * tanhfast(q2.y + (float)pv[1]);
            }
            a_ += __shfl_xor(a_, 1);
            a_ += __shfl_xor(a_, 2);
            a_ += __shfl_xor(a_, 4);
            a_ += __shfl_xor(a_, 8);
            if (part == 0) sc[s] = a_;
            __syncthreads();
            if (tid < 64) {
                float x = sc[tid], mx = x;
                for (int o = 32; o; o >>= 1) mx = fmaxf(mx, __shfl_xor(mx, o));
                float e = __expf(x - mx), su = e;
                for (int o = 32; o; o >>= 1) su += __shfl_xor(su, o);
                al[tid] = e / su;
            }
            __syncthreads();
            if (tid < 512) {
                float cacc[2];
#pragma unroll
                for (int r = 0; r < 2; ++r) {
                    const bf16x8* pp = (const bf16x8*)(eoT + (long)b * 65536 + (long)(tid * 2 + r) * 64);
                    float sacc = 0.f;
#pragma unroll
                    for (int c8 = 0; c8 < 8; ++c8) {
                        bf16x8 v8 = pp[c8];
#pragma unroll
                        for (int jj = 0; jj < 8; ++jj)
                            sacc += al[c8 * 8 + jj] * (float)v8[jj];
                    }
                    cacc[r] = sacc;
                }
                unsigned pk = (unsigned)f2b(cacc[0]) | ((unsigned)f2b(cacc[1]) << 16);
                int hh = tid * 2;
                stU((unsigned*)(dr + (long)b * 2048 + 1024 + hh), pk);
                *(unsigned*)(fccat + ((long)t * 64 + b) * 2048 + 1024 + hh) = pk;
            }
        }
        gbar(cnt, gen, ++bt);
        // ---- phase 3: gates = [h|ctx] @ Wc^T + pre; LSTM pointwise
        {
            {
                const float* pt = pre + (long)t * 64 * 4096;
                int b = tid >> 4, c4 = (tid & 15) * 4;
                *(float4*)(gs + b * 64 + c4) = *(const float4*)(pt + (long)b * 4096 + n0 + c4);
            }
            __syncthreads();
            f32x4 acc[4] = {};
            const unsigned short* Ab = dr + (long)arow * 2048 + kq * 512 + kch;
            sgemm8<4>(Ab, Bc, 0, acc);
            sgemm8<4>(Ab, Bc, 8, acc);
#pragma unroll
            for (int nt = 0; nt < 4; ++nt)
#pragma unroll
                for (int q = 0; q < 4; ++q)
                    atomicAdd(&gs[(rowg * 16 + (lane >> 4) * 4 + q) * 64 + nt * 16 + (lane & 15)],
                              acc[nt][q]);
            __syncthreads();
            if (tid < 512) {
                float4 gA = *(const float4*)(gs + pb * 64 + pj * 4);
                float4 gB = *(const float4*)(gs + pb * 64 + pj * 4 + 4);
                float h0v, h1v;
                {
                    float i_ = 1.f / (1.f + __expf(-gA.x)), f_ = 1.f / (1.f + __expf(-gA.y));
                    float g_ = tanhfast(gA.z), o_ = 1.f / (1.f + __expf(-gA.w));
                    creg0 = f_ * creg0 + i_ * g_; h0v = o_ * tanhfast(creg0);
                }
                {
                    float i_ = 1.f / (1.f + __expf(-gB.x)), f_ = 1.f / (1.f + __expf(-gB.y));
                    float g_ = tanhfast(gB.z), o_ = 1.f / (1.f + __expf(-gB.w));
                    creg1 = f_ * creg1 + i_ * g_; h1v = o_ * tanhfast(creg1);
                }
                unsigned pk = (unsigned)f2b(h0v) | ((unsigned)f2b(h1v) << 16);
                stU((unsigned*)(dw + (long)pb * 2048 + j0 + pj), pk);
                *(unsigned*)(fccat + ((long)t * 64 + pb) * 2048 + j0 + pj) = pk;
            }
        }
        gbar(cnt, gen, ++bt);
    }
}

// ---------- launch ----------
extern "C" void kernel_launch(void* const* d_in, const int* in_sizes, int n_in,
                              void* d_out, int out_size, void* d_ws, size_t ws_size,
                              hipStream_t stream) {
    const int*   src     = (const int*)d_in[0];
    const int*   tgt     = (const int*)d_in[1];
    const float* enc_emb = (const float*)d_in[2];
    const float* dec_emb = (const float*)d_in[3];
    const float* enc_Wih = (const float*)d_in[4];
    const float* enc_Whh = (const float*)d_in[5];
    const float* enc_bih = (const float*)d_in[6];
    const float* enc_bhh = (const float*)d_in[7];
    const float* dec_Wih = (const float*)d_in[8];
    const float* dec_Whh = (const float*)d_in[9];
    const float* dec_bih = (const float*)d_in[10];
    const float* dec_bhh = (const float*)d_in[11];
    const float* attn_W  = (const float*)d_in[12];
    const float* attn_b  = (const float*)d_in[13];
    const float* vvec    = (const float*)d_in[14];
    const float* fc_W    = (const float*)d_in[15];
    const float* fc_b    = (const float*)d_in[16];
    float* out = (float*)d_out;

    char* ws = (char*)d_ws;
    size_t off = 0;
    auto alloc = [&](size_t bytes) -> char* {
        off = (off + 255) & ~(size_t)255;
        char* p = ws + off; off += bytes; return p;
    };
    unsigned short* wX      = (unsigned short*)alloc(4096UL * 512 * 2);
    unsigned short* weWih   = (unsigned short*)alloc(4096UL * 512 * 2);
    unsigned short* weWhh   = (unsigned short*)alloc(4096UL * 1024 * 2);
    float*          ebias   = (float*)alloc(4096UL * 4);
    float*          pre_enc = (float*)alloc(4096UL * 4096 * 4);
    unsigned short* enc_out = (unsigned short*)alloc(4096UL * 1024 * 2);
    unsigned short* eoT     = (unsigned short*)alloc(64UL * 1024 * 64 * 2);
    unsigned short* wWe     = (unsigned short*)alloc(1024UL * 1024 * 2);
    unsigned short* wWh     = (unsigned short*)alloc(1024UL * 1024 * 2);
    float*          proj    = (float*)alloc(4096UL * 1024 * 4);
    unsigned short* dcat0   = (unsigned short*)alloc(64UL * 2048 * 2);
    unsigned short* dcat1   = (unsigned short*)alloc(64UL * 2048 * 2);
    float*          cbuf    = (float*)alloc(64UL * 1024 * 4);
    float*          qbuf    = (float*)alloc(64UL * 1024 * 4);
    unsigned short* demb    = (unsigned short*)alloc(2048UL * 512 * 2);
    unsigned short* wDemb   = (unsigned short*)alloc(4096UL * 512 * 2);
    unsigned short* wCat    = (unsigned short*)alloc(4096UL * 2048 * 2);
    float*          dbias   = (float*)alloc(4096UL * 4);
    float*          pre_dec = (float*)alloc(2048UL * 4096 * 4);
    unsigned short* fccat   = (unsigned short*)alloc(2048UL * 2048 * 2);
    unsigned short* wFc     = (unsigned short*)alloc(32000UL * 2048 * 2);
    unsigned short* hbuf0   = (unsigned short*)alloc(64UL * 1024 * 2);
    unsigned short* hbuf1   = (unsigned short*)alloc(64UL * 1024 * 2);
    int*            bar     = (int*)alloc(256);
    (void)ws_size; (void)in_sizes; (void)n_in; (void)out_size;

    hipMemsetAsync(bar, 0, 256, stream);
    hipMemsetAsync(hbuf0, 0, 64UL * 1024 * 2, stream);
    k_zero0<<<512, 256, 0, stream>>>(out);

    k_gather<<<2048, 256, 0, stream>>>(enc_emb, src, wX, 64, 64);
    k_gather<<<1024, 256, 0, stream>>>(dec_emb, tgt, demb, 31, 32);
    k_conv<<<2048, 256, 0, stream>>>(enc_Wih, weWih, 4096, 512, 512, 0, 512, 0, 1);
    k_conv<<<2048, 256, 0, stream>>>(enc_Whh, weWhh, 4096, 1024, 1024, 0, 1024, 0, 1);
    k_conv<<<2048, 256, 0, stream>>>(dec_Wih, wDemb, 4096, 512, 1536, 0, 512, 0, 1);
    k_conv<<<2048, 256, 0, stream>>>(dec_Whh, wCat, 4096, 1024, 1024, 0, 2048, 0, 1);
    k_conv<<<2048, 256, 0, stream>>>(dec_Wih, wCat, 4096, 1024, 1536, 512, 2048, 1024, 1);
    k_conv<<<2048, 256, 0, stream>>>(attn_W, wWh, 1024, 1024, 2048, 0, 1024, 0, 0);
    k_conv<<<2048, 256, 0, stream>>>(attn_W, wWe, 1024, 1024, 2048, 1024, 1024, 0, 0);
    k_conv<<<4096, 256, 0, stream>>>(fc_W, wFc, 32000, 2048, 2048, 0, 2048, 0, 0);
    k_bias<<<16, 256, 0, stream>>>(enc_bih, enc_bhh, ebias);
    k_bias<<<16, 256, 0, stream>>>(dec_bih, dec_bhh, dbias);

    // pre-gates GEMMs
    k_gemm<128,128,2,2,4,4,0><<<dim3(32, 32), 256, 0, stream>>>(
        wX, 512, weWih, 512, pre_enc, 4096, ebias, 4096, 4096, 512, 4096);
    k_gemm<128,128,2,2,4,4,0><<<dim3(32, 16), 256, 0, stream>>>(
        demb, 512, wDemb, 512, pre_dec, 4096, dbias, 2048, 4096, 512, 2048);

    // persistent encoder
    k_enc<<<NBLK, 1024, 0, stream>>>(weWhh, pre_enc, hbuf0, hbuf1, enc_out, eoT,
                                     dcat0, cbuf, bar + 0, bar + 1);

    // enc_proj (+attn_b)
    k_gemm<128,128,2,2,4,4,0><<<dim3(8, 32), 256, 0, stream>>>(
        enc_out, 1024, wWe, 1024, proj, 1024, attn_b, 4096, 1024, 1024, 4096);

    // persistent decoder
    k_dec<<<NBLK, 1024, 0, stream>>>(wWh, wCat, pre_dec, proj, eoT, vvec, cbuf,
                                     dcat0, dcat1, qbuf, fccat, bar + 2, bar + 3);

    // batched fc GEMM -> out (remapped rows), rows b*32 zeroed by k_zero0
    k_gemm<128,128,2,2,4,4,1><<<dim3(250, 16), 256, 0, stream>>>(
        fccat, 2048, wFc, 2048, out, 32000, fc_b, 2048, 32000, 2048, 1984);
}

// Round 5
// 5710.682 us; speedup vs baseline: 1.0703x; 1.0394x over previous
//
#include <hip/hip_runtime.h>
#include <hip/hip_bf16.h>

// ---------- types / helpers ----------
typedef __bf16 bf16x8 __attribute__((ext_vector_type(8)));
typedef float  f32x4  __attribute__((ext_vector_type(4)));
typedef _Float16 h16x2 __attribute__((ext_vector_type(2)));

__device__ __forceinline__ unsigned short f2b(float f) {
    union { float f; unsigned u; } w; w.f = f;
    unsigned u = w.u + 0x7FFF + ((w.u >> 16) & 1);
    return (unsigned short)(u >> 16);
}
__device__ __forceinline__ float tanhfast(float x) {
    float e = __expf(2.0f * x);
    return 1.0f - 2.0f / (e + 1.0f);
}

// coherent (cross-XCD) ops for small mutable state; read-only weights use
// normal loads and stay L2-resident (no fences anywhere).
__device__ __forceinline__ unsigned long long ldU64(const void* p) {
    return __hip_atomic_load((const unsigned long long*)p, __ATOMIC_RELAXED,
                             __HIP_MEMORY_SCOPE_SYSTEM);
}
__device__ __forceinline__ float ldF(const float* p) {
    return __hip_atomic_load((float*)p, __ATOMIC_RELAXED, __HIP_MEMORY_SCOPE_SYSTEM);
}
__device__ __forceinline__ void stU(unsigned* p, unsigned v) {
    __hip_atomic_store(p, v, __ATOMIC_RELAXED, __HIP_MEMORY_SCOPE_SYSTEM);
}
__device__ __forceinline__ void stF(float* p, float v) {
    __hip_atomic_store(p, v, __ATOMIC_RELAXED, __HIP_MEMORY_SCOPE_SYSTEM);
}
__device__ __forceinline__ int ldI(const int* p) {
    return __hip_atomic_load((int*)p, __ATOMIC_RELAXED, __HIP_MEMORY_SCOPE_SYSTEM);
}
__device__ __forceinline__ void stI(int* p, int v) {
    __hip_atomic_store(p, v, __ATOMIC_RELAXED, __HIP_MEMORY_SCOPE_SYSTEM);
}
__device__ __forceinline__ bf16x8 ldA8(const unsigned short* p) {
    union { unsigned long long u[2]; bf16x8 v; } r;
    r.u[0] = ldU64(p);
    r.u[1] = ldU64(p + 4);
    return r.v;
}

#define GLD16(g, l) __builtin_amdgcn_global_load_lds( \
    (const __attribute__((address_space(1))) void*)(g), \
    (__attribute__((address_space(3))) void*)(l), 16, 0, 0)

#define NBLK 64
#define SLOT_STRIDE 16   // ints -> 64B per slot, no line ping-pong

// contention-free tree grid barrier:
//   arrive:  each block stores epoch to its OWN padded slot (parallel)
//   gather:  block 0 wave 0, lane i polls slot i (one 64-lane load per round)
//   release: block 0 stores gen; others poll gen
__device__ __forceinline__ void gbar(int* slots, int* gen, int target) {
    asm volatile("s_waitcnt vmcnt(0)" ::: "memory");
    __syncthreads();
    if (blockIdx.x == 0) {
        if (threadIdx.x < 64) {
            if (threadIdx.x == 0) stI(slots, target);
            while (ldI(slots + threadIdx.x * SLOT_STRIDE) < target)
                __builtin_amdgcn_s_sleep(1);
        }
        __syncthreads();
        if (threadIdx.x == 0) stI(gen, target);
    } else {
        if (threadIdx.x == 0) {
            stI(slots + blockIdx.x * SLOT_STRIDE, target);
            while (ldI(gen) < target)
                __builtin_amdgcn_s_sleep(1);
        }
        __syncthreads();
    }
}

// streamed MFMA batch: 8 K-chunks, A coherent, B normal (L2)
template<int NB>
__device__ __forceinline__ void sgemm8(const unsigned short* Ab,
                                       const unsigned short* const (&Bb)[NB],
                                       int coff, f32x4 (&acc)[NB]) {
    bf16x8 a[8];
#pragma unroll
    for (int kk = 0; kk < 8; ++kk) a[kk] = ldA8(Ab + (coff + kk) * 32);
#pragma unroll
    for (int kk = 0; kk < 8; ++kk)
#pragma unroll
        for (int nt = 0; nt < NB; ++nt)
            acc[nt] = __builtin_amdgcn_mfma_f32_16x16x32_bf16(
                a[kk], *(const bf16x8*)(Bb[nt] + (coff + kk) * 32), acc[nt], 0, 0, 0);
}

// ---------- elementwise / conversion kernels ----------

__global__ void k_gather(const float* __restrict__ emb, const int* __restrict__ tok,
                         unsigned short* __restrict__ out, int L, int ldtok) {
    long total = (long)L * 64 * 128;
    for (long i = (long)blockIdx.x * blockDim.x + threadIdx.x; i < total;
         i += (long)gridDim.x * blockDim.x) {
        int  e4 = (int)(i & 127);
        long r  = i >> 7;
        int  t  = (int)(r >> 6), b = (int)(r & 63);
        int  tk = tok[b * ldtok + t];
        float4 v = *(const float4*)(emb + (long)tk * 512 + e4 * 4);
        ushort4 o; o.x = f2b(v.x); o.y = f2b(v.y); o.z = f2b(v.z); o.w = f2b(v.w);
        *(ushort4*)(out + r * 512 + e4 * 4) = o;
    }
}

__global__ void k_conv(const float* __restrict__ in, unsigned short* __restrict__ out,
                       long N_, int K_, int ldin, int col0, int ldout, int outcol0, int reorder) {
    long total = N_ * (K_ >> 2);
    int kq = K_ >> 2;
    for (long i = (long)blockIdx.x * blockDim.x + threadIdx.x; i < total;
         i += (long)gridDim.x * blockDim.x) {
        long n = i / kq;
        int  k4 = (int)(i - n * kq) * 4;
        long row = reorder ? (long)((n & 3) * 1024 + (n >> 2)) : n;
        float4 v = *(const float4*)(in + row * ldin + col0 + k4);
        ushort4 o; o.x = f2b(v.x); o.y = f2b(v.y); o.z = f2b(v.z); o.w = f2b(v.w);
        *(ushort4*)(out + n * ldout + outcol0 + k4) = o;
    }
}

__global__ void k_bias(const float* __restrict__ b1, const float* __restrict__ b2,
                       float* __restrict__ out) {
    int n = blockIdx.x * blockDim.x + threadIdx.x;
    if (n < 4096) {
        int row = (n & 3) * 1024 + (n >> 2);
        out[n] = b1[row] + b2[row];
    }
}

__global__ void k_zero0(float* __restrict__ out) {
    long total = 64L * 8000;
    for (long i = (long)blockIdx.x * blockDim.x + threadIdx.x; i < total;
         i += (long)gridDim.x * blockDim.x) {
        int b = (int)(i / 8000), q = (int)(i % 8000);
        float4 z = {0.f, 0.f, 0.f, 0.f};
        *(float4*)(out + (long)b * 1024000 + q * 4) = z;
    }
}

// ---------- big-GEMM (prep + fc), m97 structure ----------
template<int BM, int BN, int WGM, int WGN, int FM, int FN>
__device__ __forceinline__ void gemm_core(
    const unsigned short* __restrict__ A, int lda,
    const unsigned short* __restrict__ B, int ldb,
    long m0, long n0, int K,
    unsigned short* As, unsigned short* Bs,
    f32x4 (&acc)[FM][FN])
{
    const int tid  = threadIdx.x;
    const int lane = tid & 63;
    const int wave = tid >> 6;
    const int wm = wave / WGN;
    const int wn = wave % WGN;
    const int srow = lane >> 2;
    const int scol = (lane & 3) * 8;
    const int frow = lane & 15;
    const int fcol = (lane >> 4) * 8;

    for (int k0 = 0; k0 < K; k0 += 32) {
        __syncthreads();
        for (int c = wave; c < BM / 16; c += 4) {
            const unsigned short* g = A + (m0 + c * 16 + srow) * (long)lda + k0 + scol;
            GLD16(g, As + c * 512);
        }
        for (int c = wave; c < BN / 16; c += 4) {
            const unsigned short* g = B + (n0 + c * 16 + srow) * (long)ldb + k0 + scol;
            GLD16(g, Bs + c * 512);
        }
        __syncthreads();
        bf16x8 af[FM], bfr[FN];
#pragma unroll
        for (int m = 0; m < FM; ++m)
            af[m] = *(const bf16x8*)(As + ((wm * FM + m) * 16 + frow) * 32 + fcol);
#pragma unroll
        for (int n = 0; n < FN; ++n)
            bfr[n] = *(const bf16x8*)(Bs + ((wn * FN + n) * 16 + frow) * 32 + fcol);
#pragma unroll
        for (int m = 0; m < FM; ++m)
#pragma unroll
            for (int n = 0; n < FN; ++n)
                acc[m][n] = __builtin_amdgcn_mfma_f32_16x16x32_bf16(af[m], bfr[n], acc[m][n], 0, 0, 0);
    }
}

template<int BM, int BN, int WGM, int WGN, int FM, int FN, int MODE>
__global__ __launch_bounds__(256) void k_gemm(
    const unsigned short* __restrict__ A, int lda,
    const unsigned short* __restrict__ B, int ldb,
    float* __restrict__ C, long ldc, const float* __restrict__ bias,
    int M, int N, int K, int Mreal)
{
    __shared__ __align__(16) unsigned short As[BM * 32];
    __shared__ __align__(16) unsigned short Bs[BN * 32];
    long m0 = (long)blockIdx.y * BM;
    long n0 = (long)blockIdx.x * BN;
    f32x4 acc[FM][FN] = {};
    gemm_core<BM, BN, WGM, WGN, FM, FN>(A, lda, B, ldb, m0, n0, K, As, Bs, acc);

    const int lane = threadIdx.x & 63;
    const int wave = threadIdx.x >> 6;
    const int wm = wave / WGN, wn = wave % WGN;
#pragma unroll
    for (int n = 0; n < FN; ++n) {
        long col = n0 + wn * FN * 16 + n * 16 + (lane & 15);
        float bv = bias ? bias[col] : 0.0f;
#pragma unroll
        for (int m = 0; m < FM; ++m) {
            int rl = wm * FM * 16 + m * 16 + (lane >> 4) * 4;
#pragma unroll
            for (int q = 0; q < 4; ++q) {
                long r = m0 + rl + q;
                float val = acc[m][n][q] + bv;
                if (MODE == 0) {
                    C[r * ldc + col] = val;
                } else {
                    if (r < Mreal) {
                        long orow = (r & 63) * 32 + (r >> 6) + 1;
                        C[orow * ldc + col] = val;
                    }
                }
            }
        }
    }
}

// ---------- persistent encoder: 64 blocks x 1024 thr, 1 barrier/step ----------
__global__ __launch_bounds__(1024, 4) void k_enc(
    const unsigned short* __restrict__ W,    // weWhh 4096x1024 gate-interleaved
    const float* __restrict__ pre,           // [64][64][4096]
    unsigned short* __restrict__ h0,
    unsigned short* __restrict__ h1,
    unsigned short* __restrict__ enc_out,    // [b*64+t][1024]
    unsigned short* __restrict__ eoT,        // [b][h][t]
    unsigned short* __restrict__ hf,         // dcat0 h-half, stride 2048
    float* __restrict__ cspill,
    int* slots, int* gen)
{
    __shared__ float gs[64 * 64];
    const int blk = blockIdx.x, tid = threadIdx.x;
    const int lane = tid & 63, wave = tid >> 6;
    const int rowg = wave >> 2, kq = wave & 3;
    const int n0 = blk * 64, j0 = blk * 16;
    const int arow = rowg * 16 + (lane & 15);
    const int kch = (lane >> 4) * 8;
    float creg0 = 0.f, creg1 = 0.f;
    const int pb = tid >> 3, pj = (tid & 7) * 2;
    const unsigned short* Bb[4];
#pragma unroll
    for (int nt = 0; nt < 4; ++nt)
        Bb[nt] = W + (long)(n0 + nt * 16 + (lane & 15)) * 1024 + kq * 256 + kch;
    int bt = 0;
    for (int t = 0; t < 64; ++t) {
        const unsigned short* A = ((t & 1) ? h1 : h0);
        unsigned short* hw = (t & 1) ? h0 : h1;
        {
            const float* pt = pre + (long)t * 64 * 4096;
            int b = tid >> 4, c4 = (tid & 15) * 4;
            *(float4*)(gs + b * 64 + c4) = *(const float4*)(pt + (long)b * 4096 + n0 + c4);
        }
        __syncthreads();
        f32x4 acc[4] = {};
        sgemm8<4>(A + (long)arow * 1024 + kq * 256 + kch, Bb, 0, acc);
#pragma unroll
        for (int nt = 0; nt < 4; ++nt)
#pragma unroll
            for (int q = 0; q < 4; ++q)
                atomicAdd(&gs[(rowg * 16 + (lane >> 4) * 4 + q) * 64 + nt * 16 + (lane & 15)],
                          acc[nt][q]);
        __syncthreads();
        if (tid < 512) {
            float4 gA = *(const float4*)(gs + pb * 64 + pj * 4);
            float4 gB = *(const float4*)(gs + pb * 64 + pj * 4 + 4);
            float h0v, h1v;
            {
                float i_ = 1.f / (1.f + __expf(-gA.x)), f_ = 1.f / (1.f + __expf(-gA.y));
                float g_ = tanhfast(gA.z), o_ = 1.f / (1.f + __expf(-gA.w));
                creg0 = f_ * creg0 + i_ * g_; h0v = o_ * tanhfast(creg0);
            }
            {
                float i_ = 1.f / (1.f + __expf(-gB.x)), f_ = 1.f / (1.f + __expf(-gB.y));
                float g_ = tanhfast(gB.z), o_ = 1.f / (1.f + __expf(-gB.w));
                creg1 = f_ * creg1 + i_ * g_; h1v = o_ * tanhfast(creg1);
            }
            unsigned short hb0 = f2b(h0v), hb1 = f2b(h1v);
            unsigned pk = (unsigned)hb0 | ((unsigned)hb1 << 16);
            stU((unsigned*)(hw + (long)pb * 1024 + j0 + pj), pk);
            *(unsigned*)(enc_out + ((long)pb * 64 + t) * 1024 + j0 + pj) = pk;
            eoT[(long)pb * 65536 + (long)(j0 + pj) * 64 + t] = hb0;
            eoT[(long)pb * 65536 + (long)(j0 + pj + 1) * 64 + t] = hb1;
            if (t == 63) {
                *(unsigned*)(hf + (long)pb * 2048 + j0 + pj) = pk;
                cspill[(long)pb * 1024 + j0 + pj]     = creg0;
                cspill[(long)pb * 1024 + j0 + pj + 1] = creg1;
            }
        }
        gbar(slots, gen, ++bt);
    }
}

// ---------- persistent decoder: 64 blocks x 1024 thr, 3 phases/step ----------
// proj pinned in LDS as fp16 for the whole kernel
__global__ __launch_bounds__(1024, 4) void k_dec(
    const unsigned short* __restrict__ Wh,   // 1024x1024
    const unsigned short* __restrict__ Wc,   // 4096x2048 gate-interleaved
    const float* __restrict__ pre,           // [31][64][4096]
    const float* __restrict__ proj,          // [b*64+s][1024] f32 (attn_b folded)
    const unsigned short* __restrict__ eoT,  // [b][h][s]
    const float* __restrict__ v,
    const float* __restrict__ cspill,
    unsigned short* __restrict__ dcat0, unsigned short* __restrict__ dcat1,
    float* __restrict__ qbuf,
    unsigned short* __restrict__ fccat,
    int* slots, int* gen)
{
    __shared__ _Float16 projs[64 * 1024];    // 128 KB
    __shared__ float gs[64 * 64];            // 16 KB
    __shared__ float vv[1024];
    __shared__ float qv[1024];
    __shared__ float sc[64], al[64];
    const int blk = blockIdx.x, tid = threadIdx.x;
    const int lane = tid & 63, wave = tid >> 6;
    const int rowg = wave >> 2, kq = wave & 3;
    const int n0 = blk * 64, j0 = blk * 16, q0 = blk * 16;
    const int arow = rowg * 16 + (lane & 15);
    const int kch = (lane >> 4) * 8;
    const int pb = tid >> 3, pj = (tid & 7) * 2;
    for (int i4 = tid; i4 < 16384; i4 += 1024) {
        int s = i4 >> 8, h4 = (i4 & 255) * 4;
        float4 w4 = *(const float4*)(proj + ((long)blk * 64 + s) * 1024 + h4);
        h16x2 p0 = { (_Float16)w4.x, (_Float16)w4.y };
        h16x2 p1 = { (_Float16)w4.z, (_Float16)w4.w };
        *(h16x2*)(projs + s * 1024 + h4)     = p0;
        *(h16x2*)(projs + s * 1024 + h4 + 2) = p1;
    }
    if (tid < 1024) vv[tid] = v[tid];
    float creg0 = 0.f, creg1 = 0.f;
    if (tid < 512) {
        creg0 = cspill[(long)pb * 1024 + j0 + pj];
        creg1 = cspill[(long)pb * 1024 + j0 + pj + 1];
    }
    const unsigned short* Bq[1] = { Wh + (long)(q0 + (lane & 15)) * 1024 + kq * 256 + kch };
    const unsigned short* Bc[4];
#pragma unroll
    for (int nt = 0; nt < 4; ++nt)
        Bc[nt] = Wc + (long)(n0 + nt * 16 + (lane & 15)) * 2048 + kq * 512 + kch;
    __syncthreads();
    int bt = 0;
    for (int t = 0; t < 31; ++t) {
        unsigned short* dr = (t & 1) ? dcat1 : dcat0;
        unsigned short* dw = (t & 1) ? dcat0 : dcat1;
        // ---- phase 1: q[:, q0:q0+16] = h @ Wh^T (K split 4-ways, LDS reduce)
        {
            gs[tid] = 0.f;
            __syncthreads();
            f32x4 qa[1] = {};
            sgemm8<1>(dr + (long)arow * 2048 + kq * 256 + kch, Bq, 0, qa);
#pragma unroll
            for (int q = 0; q < 4; ++q)
                atomicAdd(&gs[(rowg * 16 + (lane >> 4) * 4 + q) * 16 + (lane & 15)], qa[0][q]);
            __syncthreads();
            stF(qbuf + (long)(tid >> 4) * 1024 + q0 + (tid & 15), gs[tid]);
        }
        gbar(slots, gen, ++bt);
        // ---- phase 2: attention for b = blk (proj from LDS fp16)
        {
            const int b = blk;
            qv[tid] = ldF(qbuf + (long)b * 1024 + tid);
            __syncthreads();
            int s = tid >> 4, part = tid & 15;
            const h16x2* pj2 = (const h16x2*)(projs + s * 1024);
            float a_ = 0.f;
            int base = part * 32;
#pragma unroll 8
            for (int d = 0; d < 32; ++d) {
                int dd = (d + lane) & 31;
                h16x2 pv = pj2[base + dd];
                int h = part * 64 + dd * 2;
                float2 q2 = *(const float2*)(qv + h);
                float2 v2 = *(const float2*)(vv + h);
                a_ += v2.x * tanhfast(q2.x + (float)pv[0]);
                a_ += v2.y * tanhfast(q2.y + (float)pv[1]);
            }
            a_ += __shfl_xor(a_, 1);
            a_ += __shfl_xor(a_, 2);
            a_ += __shfl_xor(a_, 4);
            a_ += __shfl_xor(a_, 8);
            if (part == 0) sc[s] = a_;
            __syncthreads();
            if (tid < 64) {
                float x = sc[tid], mx = x;
                for (int o = 32; o; o >>= 1) mx = fmaxf(mx, __shfl_xor(mx, o));
                float e = __expf(x - mx), su = e;
                for (int o = 32; o; o >>= 1) su += __shfl_xor(su, o);
                al[tid] = e / su;
            }
            __syncthreads();
            if (tid < 512) {
                float cacc[2];
#pragma unroll
                for (int r = 0; r < 2; ++r) {
                    const bf16x8* pp = (const bf16x8*)(eoT + (long)b * 65536 + (long)(tid * 2 + r) * 64);
                    float sacc = 0.f;
#pragma unroll
                    for (int c8 = 0; c8 < 8; ++c8) {
                        bf16x8 v8 = pp[c8];
#pragma unroll
                        for (int jj = 0; jj < 8; ++jj)
                            sacc += al[c8 * 8 + jj] * (float)v8[jj];
                    }
                    cacc[r] = sacc;
                }
                unsigned pk = (unsigned)f2b(cacc[0]) | ((unsigned)f2b(cacc[1]) << 16);
                int hh = tid * 2;
                stU((unsigned*)(dr + (long)b * 2048 + 1024 + hh), pk);
                *(unsigned*)(fccat + ((long)t * 64 + b) * 2048 + 1024 + hh) = pk;
            }
        }
        gbar(slots, gen, ++bt);
        // ---- phase 3: gates = [h|ctx] @ Wc^T + pre; LSTM pointwise
        {
            {
                const float* pt = pre + (long)t * 64 * 4096;
                int b = tid >> 4, c4 = (tid & 15) * 4;
                *(float4*)(gs + b * 64 + c4) = *(const float4*)(pt + (long)b * 4096 + n0 + c4);
            }
            __syncthreads();
            f32x4 acc[4] = {};
            const unsigned short* Ab = dr + (long)arow * 2048 + kq * 512 + kch;
            sgemm8<4>(Ab, Bc, 0, acc);
            sgemm8<4>(Ab, Bc, 8, acc);
#pragma unroll
            for (int nt = 0; nt < 4; ++nt)
#pragma unroll
                for (int q = 0; q < 4; ++q)
                    atomicAdd(&gs[(rowg * 16 + (lane >> 4) * 4 + q) * 64 + nt * 16 + (lane & 15)],
                              acc[nt][q]);
            __syncthreads();
            if (tid < 512) {
                float4 gA = *(const float4*)(gs + pb * 64 + pj * 4);
                float4 gB = *(const float4*)(gs + pb * 64 + pj * 4 + 4);
                float h0v, h1v;
                {
                    float i_ = 1.f / (1.f + __expf(-gA.x)), f_ = 1.f / (1.f + __expf(-gA.y));
                    float g_ = tanhfast(gA.z), o_ = 1.f / (1.f + __expf(-gA.w));
                    creg0 = f_ * creg0 + i_ * g_; h0v = o_ * tanhfast(creg0);
                }
                {
                    float i_ = 1.f / (1.f + __expf(-gB.x)), f_ = 1.f / (1.f + __expf(-gB.y));
                    float g_ = tanhfast(gB.z), o_ = 1.f / (1.f + __expf(-gB.w));
                    creg1 = f_ * creg1 + i_ * g_; h1v = o_ * tanhfast(creg1);
                }
                unsigned pk = (unsigned)f2b(h0v) | ((unsigned)f2b(h1v) << 16);
                stU((unsigned*)(dw + (long)pb * 2048 + j0 + pj), pk);
                *(unsigned*)(fccat + ((long)t * 64 + pb) * 2048 + j0 + pj) = pk;
            }
        }
        gbar(slots, gen, ++bt);
    }
}

// ---------- launch ----------
extern "C" void kernel_launch(void* const* d_in, const int* in_sizes, int n_in,
                              void* d_out, int out_size, void* d_ws, size_t ws_size,
                              hipStream_t stream) {
    const int*   src     = (const int*)d_in[0];
    const int*   tgt     = (const int*)d_in[1];
    const float* enc_emb = (const float*)d_in[2];
    const float* dec_emb = (const float*)d_in[3];
    const float* enc_Wih = (const float*)d_in[4];
    const float* enc_Whh = (const float*)d_in[5];
    const float* enc_bih = (const float*)d_in[6];
    const float* enc_bhh = (const float*)d_in[7];
    const float* dec_Wih = (const float*)d_in[8];
    const float* dec_Whh = (const float*)d_in[9];
    const float* dec_bih = (const float*)d_in[10];
    const float* dec_bhh = (const float*)d_in[11];
    const float* attn_W  = (const float*)d_in[12];
    const float* attn_b  = (const float*)d_in[13];
    const float* vvec    = (const float*)d_in[14];
    const float* fc_W    = (const float*)d_in[15];
    const float* fc_b    = (const float*)d_in[16];
    float* out = (float*)d_out;

    char* ws = (char*)d_ws;
    size_t off = 0;
    auto alloc = [&](size_t bytes) -> char* {
        off = (off + 255) & ~(size_t)255;
        char* p = ws + off; off += bytes; return p;
    };
    unsigned short* wX      = (unsigned short*)alloc(4096UL * 512 * 2);
    unsigned short* weWih   = (unsigned short*)alloc(4096UL * 512 * 2);
    unsigned short* weWhh   = (unsigned short*)alloc(4096UL * 1024 * 2);
    float*          ebias   = (float*)alloc(4096UL * 4);
    float*          pre_enc = (float*)alloc(4096UL * 4096 * 4);
    unsigned short* enc_out = (unsigned short*)alloc(4096UL * 1024 * 2);
    unsigned short* eoT     = (unsigned short*)alloc(64UL * 1024 * 64 * 2);
    unsigned short* wWe     = (unsigned short*)alloc(1024UL * 1024 * 2);
    unsigned short* wWh     = (unsigned short*)alloc(1024UL * 1024 * 2);
    float*          proj    = (float*)alloc(4096UL * 1024 * 4);
    unsigned short* dcat0   = (unsigned short*)alloc(64UL * 2048 * 2);
    unsigned short* dcat1   = (unsigned short*)alloc(64UL * 2048 * 2);
    float*          cbuf    = (float*)alloc(64UL * 1024 * 4);
    float*          qbuf    = (float*)alloc(64UL * 1024 * 4);
    unsigned short* demb    = (unsigned short*)alloc(2048UL * 512 * 2);
    unsigned short* wDemb   = (unsigned short*)alloc(4096UL * 512 * 2);
    unsigned short* wCat    = (unsigned short*)alloc(4096UL * 2048 * 2);
    float*          dbias   = (float*)alloc(4096UL * 4);
    float*          pre_dec = (float*)alloc(2048UL * 4096 * 4);
    unsigned short* fccat   = (unsigned short*)alloc(2048UL * 2048 * 2);
    unsigned short* wFc     = (unsigned short*)alloc(32000UL * 2048 * 2);
    unsigned short* hbuf0   = (unsigned short*)alloc(64UL * 1024 * 2);
    unsigned short* hbuf1   = (unsigned short*)alloc(64UL * 1024 * 2);
    int*            bar     = (int*)alloc(16384);
    (void)ws_size; (void)in_sizes; (void)n_in; (void)out_size;

    int* slotsE = bar;           // 64 slots x 64B
    int* genE   = bar + 1024;
    int* slotsD = bar + 2048;
    int* genD   = bar + 3072;

    hipMemsetAsync(bar, 0, 16384, stream);
    hipMemsetAsync(hbuf0, 0, 64UL * 1024 * 2, stream);
    k_zero0<<<512, 256, 0, stream>>>(out);

    k_gather<<<2048, 256, 0, stream>>>(enc_emb, src, wX, 64, 64);
    k_gather<<<1024, 256, 0, stream>>>(dec_emb, tgt, demb, 31, 32);
    k_conv<<<2048, 256, 0, stream>>>(enc_Wih, weWih, 4096, 512, 512, 0, 512, 0, 1);
    k_conv<<<2048, 256, 0, stream>>>(enc_Whh, weWhh, 4096, 1024, 1024, 0, 1024, 0, 1);
    k_conv<<<2048, 256, 0, stream>>>(dec_Wih, wDemb, 4096, 512, 1536, 0, 512, 0, 1);
    k_conv<<<2048, 256, 0, stream>>>(dec_Whh, wCat, 4096, 1024, 1024, 0, 2048, 0, 1);
    k_conv<<<2048, 256, 0, stream>>>(dec_Wih, wCat, 4096, 1024, 1536, 512, 2048, 1024, 1);
    k_conv<<<2048, 256, 0, stream>>>(attn_W, wWh, 1024, 1024, 2048, 0, 1024, 0, 0);
    k_conv<<<2048, 256, 0, stream>>>(attn_W, wWe, 1024, 1024, 2048, 1024, 1024, 0, 0);
    k_conv<<<4096, 256, 0, stream>>>(fc_W, wFc, 32000, 2048, 2048, 0, 2048, 0, 0);
    k_bias<<<16, 256, 0, stream>>>(enc_bih, enc_bhh, ebias);
    k_bias<<<16, 256, 0, stream>>>(dec_bih, dec_bhh, dbias);

    // pre-gates GEMMs
    k_gemm<128,128,2,2,4,4,0><<<dim3(32, 32), 256, 0, stream>>>(
        wX, 512, weWih, 512, pre_enc, 4096, ebias, 4096, 4096, 512, 4096);
    k_gemm<128,128,2,2,4,4,0><<<dim3(32, 16), 256, 0, stream>>>(
        demb, 512, wDemb, 512, pre_dec, 4096, dbias, 2048, 4096, 512, 2048);

    // persistent encoder
    k_enc<<<NBLK, 1024, 0, stream>>>(weWhh, pre_enc, hbuf0, hbuf1, enc_out, eoT,
                                     dcat0, cbuf, slotsE, genE);

    // enc_proj (+attn_b)
    k_gemm<128,128,2,2,4,4,0><<<dim3(8, 32), 256, 0, stream>>>(
        enc_out, 1024, wWe, 1024, proj, 1024, attn_b, 4096, 1024, 1024, 4096);

    // persistent decoder
    k_dec<<<NBLK, 1024, 0, stream>>>(wWh, wCat, pre_dec, proj, eoT, vvec, cbuf,
                                     dcat0, dcat1, qbuf, fccat, slotsD, genD);

    // batched fc GEMM -> out (remapped rows), rows b*32 zeroed by k_zero0
    k_gemm<128,128,2,2,4,4,1><<<dim3(250, 16), 256, 0, stream>>>(
        fccat, 2048, wFc, 2048, out, 32000, fc_b, 2048, 32000, 2048, 1984);
}

// Round 6
// 5463.896 us; speedup vs baseline: 1.1186x; 1.0452x over previous
//
#include <hip/hip_runtime.h>
#include <hip/hip_bf16.h>

// ---------- types / helpers ----------
typedef __bf16 bf16x8 __attribute__((ext_vector_type(8)));
typedef float  f32x4  __attribute__((ext_vector_type(4)));
typedef _Float16 h16x2 __attribute__((ext_vector_type(2)));

__device__ __forceinline__ unsigned short f2b(float f) {
    union { float f; unsigned u; } w; w.f = f;
    unsigned u = w.u + 0x7FFF + ((w.u >> 16) & 1);
    return (unsigned short)(u >> 16);
}
__device__ __forceinline__ float tanhfast(float x) {
    float e = __expf(2.0f * x);
    return 1.0f - 2.0f / (e + 1.0f);
}

// system-scope (cross-XCD write-through) STORES for per-step state slots.
// Readers use PLAIN cached loads: each slot is written exactly once and the
// reading CU has never touched the address before -> its L2 can't be stale.
__device__ __forceinline__ void stU(unsigned* p, unsigned v) {
    __hip_atomic_store(p, v, __ATOMIC_RELAXED, __HIP_MEMORY_SCOPE_SYSTEM);
}
__device__ __forceinline__ void stF(float* p, float v) {
    __hip_atomic_store(p, v, __ATOMIC_RELAXED, __HIP_MEMORY_SCOPE_SYSTEM);
}
__device__ __forceinline__ int ldI(const int* p) {
    return __hip_atomic_load((int*)p, __ATOMIC_RELAXED, __HIP_MEMORY_SCOPE_SYSTEM);
}
__device__ __forceinline__ void stI(int* p, int v) {
    __hip_atomic_store(p, v, __ATOMIC_RELAXED, __HIP_MEMORY_SCOPE_SYSTEM);
}

#define GLD16(g, l) __builtin_amdgcn_global_load_lds( \
    (const __attribute__((address_space(1))) void*)(g), \
    (__attribute__((address_space(3))) void*)(l), 16, 0, 0)

#define NBLK 64
#define SLOT_STRIDE 16   // ints -> 64B per slot

// contention-free tree grid barrier
__device__ __forceinline__ void gbar(int* slots, int* gen, int target) {
    asm volatile("s_waitcnt vmcnt(0)" ::: "memory");
    __syncthreads();
    if (blockIdx.x == 0) {
        if (threadIdx.x < 64) {
            if (threadIdx.x == 0) stI(slots, target);
            while (ldI(slots + threadIdx.x * SLOT_STRIDE) < target)
                __builtin_amdgcn_s_sleep(1);
        }
        __syncthreads();
        if (threadIdx.x == 0) stI(gen, target);
    } else {
        if (threadIdx.x == 0) {
            stI(slots + blockIdx.x * SLOT_STRIDE, target);
            while (ldI(gen) < target)
                __builtin_amdgcn_s_sleep(1);
        }
        __syncthreads();
    }
}

// streamed MFMA batch, plain cached loads (A from per-step slot, B L2-warm)
template<int NB>
__device__ __forceinline__ void sgemmN(const unsigned short* Ab,
                                       const unsigned short* const (&Bb)[NB],
                                       int coff, f32x4 (&acc)[NB]) {
    bf16x8 a[8];
#pragma unroll
    for (int kk = 0; kk < 8; ++kk) a[kk] = *(const bf16x8*)(Ab + (coff + kk) * 32);
#pragma unroll
    for (int kk = 0; kk < 8; ++kk)
#pragma unroll
        for (int nt = 0; nt < NB; ++nt)
            acc[nt] = __builtin_amdgcn_mfma_f32_16x16x32_bf16(
                a[kk], *(const bf16x8*)(Bb[nt] + (coff + kk) * 32), acc[nt], 0, 0, 0);
}

// ---------- elementwise / conversion kernels ----------

__global__ void k_gather(const float* __restrict__ emb, const int* __restrict__ tok,
                         unsigned short* __restrict__ out, int L, int ldtok) {
    long total = (long)L * 64 * 128;
    for (long i = (long)blockIdx.x * blockDim.x + threadIdx.x; i < total;
         i += (long)gridDim.x * blockDim.x) {
        int  e4 = (int)(i & 127);
        long r  = i >> 7;
        int  t  = (int)(r >> 6), b = (int)(r & 63);
        int  tk = tok[b * ldtok + t];
        float4 v = *(const float4*)(emb + (long)tk * 512 + e4 * 4);
        ushort4 o; o.x = f2b(v.x); o.y = f2b(v.y); o.z = f2b(v.z); o.w = f2b(v.w);
        *(ushort4*)(out + r * 512 + e4 * 4) = o;
    }
}

__global__ void k_conv(const float* __restrict__ in, unsigned short* __restrict__ out,
                       long N_, int K_, int ldin, int col0, int ldout, int outcol0, int reorder) {
    long total = N_ * (K_ >> 2);
    int kq = K_ >> 2;
    for (long i = (long)blockIdx.x * blockDim.x + threadIdx.x; i < total;
         i += (long)gridDim.x * blockDim.x) {
        long n = i / kq;
        int  k4 = (int)(i - n * kq) * 4;
        long row = reorder ? (long)((n & 3) * 1024 + (n >> 2)) : n;
        float4 v = *(const float4*)(in + row * ldin + col0 + k4);
        ushort4 o; o.x = f2b(v.x); o.y = f2b(v.y); o.z = f2b(v.z); o.w = f2b(v.w);
        *(ushort4*)(out + n * ldout + outcol0 + k4) = o;
    }
}

__global__ void k_bias(const float* __restrict__ b1, const float* __restrict__ b2,
                       float* __restrict__ out) {
    int n = blockIdx.x * blockDim.x + threadIdx.x;
    if (n < 4096) {
        int row = (n & 3) * 1024 + (n >> 2);
        out[n] = b1[row] + b2[row];
    }
}

__global__ void k_zero0(float* __restrict__ out) {
    long total = 64L * 8000;
    for (long i = (long)blockIdx.x * blockDim.x + threadIdx.x; i < total;
         i += (long)gridDim.x * blockDim.x) {
        int b = (int)(i / 8000), q = (int)(i % 8000);
        float4 z = {0.f, 0.f, 0.f, 0.f};
        *(float4*)(out + (long)b * 1024000 + q * 4) = z;
    }
}

// ---------- big-GEMM (prep + fc), m97 structure ----------
template<int BM, int BN, int WGM, int WGN, int FM, int FN>
__device__ __forceinline__ void gemm_core(
    const unsigned short* __restrict__ A, int lda,
    const unsigned short* __restrict__ B, int ldb,
    long m0, long n0, int K,
    unsigned short* As, unsigned short* Bs,
    f32x4 (&acc)[FM][FN])
{
    const int tid  = threadIdx.x;
    const int lane = tid & 63;
    const int wave = tid >> 6;
    const int wm = wave / WGN;
    const int wn = wave % WGN;
    const int srow = lane >> 2;
    const int scol = (lane & 3) * 8;
    const int frow = lane & 15;
    const int fcol = (lane >> 4) * 8;

    for (int k0 = 0; k0 < K; k0 += 32) {
        __syncthreads();
        for (int c = wave; c < BM / 16; c += 4) {
            const unsigned short* g = A + (m0 + c * 16 + srow) * (long)lda + k0 + scol;
            GLD16(g, As + c * 512);
        }
        for (int c = wave; c < BN / 16; c += 4) {
            const unsigned short* g = B + (n0 + c * 16 + srow) * (long)ldb + k0 + scol;
            GLD16(g, Bs + c * 512);
        }
        __syncthreads();
        bf16x8 af[FM], bfr[FN];
#pragma unroll
        for (int m = 0; m < FM; ++m)
            af[m] = *(const bf16x8*)(As + ((wm * FM + m) * 16 + frow) * 32 + fcol);
#pragma unroll
        for (int n = 0; n < FN; ++n)
            bfr[n] = *(const bf16x8*)(Bs + ((wn * FN + n) * 16 + frow) * 32 + fcol);
#pragma unroll
        for (int m = 0; m < FM; ++m)
#pragma unroll
            for (int n = 0; n < FN; ++n)
                acc[m][n] = __builtin_amdgcn_mfma_f32_16x16x32_bf16(af[m], bfr[n], acc[m][n], 0, 0, 0);
    }
}

template<int BM, int BN, int WGM, int WGN, int FM, int FN, int MODE>
__global__ __launch_bounds__(256) void k_gemm(
    const unsigned short* __restrict__ A, int lda,
    const unsigned short* __restrict__ B, int ldb,
    float* __restrict__ C, long ldc, const float* __restrict__ bias,
    int M, int N, int K, int Mreal)
{
    __shared__ __align__(16) unsigned short As[BM * 32];
    __shared__ __align__(16) unsigned short Bs[BN * 32];
    long m0 = (long)blockIdx.y * BM;
    long n0 = (long)blockIdx.x * BN;
    f32x4 acc[FM][FN] = {};
    gemm_core<BM, BN, WGM, WGN, FM, FN>(A, lda, B, ldb, m0, n0, K, As, Bs, acc);

    const int lane = threadIdx.x & 63;
    const int wave = threadIdx.x >> 6;
    const int wm = wave / WGN, wn = wave % WGN;
#pragma unroll
    for (int n = 0; n < FN; ++n) {
        long col = n0 + wn * FN * 16 + n * 16 + (lane & 15);
        float bv = bias ? bias[col] : 0.0f;
#pragma unroll
        for (int m = 0; m < FM; ++m) {
            int rl = wm * FM * 16 + m * 16 + (lane >> 4) * 4;
#pragma unroll
            for (int q = 0; q < 4; ++q) {
                long r = m0 + rl + q;
                float val = acc[m][n][q] + bv;
                if (MODE == 0) {
                    C[r * ldc + col] = val;
                } else {
                    if (r < Mreal) {
                        long orow = (r & 63) * 32 + (r >> 6) + 1;
                        C[orow * ldc + col] = val;
                    }
                }
            }
        }
    }
}

// ---------- persistent encoder: per-step h slots, plain cached A loads ----------
__global__ __launch_bounds__(1024, 4) void k_enc(
    const unsigned short* __restrict__ W,    // weWhh 4096x1024 gate-interleaved
    const float* __restrict__ pre,           // [64][64][4096]
    unsigned short* __restrict__ hsl,        // 65 slots x [64][1024] bf16 (slot0 zeroed)
    unsigned short* __restrict__ enc_out,    // [b*64+t][1024]
    unsigned short* __restrict__ eoT,        // [b][h][t]
    unsigned short* __restrict__ hS0,        // decoder h slot 0 (h_f)
    float* __restrict__ cspill,
    int* slots, int* gen)
{
    __shared__ float gs[64 * 64];
    const int blk = blockIdx.x, tid = threadIdx.x;
    const int lane = tid & 63, wave = tid >> 6;
    const int rowg = wave >> 2, kq = wave & 3;
    const int n0 = blk * 64, j0 = blk * 16;
    const int arow = rowg * 16 + (lane & 15);
    const int kch = (lane >> 4) * 8;
    float creg0 = 0.f, creg1 = 0.f;
    const int pb = tid >> 3, pj = (tid & 7) * 2;
    const int gb = tid >> 4, gc4 = (tid & 15) * 4;
    const unsigned short* Bb[4];
#pragma unroll
    for (int nt = 0; nt < 4; ++nt)
        Bb[nt] = W + (long)(n0 + nt * 16 + (lane & 15)) * 1024 + kq * 256 + kch;
    float4 preg = *(const float4*)(pre + (long)gb * 4096 + n0 + gc4);
    int bt = 0;
    for (int t = 0; t < 64; ++t) {
        *(float4*)(gs + gb * 64 + gc4) = preg;
        if (t < 63)   // prefetch next step's pre slice (hidden under whole step)
            preg = *(const float4*)(pre + (long)(t + 1) * 64 * 4096 + (long)gb * 4096 + n0 + gc4);
        __syncthreads();
        f32x4 acc[4] = {};
        sgemmN<4>(hsl + (long)t * 65536 + (long)arow * 1024 + kq * 256 + kch, Bb, 0, acc);
#pragma unroll
        for (int nt = 0; nt < 4; ++nt)
#pragma unroll
            for (int q = 0; q < 4; ++q)
                atomicAdd(&gs[(rowg * 16 + (lane >> 4) * 4 + q) * 64 + nt * 16 + (lane & 15)],
                          acc[nt][q]);
        __syncthreads();
        if (tid < 512) {
            float4 gA = *(const float4*)(gs + pb * 64 + pj * 4);
            float4 gB = *(const float4*)(gs + pb * 64 + pj * 4 + 4);
            float h0v, h1v;
            {
                float i_ = 1.f / (1.f + __expf(-gA.x)), f_ = 1.f / (1.f + __expf(-gA.y));
                float g_ = tanhfast(gA.z), o_ = 1.f / (1.f + __expf(-gA.w));
                creg0 = f_ * creg0 + i_ * g_; h0v = o_ * tanhfast(creg0);
            }
            {
                float i_ = 1.f / (1.f + __expf(-gB.x)), f_ = 1.f / (1.f + __expf(-gB.y));
                float g_ = tanhfast(gB.z), o_ = 1.f / (1.f + __expf(-gB.w));
                creg1 = f_ * creg1 + i_ * g_; h1v = o_ * tanhfast(creg1);
            }
            unsigned short hb0 = f2b(h0v), hb1 = f2b(h1v);
            unsigned pk = (unsigned)hb0 | ((unsigned)hb1 << 16);
            stU((unsigned*)(hsl + (long)(t + 1) * 65536 + (long)pb * 1024 + j0 + pj), pk);
            *(unsigned*)(enc_out + ((long)pb * 64 + t) * 1024 + j0 + pj) = pk;
            eoT[(long)pb * 65536 + (long)(j0 + pj) * 64 + t] = hb0;
            eoT[(long)pb * 65536 + (long)(j0 + pj + 1) * 64 + t] = hb1;
            if (t == 63) {
                *(unsigned*)(hS0 + (long)pb * 1024 + j0 + pj) = pk;
                cspill[(long)pb * 1024 + j0 + pj]     = creg0;
                cspill[(long)pb * 1024 + j0 + pj + 1] = creg1;
            }
        }
        gbar(slots, gen, ++bt);
    }
}

// ---------- persistent decoder: per-step slots for h/ctx/q ----------
__global__ __launch_bounds__(1024, 4) void k_dec(
    const unsigned short* __restrict__ Wh,   // 1024x1024
    const unsigned short* __restrict__ Wc,   // 4096x2048 gate-interleaved
    const float* __restrict__ pre,           // [31][64][4096]
    const float* __restrict__ proj,          // [b*64+s][1024] f32 (attn_b folded)
    const unsigned short* __restrict__ eoT,  // [b][h][s]
    const float* __restrict__ v,
    const float* __restrict__ cspill,
    unsigned short* __restrict__ hS,         // 32 slots x [64][1024] bf16 (slot0 = h_f)
    unsigned short* __restrict__ ctxS,       // 32 slots x [64][1024] bf16
    float* __restrict__ qS,                  // 32 slots x [64][1024] f32
    unsigned short* __restrict__ fcin,       // (t*64+b) x 2048
    int* slots, int* gen)
{
    __shared__ _Float16 projs[64 * 1024];    // 128 KB
    __shared__ float gs[64 * 64];            // 16 KB
    __shared__ float vv[1024];
    __shared__ float qv[1024];
    __shared__ float sc[64], al[64];
    const int blk = blockIdx.x, tid = threadIdx.x;
    const int lane = tid & 63, wave = tid >> 6;
    const int rowg = wave >> 2, kq = wave & 3;
    const int n0 = blk * 64, j0 = blk * 16, q0 = blk * 16;
    const int arow = rowg * 16 + (lane & 15);
    const int kch = (lane >> 4) * 8;
    const int pb = tid >> 3, pj = (tid & 7) * 2;
    const int gb = tid >> 4, gc4 = (tid & 15) * 4;
    for (int i4 = tid; i4 < 16384; i4 += 1024) {
        int s = i4 >> 8, h4 = (i4 & 255) * 4;
        float4 w4 = *(const float4*)(proj + ((long)blk * 64 + s) * 1024 + h4);
        h16x2 p0 = { (_Float16)w4.x, (_Float16)w4.y };
        h16x2 p1 = { (_Float16)w4.z, (_Float16)w4.w };
        *(h16x2*)(projs + s * 1024 + h4)     = p0;
        *(h16x2*)(projs + s * 1024 + h4 + 2) = p1;
    }
    if (tid < 1024) vv[tid] = v[tid];
    float creg0 = 0.f, creg1 = 0.f;
    if (tid < 512) {
        creg0 = cspill[(long)pb * 1024 + j0 + pj];
        creg1 = cspill[(long)pb * 1024 + j0 + pj + 1];
    }
    const unsigned short* Bq[1] = { Wh + (long)(q0 + (lane & 15)) * 1024 + kq * 256 + kch };
    const unsigned short* Bc[4];
#pragma unroll
    for (int nt = 0; nt < 4; ++nt)
        Bc[nt] = Wc + (long)(n0 + nt * 16 + (lane & 15)) * 2048 + kq * 512 + kch;
    __syncthreads();
    int bt = 0;
    for (int t = 0; t < 31; ++t) {
        const unsigned short* hSt   = hS   + (long)t * 65536;
        const unsigned short* ctxSt = ctxS + (long)t * 65536;
        // ---- phase 1: q[:, q0:q0+16] = h_t @ Wh^T  (+ prefetch pre[t] slice)
        float4 preg = *(const float4*)(pre + (long)t * 64 * 4096 + (long)gb * 4096 + n0 + gc4);
        {
            gs[tid] = 0.f;
            __syncthreads();
            f32x4 qa[1] = {};
            sgemmN<1>(hSt + (long)arow * 1024 + kq * 256 + kch, Bq, 0, qa);
#pragma unroll
            for (int q = 0; q < 4; ++q)
                atomicAdd(&gs[(rowg * 16 + (lane >> 4) * 4 + q) * 16 + (lane & 15)], qa[0][q]);
            __syncthreads();
            stF(qS + (long)t * 65536 + (long)(tid >> 4) * 1024 + q0 + (tid & 15), gs[tid]);
        }
        gbar(slots, gen, ++bt);
        // ---- phase 2: attention for b = blk
        {
            const int b = blk;
            qv[tid] = qS[(long)t * 65536 + (long)b * 1024 + tid];
            __syncthreads();
            int s = tid >> 4, part = tid & 15;
            const h16x2* pj2 = (const h16x2*)(projs + s * 1024);
            float a_ = 0.f;
            int base = part * 32;
#pragma unroll 8
            for (int d = 0; d < 32; ++d) {
                int dd = (d + lane) & 31;
                h16x2 pv = pj2[base + dd];
                int h = part * 64 + dd * 2;
                float2 q2 = *(const float2*)(qv + h);
                float2 v2 = *(const float2*)(vv + h);
                a_ += v2.x * tanhfast(q2.x + (float)pv[0]);
                a_ += v2.y * tanhfast(q2.y + (float)pv[1]);
            }
            a_ += __shfl_xor(a_, 1);
            a_ += __shfl_xor(a_, 2);
            a_ += __shfl_xor(a_, 4);
            a_ += __shfl_xor(a_, 8);
            if (part == 0) sc[s] = a_;
            __syncthreads();
            if (tid < 64) {
                float x = sc[tid], mx = x;
                for (int o = 32; o; o >>= 1) mx = fmaxf(mx, __shfl_xor(mx, o));
                float e = __expf(x - mx), su = e;
                for (int o = 32; o; o >>= 1) su += __shfl_xor(su, o);
                al[tid] = e / su;
            }
            __syncthreads();
            if (tid < 512) {
                float cacc[2];
#pragma unroll
                for (int r = 0; r < 2; ++r) {
                    const bf16x8* pp = (const bf16x8*)(eoT + (long)b * 65536 + (long)(tid * 2 + r) * 64);
                    float sacc = 0.f;
#pragma unroll
                    for (int c8 = 0; c8 < 8; ++c8) {
                        bf16x8 v8 = pp[c8];
#pragma unroll
                        for (int jj = 0; jj < 8; ++jj)
                            sacc += al[c8 * 8 + jj] * (float)v8[jj];
                    }
                    cacc[r] = sacc;
                }
                unsigned pk = (unsigned)f2b(cacc[0]) | ((unsigned)f2b(cacc[1]) << 16);
                int hh = tid * 2;
                stU((unsigned*)(ctxS + (long)t * 65536 + (long)b * 1024 + hh), pk);
                *(unsigned*)(fcin + ((long)t * 64 + b) * 2048 + 1024 + hh) = pk;
            }
        }
        gbar(slots, gen, ++bt);
        // ---- phase 3: gates = [h_t | ctx_t] @ Wc^T + pre; LSTM pointwise
        {
            *(float4*)(gs + gb * 64 + gc4) = preg;
            __syncthreads();
            f32x4 acc[4] = {};
            const unsigned short* Ab =
                (kq < 2 ? hSt : ctxSt) + (long)arow * 1024 + (kq & 1) * 512 + kch;
            sgemmN<4>(Ab, Bc, 0, acc);
            sgemmN<4>(Ab, Bc, 8, acc);
#pragma unroll
            for (int nt = 0; nt < 4; ++nt)
#pragma unroll
                for (int q = 0; q < 4; ++q)
                    atomicAdd(&gs[(rowg * 16 + (lane >> 4) * 4 + q) * 64 + nt * 16 + (lane & 15)],
                              acc[nt][q]);
            __syncthreads();
            if (tid < 512) {
                float4 gA = *(const float4*)(gs + pb * 64 + pj * 4);
                float4 gB = *(const float4*)(gs + pb * 64 + pj * 4 + 4);
                float h0v, h1v;
                {
                    float i_ = 1.f / (1.f + __expf(-gA.x)), f_ = 1.f / (1.f + __expf(-gA.y));
                    float g_ = tanhfast(gA.z), o_ = 1.f / (1.f + __expf(-gA.w));
                    creg0 = f_ * creg0 + i_ * g_; h0v = o_ * tanhfast(creg0);
                }
                {
                    float i_ = 1.f / (1.f + __expf(-gB.x)), f_ = 1.f / (1.f + __expf(-gB.y));
                    float g_ = tanhfast(gB.z), o_ = 1.f / (1.f + __expf(-gB.w));
                    creg1 = f_ * creg1 + i_ * g_; h1v = o_ * tanhfast(creg1);
                }
                unsigned pk = (unsigned)f2b(h0v) | ((unsigned)f2b(h1v) << 16);
                stU((unsigned*)(hS + (long)(t + 1) * 65536 + (long)pb * 1024 + j0 + pj), pk);
                *(unsigned*)(fcin + ((long)t * 64 + pb) * 2048 + j0 + pj) = pk;
            }
        }
        gbar(slots, gen, ++bt);
    }
}

// ---------- launch ----------
extern "C" void kernel_launch(void* const* d_in, const int* in_sizes, int n_in,
                              void* d_out, int out_size, void* d_ws, size_t ws_size,
                              hipStream_t stream) {
    const int*   src     = (const int*)d_in[0];
    const int*   tgt     = (const int*)d_in[1];
    const float* enc_emb = (const float*)d_in[2];
    const float* dec_emb = (const float*)d_in[3];
    const float* enc_Wih = (const float*)d_in[4];
    const float* enc_Whh = (const float*)d_in[5];
    const float* enc_bih = (const float*)d_in[6];
    const float* enc_bhh = (const float*)d_in[7];
    const float* dec_Wih = (const float*)d_in[8];
    const float* dec_Whh = (const float*)d_in[9];
    const float* dec_bih = (const float*)d_in[10];
    const float* dec_bhh = (const float*)d_in[11];
    const float* attn_W  = (const float*)d_in[12];
    const float* attn_b  = (const float*)d_in[13];
    const float* vvec    = (const float*)d_in[14];
    const float* fc_W    = (const float*)d_in[15];
    const float* fc_b    = (const float*)d_in[16];
    float* out = (float*)d_out;

    char* ws = (char*)d_ws;
    size_t off = 0;
    auto alloc = [&](size_t bytes) -> char* {
        off = (off + 255) & ~(size_t)255;
        char* p = ws + off; off += bytes; return p;
    };
    unsigned short* wX      = (unsigned short*)alloc(4096UL * 512 * 2);
    unsigned short* weWih   = (unsigned short*)alloc(4096UL * 512 * 2);
    unsigned short* weWhh   = (unsigned short*)alloc(4096UL * 1024 * 2);
    float*          ebias   = (float*)alloc(4096UL * 4);
    float*          pre_enc = (float*)alloc(4096UL * 4096 * 4);
    unsigned short* enc_out = (unsigned short*)alloc(4096UL * 1024 * 2);
    unsigned short* eoT     = (unsigned short*)alloc(64UL * 1024 * 64 * 2);
    unsigned short* wWe     = (unsigned short*)alloc(1024UL * 1024 * 2);
    unsigned short* wWh     = (unsigned short*)alloc(1024UL * 1024 * 2);
    float*          proj    = (float*)alloc(4096UL * 1024 * 4);
    float*          cbuf    = (float*)alloc(64UL * 1024 * 4);
    unsigned short* demb    = (unsigned short*)alloc(2048UL * 512 * 2);
    unsigned short* wDemb   = (unsigned short*)alloc(4096UL * 512 * 2);
    unsigned short* wCat    = (unsigned short*)alloc(4096UL * 2048 * 2);
    float*          dbias   = (float*)alloc(4096UL * 4);
    float*          pre_dec = (float*)alloc(2048UL * 4096 * 4);
    unsigned short* fcin    = (unsigned short*)alloc(2048UL * 2048 * 2);
    unsigned short* wFc     = (unsigned short*)alloc(32000UL * 2048 * 2);
    unsigned short* hslE    = (unsigned short*)alloc(65UL * 65536 * 2);   // enc h slots
    unsigned short* hS      = (unsigned short*)alloc(32UL * 65536 * 2);   // dec h slots
    unsigned short* ctxS    = (unsigned short*)alloc(32UL * 65536 * 2);   // dec ctx slots
    float*          qS      = (float*)alloc(32UL * 65536 * 4);            // dec q slots
    int*            bar     = (int*)alloc(16384);
    (void)ws_size; (void)in_sizes; (void)n_in; (void)out_size;

    int* slotsE = bar;           // 64 slots x 64B
    int* genE   = bar + 1024;
    int* slotsD = bar + 2048;
    int* genD   = bar + 3072;

    hipMemsetAsync(bar, 0, 16384, stream);
    hipMemsetAsync(hslE, 0, 65536UL * 2, stream);   // enc h slot 0 = zeros
    k_zero0<<<512, 256, 0, stream>>>(out);

    k_gather<<<2048, 256, 0, stream>>>(enc_emb, src, wX, 64, 64);
    k_gather<<<1024, 256, 0, stream>>>(dec_emb, tgt, demb, 31, 32);
    k_conv<<<2048, 256, 0, stream>>>(enc_Wih, weWih, 4096, 512, 512, 0, 512, 0, 1);
    k_conv<<<2048, 256, 0, stream>>>(enc_Whh, weWhh, 4096, 1024, 1024, 0, 1024, 0, 1);
    k_conv<<<2048, 256, 0, stream>>>(dec_Wih, wDemb, 4096, 512, 1536, 0, 512, 0, 1);
    k_conv<<<2048, 256, 0, stream>>>(dec_Whh, wCat, 4096, 1024, 1024, 0, 2048, 0, 1);
    k_conv<<<2048, 256, 0, stream>>>(dec_Wih, wCat, 4096, 1024, 1536, 512, 2048, 1024, 1);
    k_conv<<<2048, 256, 0, stream>>>(attn_W, wWh, 1024, 1024, 2048, 0, 1024, 0, 0);
    k_conv<<<2048, 256, 0, stream>>>(attn_W, wWe, 1024, 1024, 2048, 1024, 1024, 0, 0);
    k_conv<<<4096, 256, 0, stream>>>(fc_W, wFc, 32000, 2048, 2048, 0, 2048, 0, 0);
    k_bias<<<16, 256, 0, stream>>>(enc_bih, enc_bhh, ebias);
    k_bias<<<16, 256, 0, stream>>>(dec_bih, dec_bhh, dbias);

    // pre-gates GEMMs
    k_gemm<128,128,2,2,4,4,0><<<dim3(32, 32), 256, 0, stream>>>(
        wX, 512, weWih, 512, pre_enc, 4096, ebias, 4096, 4096, 512, 4096);
    k_gemm<128,128,2,2,4,4,0><<<dim3(32, 16), 256, 0, stream>>>(
        demb, 512, wDemb, 512, pre_dec, 4096, dbias, 2048, 4096, 512, 2048);

    // persistent encoder
    k_enc<<<NBLK, 1024, 0, stream>>>(weWhh, pre_enc, hslE, enc_out, eoT,
                                     hS, cbuf, slotsE, genE);

    // enc_proj (+attn_b)
    k_gemm<128,128,2,2,4,4,0><<<dim3(8, 32), 256, 0, stream>>>(
        enc_out, 1024, wWe, 1024, proj, 1024, attn_b, 4096, 1024, 1024, 4096);

    // persistent decoder
    k_dec<<<NBLK, 1024, 0, stream>>>(wWh, wCat, pre_dec, proj, eoT, vvec, cbuf,
                                     hS, ctxS, qS, fcin, slotsD, genD);

    // batched fc GEMM -> out (remapped rows), rows b*32 zeroed by k_zero0
    k_gemm<128,128,2,2,4,4,1><<<dim3(250, 16), 256, 0, stream>>>(
        fcin, 2048, wFc, 2048, out, 32000, fc_b, 2048, 32000, 2048, 1984);
}

// Round 7
// 2821.557 us; speedup vs baseline: 2.1662x; 1.9365x over previous
//
#include <hip/hip_runtime.h>
#include <hip/hip_bf16.h>

// ---------- types / helpers ----------
typedef __bf16 bf16x8 __attribute__((ext_vector_type(8)));
typedef float  f32x4  __attribute__((ext_vector_type(4)));
typedef _Float16 h16x8 __attribute__((ext_vector_type(8)));

__device__ __forceinline__ unsigned short f2b(float f) {
    union { float f; unsigned u; } w; w.f = f;
    unsigned u = w.u + 0x7FFF + ((w.u >> 16) & 1);
    return (unsigned short)(u >> 16);
}
__device__ __forceinline__ float tanhfast(float x) {
    float e = __expf(2.0f * x);
    return 1.0f - 2.0f / (e + 1.0f);
}

// system-scope (cross-XCD write-through) stores for per-step state slots;
// readers use plain cached loads (fresh-slot discipline:每 slot written once,
// reader CU never touched the address before -> no stale line possible).
__device__ __forceinline__ void stU(unsigned* p, unsigned v) {
    __hip_atomic_store(p, v, __ATOMIC_RELAXED, __HIP_MEMORY_SCOPE_SYSTEM);
}
__device__ __forceinline__ void stF(float* p, float v) {
    __hip_atomic_store(p, v, __ATOMIC_RELAXED, __HIP_MEMORY_SCOPE_SYSTEM);
}
__device__ __forceinline__ int ldI(const int* p) {
    return __hip_atomic_load((int*)p, __ATOMIC_RELAXED, __HIP_MEMORY_SCOPE_SYSTEM);
}
__device__ __forceinline__ void stI(int* p, int v) {
    __hip_atomic_store(p, v, __ATOMIC_RELAXED, __HIP_MEMORY_SCOPE_SYSTEM);
}

#define GLD16(g, l) __builtin_amdgcn_global_load_lds( \
    (const __attribute__((address_space(1))) void*)(g), \
    (__attribute__((address_space(3))) void*)(l), 16, 0, 0)

#define SLOT_STRIDE 16   // ints -> 64B per slot

// contention-free tree grid barrier for 256 blocks x 256 threads:
// arrive: each block stores epoch to its own padded slot; block 0: thread i
// polls slot i; release via gen word.
__device__ __forceinline__ void gbar(int* slots, int* gen, int target) {
    asm volatile("s_waitcnt vmcnt(0)" ::: "memory");
    __syncthreads();
    if (blockIdx.x == 0) {
        if (threadIdx.x == 0) stI(slots, target);
        while (ldI(slots + threadIdx.x * SLOT_STRIDE) < target)
            __builtin_amdgcn_s_sleep(1);
        __syncthreads();
        if (threadIdx.x == 0) stI(gen, target);
    } else {
        if (threadIdx.x == 0) {
            stI(slots + blockIdx.x * SLOT_STRIDE, target);
            while (ldI(gen) < target)
                __builtin_amdgcn_s_sleep(1);
        }
        __syncthreads();
    }
}

// 8 K-chunks (256 K elems) of MFMA: per-wave full-K row-tile, no reduction
__device__ __forceinline__ void mac8(const unsigned short* A, const unsigned short* B,
                                     f32x4& acc) {
    bf16x8 a[8], b[8];
#pragma unroll
    for (int kk = 0; kk < 8; ++kk) {
        a[kk] = *(const bf16x8*)(A + kk * 32);
        b[kk] = *(const bf16x8*)(B + kk * 32);
    }
#pragma unroll
    for (int kk = 0; kk < 8; ++kk)
        acc = __builtin_amdgcn_mfma_f32_16x16x32_bf16(a[kk], b[kk], acc, 0, 0, 0);
}

// ---------- elementwise / conversion kernels ----------

__global__ void k_gather(const float* __restrict__ emb, const int* __restrict__ tok,
                         unsigned short* __restrict__ out, int L, int ldtok) {
    long total = (long)L * 64 * 128;
    for (long i = (long)blockIdx.x * blockDim.x + threadIdx.x; i < total;
         i += (long)gridDim.x * blockDim.x) {
        int  e4 = (int)(i & 127);
        long r  = i >> 7;
        int  t  = (int)(r >> 6), b = (int)(r & 63);
        int  tk = tok[b * ldtok + t];
        float4 v = *(const float4*)(emb + (long)tk * 512 + e4 * 4);
        ushort4 o; o.x = f2b(v.x); o.y = f2b(v.y); o.z = f2b(v.z); o.w = f2b(v.w);
        *(ushort4*)(out + r * 512 + e4 * 4) = o;
    }
}

__global__ void k_conv(const float* __restrict__ in, unsigned short* __restrict__ out,
                       long N_, int K_, int ldin, int col0, int ldout, int outcol0, int reorder) {
    long total = N_ * (K_ >> 2);
    int kq = K_ >> 2;
    for (long i = (long)blockIdx.x * blockDim.x + threadIdx.x; i < total;
         i += (long)gridDim.x * blockDim.x) {
        long n = i / kq;
        int  k4 = (int)(i - n * kq) * 4;
        long row = reorder ? (long)((n & 3) * 1024 + (n >> 2)) : n;
        float4 v = *(const float4*)(in + row * ldin + col0 + k4);
        ushort4 o; o.x = f2b(v.x); o.y = f2b(v.y); o.z = f2b(v.z); o.w = f2b(v.w);
        *(ushort4*)(out + n * ldout + outcol0 + k4) = o;
    }
}

__global__ void k_bias(const float* __restrict__ b1, const float* __restrict__ b2,
                       float* __restrict__ out) {
    int n = blockIdx.x * blockDim.x + threadIdx.x;
    if (n < 4096) {
        int row = (n & 3) * 1024 + (n >> 2);
        out[n] = b1[row] + b2[row];
    }
}

__global__ void k_zero0(float* __restrict__ out) {
    long total = 64L * 8000;
    for (long i = (long)blockIdx.x * blockDim.x + threadIdx.x; i < total;
         i += (long)gridDim.x * blockDim.x) {
        int b = (int)(i / 8000), q = (int)(i % 8000);
        float4 z = {0.f, 0.f, 0.f, 0.f};
        *(float4*)(out + (long)b * 1024000 + q * 4) = z;
    }
}

// ---------- big-GEMM (prep + fc), m97 structure ----------
template<int BM, int BN, int WGM, int WGN, int FM, int FN>
__device__ __forceinline__ void gemm_core(
    const unsigned short* __restrict__ A, int lda,
    const unsigned short* __restrict__ B, int ldb,
    long m0, long n0, int K,
    unsigned short* As, unsigned short* Bs,
    f32x4 (&acc)[FM][FN])
{
    const int tid  = threadIdx.x;
    const int lane = tid & 63;
    const int wave = tid >> 6;
    const int wm = wave / WGN;
    const int wn = wave % WGN;
    const int srow = lane >> 2;
    const int scol = (lane & 3) * 8;
    const int frow = lane & 15;
    const int fcol = (lane >> 4) * 8;

    for (int k0 = 0; k0 < K; k0 += 32) {
        __syncthreads();
        for (int c = wave; c < BM / 16; c += 4) {
            const unsigned short* g = A + (m0 + c * 16 + srow) * (long)lda + k0 + scol;
            GLD16(g, As + c * 512);
        }
        for (int c = wave; c < BN / 16; c += 4) {
            const unsigned short* g = B + (n0 + c * 16 + srow) * (long)ldb + k0 + scol;
            GLD16(g, Bs + c * 512);
        }
        __syncthreads();
        bf16x8 af[FM], bfr[FN];
#pragma unroll
        for (int m = 0; m < FM; ++m)
            af[m] = *(const bf16x8*)(As + ((wm * FM + m) * 16 + frow) * 32 + fcol);
#pragma unroll
        for (int n = 0; n < FN; ++n)
            bfr[n] = *(const bf16x8*)(Bs + ((wn * FN + n) * 16 + frow) * 32 + fcol);
#pragma unroll
        for (int m = 0; m < FM; ++m)
#pragma unroll
            for (int n = 0; n < FN; ++n)
                acc[m][n] = __builtin_amdgcn_mfma_f32_16x16x32_bf16(af[m], bfr[n], acc[m][n], 0, 0, 0);
    }
}

// MODE 0: f32 out. MODE 1: fc row-remap. MODE 2: fp16 out.
template<int BM, int BN, int WGM, int WGN, int FM, int FN, int MODE>
__global__ __launch_bounds__(256) void k_gemm(
    const unsigned short* __restrict__ A, int lda,
    const unsigned short* __restrict__ B, int ldb,
    float* __restrict__ C, long ldc, const float* __restrict__ bias,
    int M, int N, int K, int Mreal)
{
    __shared__ __align__(16) unsigned short As[BM * 32];
    __shared__ __align__(16) unsigned short Bs[BN * 32];
    long m0 = (long)blockIdx.y * BM;
    long n0 = (long)blockIdx.x * BN;
    f32x4 acc[FM][FN] = {};
    gemm_core<BM, BN, WGM, WGN, FM, FN>(A, lda, B, ldb, m0, n0, K, As, Bs, acc);

    const int lane = threadIdx.x & 63;
    const int wave = threadIdx.x >> 6;
    const int wm = wave / WGN, wn = wave % WGN;
#pragma unroll
    for (int n = 0; n < FN; ++n) {
        long col = n0 + wn * FN * 16 + n * 16 + (lane & 15);
        float bv = bias ? bias[col] : 0.0f;
#pragma unroll
        for (int m = 0; m < FM; ++m) {
            int rl = wm * FM * 16 + m * 16 + (lane >> 4) * 4;
#pragma unroll
            for (int q = 0; q < 4; ++q) {
                long r = m0 + rl + q;
                float val = acc[m][n][q] + bv;
                if (MODE == 0) {
                    C[r * ldc + col] = val;
                } else if (MODE == 2) {
                    ((_Float16*)C)[r * ldc + col] = (_Float16)val;
                } else {
                    if (r < Mreal) {
                        long orow = (r & 63) * 32 + (r >> 6) + 1;
                        C[orow * ldc + col] = val;
                    }
                }
            }
        }
    }
}

// ---------- persistent encoder: 256 blocks x 256 threads, 1 barrier/step ----------
// block owns 16 gate-cols (n0 = blk*16); wave m owns rows m*16..+15 with FULL K.
__global__ __launch_bounds__(256) void k_enc(
    const unsigned short* __restrict__ W,    // weWhh 4096x1024 gate-interleaved
    const float* __restrict__ pre,           // [64][64][4096]
    unsigned short* __restrict__ hsl,        // 65 slots x [64][1024] (slot0 zeroed)
    unsigned short* __restrict__ enc_out,    // [b*64+t][1024]
    unsigned short* __restrict__ eoT,        // [b][h][t]
    unsigned short* __restrict__ hS0,        // dec h slot 0 (h_f)
    float* __restrict__ cspill,
    int* slots, int* gen)
{
    __shared__ float gs[64 * 16];
    const int blk = blockIdx.x, tid = threadIdx.x;
    const int lane = tid & 63, wave = tid >> 6;
    const int n0 = blk * 16;
    const int arow = wave * 16 + (lane & 15);
    const int kch = (lane >> 4) * 8;
    const unsigned short* Bw = W + (long)(n0 + (lane & 15)) * 1024 + kch;
    const int pb = tid >> 1, pjl = (tid & 1) * 2;    // active for tid<128
    const int jg = blk * 4 + pjl;
    float c0 = 0.f, c1 = 0.f;
    float4 pr0 = {}, pr1 = {};
    if (tid < 128) {
        pr0 = *(const float4*)(pre + (long)pb * 4096 + n0 + pjl * 4);
        pr1 = *(const float4*)(pre + (long)pb * 4096 + n0 + pjl * 4 + 4);
    }
    int bt = 0;
    for (int t = 0; t < 64; ++t) {
        const unsigned short* Ar = hsl + (long)t * 65536 + (long)arow * 1024 + kch;
        f32x4 acc = {};
        mac8(Ar, Bw, acc);
        mac8(Ar + 256, Bw + 256, acc);
        mac8(Ar + 512, Bw + 512, acc);
        mac8(Ar + 768, Bw + 768, acc);
#pragma unroll
        for (int q = 0; q < 4; ++q)
            gs[(wave * 16 + (lane >> 4) * 4 + q) * 16 + (lane & 15)] = acc[q];
        __syncthreads();
        if (tid < 128) {
            float4 gA = *(const float4*)(gs + pb * 16 + pjl * 4);
            float4 gB = *(const float4*)(gs + pb * 16 + pjl * 4 + 4);
            float h0v, h1v;
            {
                float gi = gA.x + pr0.x, gf = gA.y + pr0.y, gg = gA.z + pr0.z, go = gA.w + pr0.w;
                float i_ = 1.f / (1.f + __expf(-gi)), f_ = 1.f / (1.f + __expf(-gf));
                float g_ = tanhfast(gg), o_ = 1.f / (1.f + __expf(-go));
                c0 = f_ * c0 + i_ * g_; h0v = o_ * tanhfast(c0);
            }
            {
                float gi = gB.x + pr1.x, gf = gB.y + pr1.y, gg = gB.z + pr1.z, go = gB.w + pr1.w;
                float i_ = 1.f / (1.f + __expf(-gi)), f_ = 1.f / (1.f + __expf(-gf));
                float g_ = tanhfast(gg), o_ = 1.f / (1.f + __expf(-go));
                c1 = f_ * c1 + i_ * g_; h1v = o_ * tanhfast(c1);
            }
            unsigned short hb0 = f2b(h0v), hb1 = f2b(h1v);
            unsigned pk = (unsigned)hb0 | ((unsigned)hb1 << 16);
            stU((unsigned*)(hsl + (long)(t + 1) * 65536 + (long)pb * 1024 + jg), pk);
            *(unsigned*)(enc_out + ((long)pb * 64 + t) * 1024 + jg) = pk;
            eoT[((long)pb * 1024 + jg) * 64 + t]     = hb0;
            eoT[((long)pb * 1024 + jg + 1) * 64 + t] = hb1;
            if (t < 63) {
                pr0 = *(const float4*)(pre + (long)(t + 1) * 262144 + (long)pb * 4096 + n0 + pjl * 4);
                pr1 = *(const float4*)(pre + (long)(t + 1) * 262144 + (long)pb * 4096 + n0 + pjl * 4 + 4);
            } else {
                *(unsigned*)(hS0 + (long)pb * 1024 + jg) = pk;
                cspill[(long)pb * 1024 + jg]     = c0;
                cspill[(long)pb * 1024 + jg + 1] = c1;
            }
        }
        gbar(slots, gen, ++bt);
    }
}

// ---------- persistent decoder: 256 blocks x 256 threads, 3 phases/step ----------
__global__ __launch_bounds__(256) void k_dec(
    const unsigned short* __restrict__ Wh,   // 1024x1024
    const unsigned short* __restrict__ Wc,   // 4096x2048 gate-interleaved
    const float* __restrict__ pre,           // [31][64][4096]
    const _Float16* __restrict__ proj16,     // [b*64+s][1024] fp16 (attn_b folded)
    const unsigned short* __restrict__ eoT,  // [b][h][t]
    const float* __restrict__ v,
    const float* __restrict__ cspill,
    unsigned short* __restrict__ hS,         // 32 slots x [64][1024] (slot0 = h_f)
    unsigned short* __restrict__ ctxS,       // 32 slots x [64][1024]
    float* __restrict__ qS,                  // 32 slots x [64][1024] f32
    unsigned short* __restrict__ fcin,       // (t*64+b) x 2048
    int* slots, int* gen)
{
    __shared__ float gs[64 * 16];
    __shared__ float qv[1024], vv[1024];
    __shared__ float sc[64], al[64];
    const int blk = blockIdx.x, tid = threadIdx.x;
    const int lane = tid & 63, wave = tid >> 6;
    const int n0 = blk * 16;
    const int arow = wave * 16 + (lane & 15);
    const int kch = (lane >> 4) * 8;
    const int pb = tid >> 1, pjl = (tid & 1) * 2;
    const int jg = blk * 4 + pjl;
    {
        float4 v4 = *(const float4*)(v + tid * 4);
        *(float4*)(vv + tid * 4) = v4;
    }
    float c0 = 0.f, c1 = 0.f;
    if (tid < 128) {
        c0 = cspill[(long)pb * 1024 + jg];
        c1 = cspill[(long)pb * 1024 + jg + 1];
    }
    __syncthreads();
    int bt = 0;
    for (int t = 0; t < 31; ++t) {
        const unsigned short* hSt   = hS   + (long)t * 65536;
        const unsigned short* ctxSt = ctxS + (long)t * 65536;
        float4 pr0 = {}, pr1 = {};
        if (tid < 128) {
            pr0 = *(const float4*)(pre + (long)t * 262144 + (long)pb * 4096 + n0 + pjl * 4);
            pr1 = *(const float4*)(pre + (long)t * 262144 + (long)pb * 4096 + n0 + pjl * 4 + 4);
        }
        // ---- phase 1: q cols (blocks 0..63: 16 cols each)
        if (blk < 64) {
            const unsigned short* Ar = hSt + (long)arow * 1024 + kch;
            const unsigned short* Bq = Wh + (long)(blk * 16 + (lane & 15)) * 1024 + kch;
            f32x4 qa = {};
            mac8(Ar, Bq, qa);
            mac8(Ar + 256, Bq + 256, qa);
            mac8(Ar + 512, Bq + 512, qa);
            mac8(Ar + 768, Bq + 768, qa);
#pragma unroll
            for (int q = 0; q < 4; ++q)
                gs[(wave * 16 + (lane >> 4) * 4 + q) * 16 + (lane & 15)] = qa[q];
            __syncthreads();
            int b = tid >> 2, cl = (tid & 3) * 4;
            float* qd = qS + (long)t * 65536 + (long)b * 1024 + blk * 16 + cl;
#pragma unroll
            for (int g = 0; g < 4; ++g) stF(qd + g, gs[b * 16 + cl + g]);
        }
        gbar(slots, gen, ++bt);
        // ---- phase 2: attention (blocks 0..63: b = blk)
        if (blk < 64) {
            const int b = blk;
            *(float4*)(qv + tid * 4) = *(const float4*)(qS + (long)t * 65536 + (long)b * 1024 + tid * 4);
            __syncthreads();
            int s = tid >> 2, part = tid & 3;
            const h16x8* pp = (const h16x8*)(proj16 + ((long)b * 64 + s) * 1024 + part * 256);
            float a_ = 0.f;
#pragma unroll 4
            for (int d = 0; d < 32; ++d) {
                h16x8 pv = pp[d];
                int h = part * 256 + d * 8;
#pragma unroll
                for (int j = 0; j < 8; ++j)
                    a_ += vv[h + j] * tanhfast(qv[h + j] + (float)pv[j]);
            }
            a_ += __shfl_xor(a_, 1);
            a_ += __shfl_xor(a_, 2);
            if (part == 0) sc[s] = a_;
            __syncthreads();
            if (tid < 64) {
                float x = sc[tid], mx = x;
                for (int o = 32; o; o >>= 1) mx = fmaxf(mx, __shfl_xor(mx, o));
                float e = __expf(x - mx), su = e;
                for (int o = 32; o; o >>= 1) su += __shfl_xor(su, o);
                al[tid] = e / su;
            }
            __syncthreads();
            int h0 = tid * 4;
            float cacc[4];
#pragma unroll
            for (int r = 0; r < 4; ++r) {
                const bf16x8* ep = (const bf16x8*)(eoT + ((long)b * 1024 + h0 + r) * 64);
                float s_ = 0.f;
#pragma unroll
                for (int c8 = 0; c8 < 8; ++c8) {
                    bf16x8 v8 = ep[c8];
#pragma unroll
                    for (int jj = 0; jj < 8; ++jj)
                        s_ += al[c8 * 8 + jj] * (float)v8[jj];
                }
                cacc[r] = s_;
            }
            unsigned pk0 = (unsigned)f2b(cacc[0]) | ((unsigned)f2b(cacc[1]) << 16);
            unsigned pk1 = (unsigned)f2b(cacc[2]) | ((unsigned)f2b(cacc[3]) << 16);
            stU((unsigned*)(ctxS + (long)t * 65536 + (long)b * 1024 + h0), pk0);
            stU((unsigned*)(ctxS + (long)t * 65536 + (long)b * 1024 + h0 + 2), pk1);
            *(unsigned*)(fcin + ((long)t * 64 + b) * 2048 + 1024 + h0)     = pk0;
            *(unsigned*)(fcin + ((long)t * 64 + b) * 2048 + 1024 + h0 + 2) = pk1;
        }
        gbar(slots, gen, ++bt);
        // ---- phase 3: gates (all 256 blocks, 16 cols each, K=2048)
        {
            const unsigned short* Ah = hSt   + (long)arow * 1024 + kch;
            const unsigned short* Ac = ctxSt + (long)arow * 1024 + kch;
            const unsigned short* Bw = Wc + (long)(n0 + (lane & 15)) * 2048 + kch;
            f32x4 acc = {};
            mac8(Ah,       Bw,        acc);
            mac8(Ah + 256, Bw + 256,  acc);
            mac8(Ah + 512, Bw + 512,  acc);
            mac8(Ah + 768, Bw + 768,  acc);
            mac8(Ac,       Bw + 1024, acc);
            mac8(Ac + 256, Bw + 1280, acc);
            mac8(Ac + 512, Bw + 1536, acc);
            mac8(Ac + 768, Bw + 1792, acc);
#pragma unroll
            for (int q = 0; q < 4; ++q)
                gs[(wave * 16 + (lane >> 4) * 4 + q) * 16 + (lane & 15)] = acc[q];
            __syncthreads();
            if (tid < 128) {
                float4 gA = *(const float4*)(gs + pb * 16 + pjl * 4);
                float4 gB = *(const float4*)(gs + pb * 16 + pjl * 4 + 4);
                float h0v, h1v;
                {
                    float gi = gA.x + pr0.x, gf = gA.y + pr0.y, gg = gA.z + pr0.z, go = gA.w + pr0.w;
                    float i_ = 1.f / (1.f + __expf(-gi)), f_ = 1.f / (1.f + __expf(-gf));
                    float g_ = tanhfast(gg), o_ = 1.f / (1.f + __expf(-go));
                    c0 = f_ * c0 + i_ * g_; h0v = o_ * tanhfast(c0);
                }
                {
                    float gi = gB.x + pr1.x, gf = gB.y + pr1.y, gg = gB.z + pr1.z, go = gB.w + pr1.w;
                    float i_ = 1.f / (1.f + __expf(-gi)), f_ = 1.f / (1.f + __expf(-gf));
                    float g_ = tanhfast(gg), o_ = 1.f / (1.f + __expf(-go));
                    c1 = f_ * c1 + i_ * g_; h1v = o_ * tanhfast(c1);
                }
                unsigned pk = (unsigned)f2b(h0v) | ((unsigned)f2b(h1v) << 16);
                stU((unsigned*)(hS + (long)(t + 1) * 65536 + (long)pb * 1024 + jg), pk);
                *(unsigned*)(fcin + ((long)t * 64 + pb) * 2048 + jg) = pk;
            }
        }
        gbar(slots, gen, ++bt);
    }
}

// ---------- launch ----------
extern "C" void kernel_launch(void* const* d_in, const int* in_sizes, int n_in,
                              void* d_out, int out_size, void* d_ws, size_t ws_size,
                              hipStream_t stream) {
    const int*   src     = (const int*)d_in[0];
    const int*   tgt     = (const int*)d_in[1];
    const float* enc_emb = (const float*)d_in[2];
    const float* dec_emb = (const float*)d_in[3];
    const float* enc_Wih = (const float*)d_in[4];
    const float* enc_Whh = (const float*)d_in[5];
    const float* enc_bih = (const float*)d_in[6];
    const float* enc_bhh = (const float*)d_in[7];
    const float* dec_Wih = (const float*)d_in[8];
    const float* dec_Whh = (const float*)d_in[9];
    const float* dec_bih = (const float*)d_in[10];
    const float* dec_bhh = (const float*)d_in[11];
    const float* attn_W  = (const float*)d_in[12];
    const float* attn_b  = (const float*)d_in[13];
    const float* vvec    = (const float*)d_in[14];
    const float* fc_W    = (const float*)d_in[15];
    const float* fc_b    = (const float*)d_in[16];
    float* out = (float*)d_out;

    char* ws = (char*)d_ws;
    size_t off = 0;
    auto alloc = [&](size_t bytes) -> char* {
        off = (off + 255) & ~(size_t)255;
        char* p = ws + off; off += bytes; return p;
    };
    unsigned short* wX      = (unsigned short*)alloc(4096UL * 512 * 2);
    unsigned short* weWih   = (unsigned short*)alloc(4096UL * 512 * 2);
    unsigned short* weWhh   = (unsigned short*)alloc(4096UL * 1024 * 2);
    float*          ebias   = (float*)alloc(4096UL * 4);
    float*          pre_enc = (float*)alloc(4096UL * 4096 * 4);
    unsigned short* enc_out = (unsigned short*)alloc(4096UL * 1024 * 2);
    unsigned short* eoT     = (unsigned short*)alloc(64UL * 1024 * 64 * 2);
    unsigned short* wWe     = (unsigned short*)alloc(1024UL * 1024 * 2);
    unsigned short* wWh     = (unsigned short*)alloc(1024UL * 1024 * 2);
    _Float16*       proj16  = (_Float16*)alloc(4096UL * 1024 * 2);
    float*          cbuf    = (float*)alloc(64UL * 1024 * 4);
    unsigned short* demb    = (unsigned short*)alloc(2048UL * 512 * 2);
    unsigned short* wDemb   = (unsigned short*)alloc(4096UL * 512 * 2);
    unsigned short* wCat    = (unsigned short*)alloc(4096UL * 2048 * 2);
    float*          dbias   = (float*)alloc(4096UL * 4);
    float*          pre_dec = (float*)alloc(2048UL * 4096 * 4);
    unsigned short* fcin    = (unsigned short*)alloc(2048UL * 2048 * 2);
    unsigned short* wFc     = (unsigned short*)alloc(32000UL * 2048 * 2);
    unsigned short* hslE    = (unsigned short*)alloc(65UL * 65536 * 2);
    unsigned short* hS      = (unsigned short*)alloc(32UL * 65536 * 2);
    unsigned short* ctxS    = (unsigned short*)alloc(32UL * 65536 * 2);
    float*          qS      = (float*)alloc(32UL * 65536 * 4);
    int*            bar     = (int*)alloc(65536);
    (void)ws_size; (void)in_sizes; (void)n_in; (void)out_size;

    int* slotsE = bar;            // 256 slots x 64B
    int* genE   = bar + 4096;
    int* slotsD = bar + 8192;
    int* genD   = bar + 12288;

    hipMemsetAsync(bar, 0, 65536, stream);
    hipMemsetAsync(hslE, 0, 65536UL * 2, stream);   // enc h slot 0 = zeros
    k_zero0<<<512, 256, 0, stream>>>(out);

    k_gather<<<2048, 256, 0, stream>>>(enc_emb, src, wX, 64, 64);
    k_gather<<<1024, 256, 0, stream>>>(dec_emb, tgt, demb, 31, 32);
    k_conv<<<2048, 256, 0, stream>>>(enc_Wih, weWih, 4096, 512, 512, 0, 512, 0, 1);
    k_conv<<<2048, 256, 0, stream>>>(enc_Whh, weWhh, 4096, 1024, 1024, 0, 1024, 0, 1);
    k_conv<<<2048, 256, 0, stream>>>(dec_Wih, wDemb, 4096, 512, 1536, 0, 512, 0, 1);
    k_conv<<<2048, 256, 0, stream>>>(dec_Whh, wCat, 4096, 1024, 1024, 0, 2048, 0, 1);
    k_conv<<<2048, 256, 0, stream>>>(dec_Wih, wCat, 4096, 1024, 1536, 512, 2048, 1024, 1);
    k_conv<<<2048, 256, 0, stream>>>(attn_W, wWh, 1024, 1024, 2048, 0, 1024, 0, 0);
    k_conv<<<2048, 256, 0, stream>>>(attn_W, wWe, 1024, 1024, 2048, 1024, 1024, 0, 0);
    k_conv<<<4096, 256, 0, stream>>>(fc_W, wFc, 32000, 2048, 2048, 0, 2048, 0, 0);
    k_bias<<<16, 256, 0, stream>>>(enc_bih, enc_bhh, ebias);
    k_bias<<<16, 256, 0, stream>>>(dec_bih, dec_bhh, dbias);

    // pre-gates GEMMs
    k_gemm<128,128,2,2,4,4,0><<<dim3(32, 32), 256, 0, stream>>>(
        wX, 512, weWih, 512, pre_enc, 4096, ebias, 4096, 4096, 512, 4096);
    k_gemm<128,128,2,2,4,4,0><<<dim3(32, 16), 256, 0, stream>>>(
        demb, 512, wDemb, 512, pre_dec, 4096, dbias, 2048, 4096, 512, 2048);

    // persistent encoder (256 blocks, all CUs)
    k_enc<<<256, 256, 0, stream>>>(weWhh, pre_enc, hslE, enc_out, eoT,
                                   hS, cbuf, slotsE, genE);

    // enc_proj (+attn_b) -> fp16
    k_gemm<128,128,2,2,4,4,2><<<dim3(8, 32), 256, 0, stream>>>(
        enc_out, 1024, wWe, 1024, (float*)proj16, 1024, attn_b, 4096, 1024, 1024, 4096);

    // persistent decoder (256 blocks)
    k_dec<<<256, 256, 0, stream>>>(wWh, wCat, pre_dec, proj16, eoT, vvec, cbuf,
                                   hS, ctxS, qS, fcin, slotsD, genD);

    // batched fc GEMM -> out (remapped rows), rows b*32 zeroed by k_zero0
    k_gemm<128,128,2,2,4,4,1><<<dim3(250, 16), 256, 0, stream>>>(
        fcin, 2048, wFc, 2048, out, 32000, fc_b, 2048, 32000, 2048, 1984);
}

// Round 8
// 2680.024 us; speedup vs baseline: 2.2806x; 1.0528x over previous
//
#include <hip/hip_runtime.h>
#include <hip/hip_bf16.h>

// ---------- types / helpers ----------
typedef __bf16 bf16x8 __attribute__((ext_vector_type(8)));
typedef float  f32x4  __attribute__((ext_vector_type(4)));
typedef _Float16 h16x8 __attribute__((ext_vector_type(8)));

__device__ __forceinline__ unsigned short f2b(float f) {
    union { float f; unsigned u; } w; w.f = f;
    unsigned u = w.u + 0x7FFF + ((w.u >> 16) & 1);
    return (unsigned short)(u >> 16);
}
__device__ __forceinline__ float tanhfast(float x) {
    float e = __expf(2.0f * x);
    return 1.0f - 2.0f / (e + 1.0f);
}

// AGENT-scope (device/L3-coherent) write-through stores for per-step state;
// readers use plain cached loads (fresh-slot discipline: each slot written
// once, reader CU never touched the address -> its L2 cannot be stale).
__device__ __forceinline__ void stU(unsigned* p, unsigned v) {
    __hip_atomic_store(p, v, __ATOMIC_RELAXED, __HIP_MEMORY_SCOPE_AGENT);
}
__device__ __forceinline__ void stF(float* p, float v) {
    __hip_atomic_store(p, v, __ATOMIC_RELAXED, __HIP_MEMORY_SCOPE_AGENT);
}
__device__ __forceinline__ int ldI(const int* p) {
    return __hip_atomic_load((int*)p, __ATOMIC_RELAXED, __HIP_MEMORY_SCOPE_AGENT);
}
__device__ __forceinline__ void stI(int* p, int v) {
    __hip_atomic_store(p, v, __ATOMIC_RELAXED, __HIP_MEMORY_SCOPE_AGENT);
}

#define GLD16(g, l) __builtin_amdgcn_global_load_lds( \
    (const __attribute__((address_space(1))) void*)(g), \
    (__attribute__((address_space(3))) void*)(l), 16, 0, 0)

#define SLOT_STRIDE 16   // ints -> 64B per slot

// contention-free tree grid barrier (256 blocks x 256 threads)
__device__ __forceinline__ void gbar(int* slots, int* gen, int target) {
    asm volatile("s_waitcnt vmcnt(0)" ::: "memory");
    __syncthreads();
    if (blockIdx.x == 0) {
        if (threadIdx.x == 0) stI(slots, target);
        while (ldI(slots + threadIdx.x * SLOT_STRIDE) < target)
            __builtin_amdgcn_s_sleep(1);
        __syncthreads();
        if (threadIdx.x == 0) stI(gen, target);
    } else {
        if (threadIdx.x == 0) {
            stI(slots + blockIdx.x * SLOT_STRIDE, target);
            while (ldI(gen) < target)
                __builtin_amdgcn_s_sleep(1);
        }
        __syncthreads();
    }
}

// 8 K-chunks (256 K elems) of MFMA: per-wave row-tile, plain cached loads
__device__ __forceinline__ void mac8(const unsigned short* A, const unsigned short* B,
                                     f32x4& acc) {
    bf16x8 a[8], b[8];
#pragma unroll
    for (int kk = 0; kk < 8; ++kk) {
        a[kk] = *(const bf16x8*)(A + kk * 32);
        b[kk] = *(const bf16x8*)(B + kk * 32);
    }
#pragma unroll
    for (int kk = 0; kk < 8; ++kk)
        acc = __builtin_amdgcn_mfma_f32_16x16x32_bf16(a[kk], b[kk], acc, 0, 0, 0);
}

// ---------- elementwise / conversion kernels ----------

__global__ void k_gather(const float* __restrict__ emb, const int* __restrict__ tok,
                         unsigned short* __restrict__ out, int L, int ldtok) {
    long total = (long)L * 64 * 128;
    for (long i = (long)blockIdx.x * blockDim.x + threadIdx.x; i < total;
         i += (long)gridDim.x * blockDim.x) {
        int  e4 = (int)(i & 127);
        long r  = i >> 7;
        int  t  = (int)(r >> 6), b = (int)(r & 63);
        int  tk = tok[b * ldtok + t];
        float4 v = *(const float4*)(emb + (long)tk * 512 + e4 * 4);
        ushort4 o; o.x = f2b(v.x); o.y = f2b(v.y); o.z = f2b(v.z); o.w = f2b(v.w);
        *(ushort4*)(out + r * 512 + e4 * 4) = o;
    }
}

__global__ void k_conv(const float* __restrict__ in, unsigned short* __restrict__ out,
                       long N_, int K_, int ldin, int col0, int ldout, int outcol0, int reorder) {
    long total = N_ * (K_ >> 2);
    int kq = K_ >> 2;
    for (long i = (long)blockIdx.x * blockDim.x + threadIdx.x; i < total;
         i += (long)gridDim.x * blockDim.x) {
        long n = i / kq;
        int  k4 = (int)(i - n * kq) * 4;
        long row = reorder ? (long)((n & 3) * 1024 + (n >> 2)) : n;
        float4 v = *(const float4*)(in + row * ldin + col0 + k4);
        ushort4 o; o.x = f2b(v.x); o.y = f2b(v.y); o.z = f2b(v.z); o.w = f2b(v.w);
        *(ushort4*)(out + n * ldout + outcol0 + k4) = o;
    }
}

__global__ void k_bias(const float* __restrict__ b1, const float* __restrict__ b2,
                       float* __restrict__ out) {
    int n = blockIdx.x * blockDim.x + threadIdx.x;
    if (n < 4096) {
        int row = (n & 3) * 1024 + (n >> 2);
        out[n] = b1[row] + b2[row];
    }
}

__global__ void k_zero0(float* __restrict__ out) {
    long total = 64L * 8000;
    for (long i = (long)blockIdx.x * blockDim.x + threadIdx.x; i < total;
         i += (long)gridDim.x * blockDim.x) {
        int b = (int)(i / 8000), q = (int)(i % 8000);
        float4 z = {0.f, 0.f, 0.f, 0.f};
        *(float4*)(out + (long)b * 1024000 + q * 4) = z;
    }
}

// ---------- big-GEMM (prep + fc), m97 structure ----------
template<int BM, int BN, int WGM, int WGN, int FM, int FN>
__device__ __forceinline__ void gemm_core(
    const unsigned short* __restrict__ A, int lda,
    const unsigned short* __restrict__ B, int ldb,
    long m0, long n0, int K,
    unsigned short* As, unsigned short* Bs,
    f32x4 (&acc)[FM][FN])
{
    const int tid  = threadIdx.x;
    const int lane = tid & 63;
    const int wave = tid >> 6;
    const int wm = wave / WGN;
    const int wn = wave % WGN;
    const int srow = lane >> 2;
    const int scol = (lane & 3) * 8;
    const int frow = lane & 15;
    const int fcol = (lane >> 4) * 8;

    for (int k0 = 0; k0 < K; k0 += 32) {
        __syncthreads();
        for (int c = wave; c < BM / 16; c += 4) {
            const unsigned short* g = A + (m0 + c * 16 + srow) * (long)lda + k0 + scol;
            GLD16(g, As + c * 512);
        }
        for (int c = wave; c < BN / 16; c += 4) {
            const unsigned short* g = B + (n0 + c * 16 + srow) * (long)ldb + k0 + scol;
            GLD16(g, Bs + c * 512);
        }
        __syncthreads();
        bf16x8 af[FM], bfr[FN];
#pragma unroll
        for (int m = 0; m < FM; ++m)
            af[m] = *(const bf16x8*)(As + ((wm * FM + m) * 16 + frow) * 32 + fcol);
#pragma unroll
        for (int n = 0; n < FN; ++n)
            bfr[n] = *(const bf16x8*)(Bs + ((wn * FN + n) * 16 + frow) * 32 + fcol);
#pragma unroll
        for (int m = 0; m < FM; ++m)
#pragma unroll
            for (int n = 0; n < FN; ++n)
                acc[m][n] = __builtin_amdgcn_mfma_f32_16x16x32_bf16(af[m], bfr[n], acc[m][n], 0, 0, 0);
    }
}

// MODE 0: f32 out. MODE 1: fc row-remap + XCD-grouped swizzled 1D grid.
// MODE 2: fp16 out.
template<int BM, int BN, int WGM, int WGN, int FM, int FN, int MODE>
__global__ __launch_bounds__(256) void k_gemm(
    const unsigned short* __restrict__ A, int lda,
    const unsigned short* __restrict__ B, int ldb,
    float* __restrict__ C, long ldc, const float* __restrict__ bias,
    int M, int N, int K, int Mreal)
{
    __shared__ __align__(16) unsigned short As[BM * 32];
    __shared__ __align__(16) unsigned short Bs[BN * 32];
    long m0, n0;
    if (MODE == 1) {
        // group all 16 M-panels of an N-panel on one XCD (bid%8 = XCD)
        int bid = blockIdx.x;
        int n = (bid & 7) * 32 + (bid >> 7);
        int m = (bid >> 3) & 15;
        if (n >= 250) return;
        m0 = (long)m * BM; n0 = (long)n * BN;
    } else {
        m0 = (long)blockIdx.y * BM; n0 = (long)blockIdx.x * BN;
    }
    f32x4 acc[FM][FN] = {};
    gemm_core<BM, BN, WGM, WGN, FM, FN>(A, lda, B, ldb, m0, n0, K, As, Bs, acc);

    const int lane = threadIdx.x & 63;
    const int wave = threadIdx.x >> 6;
    const int wm = wave / WGN, wn = wave % WGN;
#pragma unroll
    for (int n = 0; n < FN; ++n) {
        long col = n0 + wn * FN * 16 + n * 16 + (lane & 15);
        float bv = bias ? bias[col] : 0.0f;
#pragma unroll
        for (int m = 0; m < FM; ++m) {
            int rl = wm * FM * 16 + m * 16 + (lane >> 4) * 4;
#pragma unroll
            for (int q = 0; q < 4; ++q) {
                long r = m0 + rl + q;
                float val = acc[m][n][q] + bv;
                if (MODE == 0) {
                    C[r * ldc + col] = val;
                } else if (MODE == 2) {
                    ((_Float16*)C)[r * ldc + col] = (_Float16)val;
                } else {
                    if (r < Mreal) {
                        long orow = (r & 63) * 32 + (r >> 6) + 1;
                        C[orow * ldc + col] = val;
                    }
                }
            }
        }
    }
}

// ---------- persistent encoder: 256 blocks x 256 threads, 1 barrier/step ----------
__global__ __launch_bounds__(256) void k_enc(
    const unsigned short* __restrict__ W,    // weWhh 4096x1024 gate-interleaved
    const float* __restrict__ pre,           // [64][64][4096]
    unsigned short* __restrict__ hsl,        // 65 slots x [64][1024] (slot0 zeroed)
    unsigned short* __restrict__ enc_out,    // [b*64+t][1024]
    unsigned short* __restrict__ eoT,        // [b][h][t]
    unsigned short* __restrict__ hS0,        // dec h slot 0 (h_f)
    float* __restrict__ cspill,
    int* slots, int* gen)
{
    __shared__ float gs[64 * 16];
    const int blk = blockIdx.x, tid = threadIdx.x;
    const int lane = tid & 63, wave = tid >> 6;
    const int n0 = blk * 16;
    const int arow = wave * 16 + (lane & 15);
    const int kch = (lane >> 4) * 8;
    const unsigned short* Bw = W + (long)(n0 + (lane & 15)) * 1024 + kch;
    const int pb = tid >> 1, pjl = (tid & 1) * 2;    // active for tid<128
    const int jg = blk * 4 + pjl;
    float c0 = 0.f, c1 = 0.f;
    float4 pr0 = {}, pr1 = {};
    if (tid < 128) {
        pr0 = *(const float4*)(pre + (long)pb * 4096 + n0 + pjl * 4);
        pr1 = *(const float4*)(pre + (long)pb * 4096 + n0 + pjl * 4 + 4);
    }
    int bt = 0;
    for (int t = 0; t < 64; ++t) {
        const unsigned short* Ar = hsl + (long)t * 65536 + (long)arow * 1024 + kch;
        f32x4 acc = {};
        mac8(Ar, Bw, acc);
        mac8(Ar + 256, Bw + 256, acc);
        mac8(Ar + 512, Bw + 512, acc);
        mac8(Ar + 768, Bw + 768, acc);
#pragma unroll
        for (int q = 0; q < 4; ++q)
            gs[(wave * 16 + (lane >> 4) * 4 + q) * 16 + (lane & 15)] = acc[q];
        __syncthreads();
        if (tid < 128) {
            float4 gA = *(const float4*)(gs + pb * 16 + pjl * 4);
            float4 gB = *(const float4*)(gs + pb * 16 + pjl * 4 + 4);
            float h0v, h1v;
            {
                float gi = gA.x + pr0.x, gf = gA.y + pr0.y, gg = gA.z + pr0.z, go = gA.w + pr0.w;
                float i_ = 1.f / (1.f + __expf(-gi)), f_ = 1.f / (1.f + __expf(-gf));
                float g_ = tanhfast(gg), o_ = 1.f / (1.f + __expf(-go));
                c0 = f_ * c0 + i_ * g_; h0v = o_ * tanhfast(c0);
            }
            {
                float gi = gB.x + pr1.x, gf = gB.y + pr1.y, gg = gB.z + pr1.z, go = gB.w + pr1.w;
                float i_ = 1.f / (1.f + __expf(-gi)), f_ = 1.f / (1.f + __expf(-gf));
                float g_ = tanhfast(gg), o_ = 1.f / (1.f + __expf(-go));
                c1 = f_ * c1 + i_ * g_; h1v = o_ * tanhfast(c1);
            }
            unsigned short hb0 = f2b(h0v), hb1 = f2b(h1v);
            unsigned pk = (unsigned)hb0 | ((unsigned)hb1 << 16);
            stU((unsigned*)(hsl + (long)(t + 1) * 65536 + (long)pb * 1024 + jg), pk);
            *(unsigned*)(enc_out + ((long)pb * 64 + t) * 1024 + jg) = pk;
            eoT[((long)pb * 1024 + jg) * 64 + t]     = hb0;
            eoT[((long)pb * 1024 + jg + 1) * 64 + t] = hb1;
            if (t < 63) {
                pr0 = *(const float4*)(pre + (long)(t + 1) * 262144 + (long)pb * 4096 + n0 + pjl * 4);
                pr1 = *(const float4*)(pre + (long)(t + 1) * 262144 + (long)pb * 4096 + n0 + pjl * 4 + 4);
            } else {
                *(unsigned*)(hS0 + (long)pb * 1024 + jg) = pk;
                cspill[(long)pb * 1024 + jg]     = c0;
                cspill[(long)pb * 1024 + jg + 1] = c1;
            }
        }
        gbar(slots, gen, ++bt);
    }
}

// ---------- persistent decoder: 256 blocks x 256 threads, 3 phases/step ----------
__global__ __launch_bounds__(256) void k_dec(
    const unsigned short* __restrict__ Wh,   // 1024x1024
    const unsigned short* __restrict__ Wc,   // 4096x2048 gate-interleaved
    const float* __restrict__ pre,           // [31][64][4096]
    const _Float16* __restrict__ proj16,     // [b*64+s][1024] fp16 (attn_b folded)
    const unsigned short* __restrict__ eoT,  // [b][h][t]
    const float* __restrict__ v,
    const float* __restrict__ cspill,
    unsigned short* __restrict__ hS,         // 32 slots x [64][1024] (slot0 = h_f)
    unsigned short* __restrict__ ctxS,       // 32 slots x [64][1024]
    float* __restrict__ qS,                  // 32 slots x [64][1024] f32
    unsigned short* __restrict__ fcin,       // (t*64+b) x 2048
    int* slots, int* gen)
{
    __shared__ float gs[64 * 16];
    __shared__ float qv[1024], vv[1024];
    __shared__ float sc[64], al[64];
    const int blk = blockIdx.x, tid = threadIdx.x;
    const int lane = tid & 63, wave = tid >> 6;
    const int n0 = blk * 16;
    const int arow = wave * 16 + (lane & 15);
    const int kch = (lane >> 4) * 8;
    const int pb = tid >> 1, pjl = (tid & 1) * 2;
    const int jg = blk * 4 + pjl;
    {
        float4 v4 = *(const float4*)(v + tid * 4);
        *(float4*)(vv + tid * 4) = v4;
    }
    float c0 = 0.f, c1 = 0.f;
    if (tid < 128) {
        c0 = cspill[(long)pb * 1024 + jg];
        c1 = cspill[(long)pb * 1024 + jg + 1];
    }
    __syncthreads();
    int bt = 0;
    for (int t = 0; t < 31; ++t) {
        const unsigned short* hSt   = hS   + (long)t * 65536;
        const unsigned short* ctxSt = ctxS + (long)t * 65536;
        float4 pr0 = {}, pr1 = {};
        if (tid < 128) {
            pr0 = *(const float4*)(pre + (long)t * 262144 + (long)pb * 4096 + n0 + pjl * 4);
            pr1 = *(const float4*)(pre + (long)t * 262144 + (long)pb * 4096 + n0 + pjl * 4 + 4);
        }
        // ---- phase 1: q = h_t @ Wh^T, ALL 256 blocks (64 n-tiles x 4 m-tiles),
        //      per-wave K=256 split + LDS reduce
        {
            int nq = blk >> 2, mt = blk & 3;
            gs[tid] = 0.f;
            __syncthreads();
            const unsigned short* Ar = hSt + (long)(mt * 16 + (lane & 15)) * 1024 + wave * 256 + kch;
            const unsigned short* Bq = Wh + (long)(nq * 16 + (lane & 15)) * 1024 + wave * 256 + kch;
            f32x4 qa = {};
            mac8(Ar, Bq, qa);
#pragma unroll
            for (int q = 0; q < 4; ++q)
                atomicAdd(&gs[((lane >> 4) * 4 + q) * 16 + (lane & 15)], qa[q]);
            __syncthreads();
            stF(qS + (long)t * 65536 + (long)(mt * 16 + (tid >> 4)) * 1024 + nq * 16 + (tid & 15),
                gs[tid]);
        }
        gbar(slots, gen, ++bt);
        // ---- phase 2: attention (blocks 0..63: b = blk)
        if (blk < 64) {
            const int b = blk;
            *(float4*)(qv + tid * 4) = *(const float4*)(qS + (long)t * 65536 + (long)b * 1024 + tid * 4);
            __syncthreads();
            int s = tid >> 2, part = tid & 3;
            const h16x8* pp = (const h16x8*)(proj16 + ((long)b * 64 + s) * 1024 + part * 256);
            float a_ = 0.f;
#pragma unroll 4
            for (int d = 0; d < 32; ++d) {
                h16x8 pv = pp[d];
                int h = part * 256 + d * 8;
#pragma unroll
                for (int j = 0; j < 8; ++j)
                    a_ += vv[h + j] * tanhfast(qv[h + j] + (float)pv[j]);
            }
            a_ += __shfl_xor(a_, 1);
            a_ += __shfl_xor(a_, 2);
            if (part == 0) sc[s] = a_;
            __syncthreads();
            if (tid < 64) {
                float x = sc[tid], mx = x;
                for (int o = 32; o; o >>= 1) mx = fmaxf(mx, __shfl_xor(mx, o));
                float e = __expf(x - mx), su = e;
                for (int o = 32; o; o >>= 1) su += __shfl_xor(su, o);
                al[tid] = e / su;
            }
            __syncthreads();
            int h0 = tid * 4;
            float cacc[4];
#pragma unroll
            for (int r = 0; r < 4; ++r) {
                const bf16x8* ep = (const bf16x8*)(eoT + ((long)b * 1024 + h0 + r) * 64);
                float s_ = 0.f;
#pragma unroll
                for (int c8 = 0; c8 < 8; ++c8) {
                    bf16x8 v8 = ep[c8];
#pragma unroll
                    for (int jj = 0; jj < 8; ++jj)
                        s_ += al[c8 * 8 + jj] * (float)v8[jj];
                }
                cacc[r] = s_;
            }
            unsigned pk0 = (unsigned)f2b(cacc[0]) | ((unsigned)f2b(cacc[1]) << 16);
            unsigned pk1 = (unsigned)f2b(cacc[2]) | ((unsigned)f2b(cacc[3]) << 16);
            stU((unsigned*)(ctxS + (long)t * 65536 + (long)b * 1024 + h0), pk0);
            stU((unsigned*)(ctxS + (long)t * 65536 + (long)b * 1024 + h0 + 2), pk1);
            *(unsigned*)(fcin + ((long)t * 64 + b) * 2048 + 1024 + h0)     = pk0;
            *(unsigned*)(fcin + ((long)t * 64 + b) * 2048 + 1024 + h0 + 2) = pk1;
        }
        gbar(slots, gen, ++bt);
        // ---- phase 3: gates (all 256 blocks, 16 cols each, K=2048)
        {
            const unsigned short* Ah = hSt   + (long)arow * 1024 + kch;
            const unsigned short* Ac = ctxSt + (long)arow * 1024 + kch;
            const unsigned short* Bw = Wc + (long)(n0 + (lane & 15)) * 2048 + kch;
            f32x4 acc = {};
            mac8(Ah,       Bw,        acc);
            mac8(Ah + 256, Bw + 256,  acc);
            mac8(Ah + 512, Bw + 512,  acc);
            mac8(Ah + 768, Bw + 768,  acc);
            mac8(Ac,       Bw + 1024, acc);
            mac8(Ac + 256, Bw + 1280, acc);
            mac8(Ac + 512, Bw + 1536, acc);
            mac8(Ac + 768, Bw + 1792, acc);
#pragma unroll
            for (int q = 0; q < 4; ++q)
                gs[(wave * 16 + (lane >> 4) * 4 + q) * 16 + (lane & 15)] = acc[q];
            __syncthreads();
            if (tid < 128) {
                float4 gA = *(const float4*)(gs + pb * 16 + pjl * 4);
                float4 gB = *(const float4*)(gs + pb * 16 + pjl * 4 + 4);
                float h0v, h1v;
                {
                    float gi = gA.x + pr0.x, gf = gA.y + pr0.y, gg = gA.z + pr0.z, go = gA.w + pr0.w;
                    float i_ = 1.f / (1.f + __expf(-gi)), f_ = 1.f / (1.f + __expf(-gf));
                    float g_ = tanhfast(gg), o_ = 1.f / (1.f + __expf(-go));
                    c0 = f_ * c0 + i_ * g_; h0v = o_ * tanhfast(c0);
                }
                {
                    float gi = gB.x + pr1.x, gf = gB.y + pr1.y, gg = gB.z + pr1.z, go = gB.w + pr1.w;
                    float i_ = 1.f / (1.f + __expf(-gi)), f_ = 1.f / (1.f + __expf(-gf));
                    float g_ = tanhfast(gg), o_ = 1.f / (1.f + __expf(-go));
                    c1 = f_ * c1 + i_ * g_; h1v = o_ * tanhfast(c1);
                }
                unsigned pk = (unsigned)f2b(h0v) | ((unsigned)f2b(h1v) << 16);
                stU((unsigned*)(hS + (long)(t + 1) * 65536 + (long)pb * 1024 + jg), pk);
                *(unsigned*)(fcin + ((long)t * 64 + pb) * 2048 + jg) = pk;
            }
        }
        gbar(slots, gen, ++bt);
    }
}

// ---------- launch ----------
extern "C" void kernel_launch(void* const* d_in, const int* in_sizes, int n_in,
                              void* d_out, int out_size, void* d_ws, size_t ws_size,
                              hipStream_t stream) {
    const int*   src     = (const int*)d_in[0];
    const int*   tgt     = (const int*)d_in[1];
    const float* enc_emb = (const float*)d_in[2];
    const float* dec_emb = (const float*)d_in[3];
    const float* enc_Wih = (const float*)d_in[4];
    const float* enc_Whh = (const float*)d_in[5];
    const float* enc_bih = (const float*)d_in[6];
    const float* enc_bhh = (const float*)d_in[7];
    const float* dec_Wih = (const float*)d_in[8];
    const float* dec_Whh = (const float*)d_in[9];
    const float* dec_bih = (const float*)d_in[10];
    const float* dec_bhh = (const float*)d_in[11];
    const float* attn_W  = (const float*)d_in[12];
    const float* attn_b  = (const float*)d_in[13];
    const float* vvec    = (const float*)d_in[14];
    const float* fc_W    = (const float*)d_in[15];
    const float* fc_b    = (const float*)d_in[16];
    float* out = (float*)d_out;

    char* ws = (char*)d_ws;
    size_t off = 0;
    auto alloc = [&](size_t bytes) -> char* {
        off = (off + 255) & ~(size_t)255;
        char* p = ws + off; off += bytes; return p;
    };
    unsigned short* wX      = (unsigned short*)alloc(4096UL * 512 * 2);
    unsigned short* weWih   = (unsigned short*)alloc(4096UL * 512 * 2);
    unsigned short* weWhh   = (unsigned short*)alloc(4096UL * 1024 * 2);
    float*          ebias   = (float*)alloc(4096UL * 4);
    float*          pre_enc = (float*)alloc(4096UL * 4096 * 4);
    unsigned short* enc_out = (unsigned short*)alloc(4096UL * 1024 * 2);
    unsigned short* eoT     = (unsigned short*)alloc(64UL * 1024 * 64 * 2);
    unsigned short* wWe     = (unsigned short*)alloc(1024UL * 1024 * 2);
    unsigned short* wWh     = (unsigned short*)alloc(1024UL * 1024 * 2);
    _Float16*       proj16  = (_Float16*)alloc(4096UL * 1024 * 2);
    float*          cbuf    = (float*)alloc(64UL * 1024 * 4);
    unsigned short* demb    = (unsigned short*)alloc(2048UL * 512 * 2);
    unsigned short* wDemb   = (unsigned short*)alloc(4096UL * 512 * 2);
    unsigned short* wCat    = (unsigned short*)alloc(4096UL * 2048 * 2);
    float*          dbias   = (float*)alloc(4096UL * 4);
    float*          pre_dec = (float*)alloc(2048UL * 4096 * 4);
    unsigned short* fcin    = (unsigned short*)alloc(2048UL * 2048 * 2);
    unsigned short* wFc     = (unsigned short*)alloc(32000UL * 2048 * 2);
    unsigned short* hslE    = (unsigned short*)alloc(65UL * 65536 * 2);
    unsigned short* hS      = (unsigned short*)alloc(32UL * 65536 * 2);
    unsigned short* ctxS    = (unsigned short*)alloc(32UL * 65536 * 2);
    float*          qS      = (float*)alloc(32UL * 65536 * 4);
    int*            bar     = (int*)alloc(65536);
    (void)ws_size; (void)in_sizes; (void)n_in; (void)out_size;

    int* slotsE = bar;            // 256 slots x 64B
    int* genE   = bar + 4096;
    int* slotsD = bar + 8192;
    int* genD   = bar + 12288;

    hipMemsetAsync(bar, 0, 65536, stream);
    hipMemsetAsync(hslE, 0, 65536UL * 2, stream);   // enc h slot 0 = zeros
    k_zero0<<<512, 256, 0, stream>>>(out);

    k_gather<<<2048, 256, 0, stream>>>(enc_emb, src, wX, 64, 64);
    k_gather<<<1024, 256, 0, stream>>>(dec_emb, tgt, demb, 31, 32);
    k_conv<<<2048, 256, 0, stream>>>(enc_Wih, weWih, 4096, 512, 512, 0, 512, 0, 1);
    k_conv<<<2048, 256, 0, stream>>>(enc_Whh, weWhh, 4096, 1024, 1024, 0, 1024, 0, 1);
    k_conv<<<2048, 256, 0, stream>>>(dec_Wih, wDemb, 4096, 512, 1536, 0, 512, 0, 1);
    k_conv<<<2048, 256, 0, stream>>>(dec_Whh, wCat, 4096, 1024, 1024, 0, 2048, 0, 1);
    k_conv<<<2048, 256, 0, stream>>>(dec_Wih, wCat, 4096, 1024, 1536, 512, 2048, 1024, 1);
    k_conv<<<2048, 256, 0, stream>>>(attn_W, wWh, 1024, 1024, 2048, 0, 1024, 0, 0);
    k_conv<<<2048, 256, 0, stream>>>(attn_W, wWe, 1024, 1024, 2048, 1024, 1024, 0, 0);
    k_conv<<<4096, 256, 0, stream>>>(fc_W, wFc, 32000, 2048, 2048, 0, 2048, 0, 0);
    k_bias<<<16, 256, 0, stream>>>(enc_bih, enc_bhh, ebias);
    k_bias<<<16, 256, 0, stream>>>(dec_bih, dec_bhh, dbias);

    // pre-gates GEMMs
    k_gemm<128,128,2,2,4,4,0><<<dim3(32, 32), 256, 0, stream>>>(
        wX, 512, weWih, 512, pre_enc, 4096, ebias, 4096, 4096, 512, 4096);
    k_gemm<128,128,2,2,4,4,0><<<dim3(32, 16), 256, 0, stream>>>(
        demb, 512, wDemb, 512, pre_dec, 4096, dbias, 2048, 4096, 512, 2048);

    // persistent encoder (256 blocks, all CUs)
    k_enc<<<256, 256, 0, stream>>>(weWhh, pre_enc, hslE, enc_out, eoT,
                                   hS, cbuf, slotsE, genE);

    // enc_proj (+attn_b) -> fp16
    k_gemm<128,128,2,2,4,4,2><<<dim3(8, 32), 256, 0, stream>>>(
        enc_out, 1024, wWe, 1024, (float*)proj16, 1024, attn_b, 4096, 1024, 1024, 4096);

    // persistent decoder (256 blocks)
    k_dec<<<256, 256, 0, stream>>>(wWh, wCat, pre_dec, proj16, eoT, vvec, cbuf,
                                   hS, ctxS, qS, fcin, slotsD, genD);

    // batched fc GEMM -> out (XCD-grouped swizzle; rows b*32 zeroed by k_zero0)
    k_gemm<128,128,2,2,4,4,1><<<dim3(4096), 256, 0, stream>>>(
        fcin, 2048, wFc, 2048, out, 32000, fc_b, 2048, 32000, 2048, 1984);
}

// Round 9
// 2595.009 us; speedup vs baseline: 2.3554x; 1.0328x over previous
//
#include <hip/hip_runtime.h>
#include <hip/hip_bf16.h>

// ---------- types / helpers ----------
typedef __bf16 bf16x8 __attribute__((ext_vector_type(8)));
typedef float  f32x4  __attribute__((ext_vector_type(4)));
typedef _Float16 h16x8 __attribute__((ext_vector_type(8)));

__device__ __forceinline__ unsigned short f2b(float f) {
    union { float f; unsigned u; } w; w.f = f;
    unsigned u = w.u + 0x7FFF + ((w.u >> 16) & 1);
    return (unsigned short)(u >> 16);
}
__device__ __forceinline__ float tanhfast(float x) {
    float e = __expf(2.0f * x);
    return 1.0f - 2.0f / (e + 1.0f);
}

// AGENT-scope (device/L3-coherent) write-through stores for per-step state;
// readers use plain cached loads (fresh-slot discipline: each slot written
// once, reader CU never touched the address -> its L2 cannot be stale).
__device__ __forceinline__ void stU(unsigned* p, unsigned v) {
    __hip_atomic_store(p, v, __ATOMIC_RELAXED, __HIP_MEMORY_SCOPE_AGENT);
}
__device__ __forceinline__ void stF(float* p, float v) {
    __hip_atomic_store(p, v, __ATOMIC_RELAXED, __HIP_MEMORY_SCOPE_AGENT);
}
__device__ __forceinline__ int ldI(const int* p) {
    return __hip_atomic_load((int*)p, __ATOMIC_RELAXED, __HIP_MEMORY_SCOPE_AGENT);
}
__device__ __forceinline__ void stI(int* p, int v) {
    __hip_atomic_store(p, v, __ATOMIC_RELAXED, __HIP_MEMORY_SCOPE_AGENT);
}

#define GLD16(g, l) __builtin_amdgcn_global_load_lds( \
    (const __attribute__((address_space(1))) void*)(g), \
    (__attribute__((address_space(3))) void*)(l), 16, 0, 0)

#define SLOT_STRIDE 16   // ints -> 64B per slot
#define NPOLL 256        // grid size of persistent kernels

// contention-free tree grid barrier (256 blocks)
__device__ __forceinline__ void gbar(int* slots, int* gen, int target) {
    asm volatile("s_waitcnt vmcnt(0)" ::: "memory");
    __syncthreads();
    if (blockIdx.x == 0) {
        if (threadIdx.x == 0) stI(slots, target);
        if (threadIdx.x < NPOLL) {
            while (ldI(slots + threadIdx.x * SLOT_STRIDE) < target)
                __builtin_amdgcn_s_sleep(1);
        }
        __syncthreads();
        if (threadIdx.x == 0) stI(gen, target);
    } else {
        if (threadIdx.x == 0) {
            stI(slots + blockIdx.x * SLOT_STRIDE, target);
            while (ldI(gen) < target)
                __builtin_amdgcn_s_sleep(1);
        }
        __syncthreads();
    }
}

// 8 K-chunks (256 K elems) of MFMA: per-wave row-tile, plain cached loads
__device__ __forceinline__ void mac8(const unsigned short* A, const unsigned short* B,
                                     f32x4& acc) {
    bf16x8 a[8], b[8];
#pragma unroll
    for (int kk = 0; kk < 8; ++kk) {
        a[kk] = *(const bf16x8*)(A + kk * 32);
        b[kk] = *(const bf16x8*)(B + kk * 32);
    }
#pragma unroll
    for (int kk = 0; kk < 8; ++kk)
        acc = __builtin_amdgcn_mfma_f32_16x16x32_bf16(a[kk], b[kk], acc, 0, 0, 0);
}
// 4 K-chunks (128 K elems)
__device__ __forceinline__ void mac4(const unsigned short* A, const unsigned short* B,
                                     f32x4& acc) {
    bf16x8 a[4], b[4];
#pragma unroll
    for (int kk = 0; kk < 4; ++kk) {
        a[kk] = *(const bf16x8*)(A + kk * 32);
        b[kk] = *(const bf16x8*)(B + kk * 32);
    }
#pragma unroll
    for (int kk = 0; kk < 4; ++kk)
        acc = __builtin_amdgcn_mfma_f32_16x16x32_bf16(a[kk], b[kk], acc, 0, 0, 0);
}

// ---------- elementwise / conversion kernels ----------

__global__ void k_gather(const float* __restrict__ emb, const int* __restrict__ tok,
                         unsigned short* __restrict__ out, int L, int ldtok) {
    long total = (long)L * 64 * 128;
    for (long i = (long)blockIdx.x * blockDim.x + threadIdx.x; i < total;
         i += (long)gridDim.x * blockDim.x) {
        int  e4 = (int)(i & 127);
        long r  = i >> 7;
        int  t  = (int)(r >> 6), b = (int)(r & 63);
        int  tk = tok[b * ldtok + t];
        float4 v = *(const float4*)(emb + (long)tk * 512 + e4 * 4);
        ushort4 o; o.x = f2b(v.x); o.y = f2b(v.y); o.z = f2b(v.z); o.w = f2b(v.w);
        *(ushort4*)(out + r * 512 + e4 * 4) = o;
    }
}

__global__ void k_conv(const float* __restrict__ in, unsigned short* __restrict__ out,
                       long N_, int K_, int ldin, int col0, int ldout, int outcol0, int reorder) {
    long total = N_ * (K_ >> 2);
    int kq = K_ >> 2;
    for (long i = (long)blockIdx.x * blockDim.x + threadIdx.x; i < total;
         i += (long)gridDim.x * blockDim.x) {
        long n = i / kq;
        int  k4 = (int)(i - n * kq) * 4;
        long row = reorder ? (long)((n & 3) * 1024 + (n >> 2)) : n;
        float4 v = *(const float4*)(in + row * ldin + col0 + k4);
        ushort4 o; o.x = f2b(v.x); o.y = f2b(v.y); o.z = f2b(v.z); o.w = f2b(v.w);
        *(ushort4*)(out + n * ldout + outcol0 + k4) = o;
    }
}

__global__ void k_bias(const float* __restrict__ b1, const float* __restrict__ b2,
                       float* __restrict__ out) {
    int n = blockIdx.x * blockDim.x + threadIdx.x;
    if (n < 4096) {
        int row = (n & 3) * 1024 + (n >> 2);
        out[n] = b1[row] + b2[row];
    }
}

__global__ void k_zero0(float* __restrict__ out) {
    long total = 64L * 8000;
    for (long i = (long)blockIdx.x * blockDim.x + threadIdx.x; i < total;
         i += (long)gridDim.x * blockDim.x) {
        int b = (int)(i / 8000), q = (int)(i % 8000);
        float4 z = {0.f, 0.f, 0.f, 0.f};
        *(float4*)(out + (long)b * 1024000 + q * 4) = z;
    }
}

// ---------- big-GEMM (prep + fc), m97 structure ----------
template<int BM, int BN, int WGM, int WGN, int FM, int FN>
__device__ __forceinline__ void gemm_core(
    const unsigned short* __restrict__ A, int lda,
    const unsigned short* __restrict__ B, int ldb,
    long m0, long n0, int K,
    unsigned short* As, unsigned short* Bs,
    f32x4 (&acc)[FM][FN])
{
    const int tid  = threadIdx.x;
    const int lane = tid & 63;
    const int wave = tid >> 6;
    const int wm = wave / WGN;
    const int wn = wave % WGN;
    const int srow = lane >> 2;
    const int scol = (lane & 3) * 8;
    const int frow = lane & 15;
    const int fcol = (lane >> 4) * 8;

    for (int k0 = 0; k0 < K; k0 += 32) {
        __syncthreads();
        for (int c = wave; c < BM / 16; c += 4) {
            const unsigned short* g = A + (m0 + c * 16 + srow) * (long)lda + k0 + scol;
            GLD16(g, As + c * 512);
        }
        for (int c = wave; c < BN / 16; c += 4) {
            const unsigned short* g = B + (n0 + c * 16 + srow) * (long)ldb + k0 + scol;
            GLD16(g, Bs + c * 512);
        }
        __syncthreads();
        bf16x8 af[FM], bfr[FN];
#pragma unroll
        for (int m = 0; m < FM; ++m)
            af[m] = *(const bf16x8*)(As + ((wm * FM + m) * 16 + frow) * 32 + fcol);
#pragma unroll
        for (int n = 0; n < FN; ++n)
            bfr[n] = *(const bf16x8*)(Bs + ((wn * FN + n) * 16 + frow) * 32 + fcol);
#pragma unroll
        for (int m = 0; m < FM; ++m)
#pragma unroll
            for (int n = 0; n < FN; ++n)
                acc[m][n] = __builtin_amdgcn_mfma_f32_16x16x32_bf16(af[m], bfr[n], acc[m][n], 0, 0, 0);
    }
}

// MODE 0: f32 out. MODE 1: fc row-remap + XCD-grouped swizzled 1D grid.
// MODE 2: fp16 out.
template<int BM, int BN, int WGM, int WGN, int FM, int FN, int MODE>
__global__ __launch_bounds__(256) void k_gemm(
    const unsigned short* __restrict__ A, int lda,
    const unsigned short* __restrict__ B, int ldb,
    float* __restrict__ C, long ldc, const float* __restrict__ bias,
    int M, int N, int K, int Mreal)
{
    __shared__ __align__(16) unsigned short As[BM * 32];
    __shared__ __align__(16) unsigned short Bs[BN * 32];
    long m0, n0;
    if (MODE == 1) {
        int bid = blockIdx.x;
        int n = (bid & 7) * 32 + (bid >> 7);
        int m = (bid >> 3) & 15;
        if (n >= 250) return;
        m0 = (long)m * BM; n0 = (long)n * BN;
    } else {
        m0 = (long)blockIdx.y * BM; n0 = (long)blockIdx.x * BN;
    }
    f32x4 acc[FM][FN] = {};
    gemm_core<BM, BN, WGM, WGN, FM, FN>(A, lda, B, ldb, m0, n0, K, As, Bs, acc);

    const int lane = threadIdx.x & 63;
    const int wave = threadIdx.x >> 6;
    const int wm = wave / WGN, wn = wave % WGN;
#pragma unroll
    for (int n = 0; n < FN; ++n) {
        long col = n0 + wn * FN * 16 + n * 16 + (lane & 15);
        float bv = bias ? bias[col] : 0.0f;
#pragma unroll
        for (int m = 0; m < FM; ++m) {
            int rl = wm * FM * 16 + m * 16 + (lane >> 4) * 4;
#pragma unroll
            for (int q = 0; q < 4; ++q) {
                long r = m0 + rl + q;
                float val = acc[m][n][q] + bv;
                if (MODE == 0) {
                    C[r * ldc + col] = val;
                } else if (MODE == 2) {
                    ((_Float16*)C)[r * ldc + col] = (_Float16)val;
                } else {
                    if (r < Mreal) {
                        long orow = (r & 63) * 32 + (r >> 6) + 1;
                        C[orow * ldc + col] = val;
                    }
                }
            }
        }
    }
}

// ---------- persistent encoder: 256 blocks x 512 threads (8 waves, 2/SIMD) ----------
// block owns 16 gate-cols; wave = (row-tile rt 0..3, k-half kh 0..1).
__global__ __launch_bounds__(512, 2) void k_enc(
    const unsigned short* __restrict__ W,    // weWhh 4096x1024 gate-interleaved
    const float* __restrict__ pre,           // [64][64][4096]
    unsigned short* __restrict__ hsl,        // 65 slots x [64][1024] (slot0 zeroed)
    unsigned short* __restrict__ enc_out,    // [b*64+t][1024]
    unsigned short* __restrict__ eoT,        // [b][h][t]
    unsigned short* __restrict__ hS0,        // dec h slot 0 (h_f)
    float* __restrict__ cspill,
    int* slots, int* gen)
{
    __shared__ float gs[64 * 16];
    const int blk = blockIdx.x, tid = threadIdx.x;
    const int lane = tid & 63, wave = tid >> 6;
    const int rt = wave >> 1, kh = wave & 1;
    const int n0 = blk * 16;
    const int arow = rt * 16 + (lane & 15);
    const int kch = kh * 512 + (lane >> 4) * 8;
    const int grow = (rt * 16 + (lane >> 4) * 4) * 16 + (lane & 15);
    const unsigned short* Bw = W + (long)(n0 + (lane & 15)) * 1024 + kch;
    const int pb = tid >> 1, pjl = (tid & 1) * 2;    // active for tid<128
    const int jg = blk * 4 + pjl;
    float c0 = 0.f, c1 = 0.f;
    float4 pr0 = {}, pr1 = {};
    if (tid < 128) {
        pr0 = *(const float4*)(pre + (long)pb * 4096 + n0 + pjl * 4);
        pr1 = *(const float4*)(pre + (long)pb * 4096 + n0 + pjl * 4 + 4);
    }
    int bt = 0;
    for (int t = 0; t < 64; ++t) {
        const unsigned short* Ar = hsl + (long)t * 65536 + (long)arow * 1024 + kch;
        f32x4 acc = {};
        mac8(Ar, Bw, acc);
        mac8(Ar + 256, Bw + 256, acc);
        if (kh == 0) {
#pragma unroll
            for (int q = 0; q < 4; ++q) gs[grow + q * 16] = acc[q];
        }
        __syncthreads();
        if (kh == 1) {
#pragma unroll
            for (int q = 0; q < 4; ++q) atomicAdd(&gs[grow + q * 16], acc[q]);
        }
        __syncthreads();
        if (tid < 128) {
            float4 gA = *(const float4*)(gs + pb * 16 + pjl * 4);
            float4 gB = *(const float4*)(gs + pb * 16 + pjl * 4 + 4);
            float h0v, h1v;
            {
                float gi = gA.x + pr0.x, gf = gA.y + pr0.y, gg = gA.z + pr0.z, go = gA.w + pr0.w;
                float i_ = 1.f / (1.f + __expf(-gi)), f_ = 1.f / (1.f + __expf(-gf));
                float g_ = tanhfast(gg), o_ = 1.f / (1.f + __expf(-go));
                c0 = f_ * c0 + i_ * g_; h0v = o_ * tanhfast(c0);
            }
            {
                float gi = gB.x + pr1.x, gf = gB.y + pr1.y, gg = gB.z + pr1.z, go = gB.w + pr1.w;
                float i_ = 1.f / (1.f + __expf(-gi)), f_ = 1.f / (1.f + __expf(-gf));
                float g_ = tanhfast(gg), o_ = 1.f / (1.f + __expf(-go));
                c1 = f_ * c1 + i_ * g_; h1v = o_ * tanhfast(c1);
            }
            unsigned short hb0 = f2b(h0v), hb1 = f2b(h1v);
            unsigned pk = (unsigned)hb0 | ((unsigned)hb1 << 16);
            stU((unsigned*)(hsl + (long)(t + 1) * 65536 + (long)pb * 1024 + jg), pk);
            *(unsigned*)(enc_out + ((long)pb * 64 + t) * 1024 + jg) = pk;
            eoT[((long)pb * 1024 + jg) * 64 + t]     = hb0;
            eoT[((long)pb * 1024 + jg + 1) * 64 + t] = hb1;
            if (t < 63) {
                pr0 = *(const float4*)(pre + (long)(t + 1) * 262144 + (long)pb * 4096 + n0 + pjl * 4);
                pr1 = *(const float4*)(pre + (long)(t + 1) * 262144 + (long)pb * 4096 + n0 + pjl * 4 + 4);
            } else {
                *(unsigned*)(hS0 + (long)pb * 1024 + jg) = pk;
                cspill[(long)pb * 1024 + jg]     = c0;
                cspill[(long)pb * 1024 + jg + 1] = c1;
            }
        }
        gbar(slots, gen, ++bt);
    }
}

// ---------- persistent decoder: 256 blocks x 512 threads, 3 phases/step ----------
__global__ __launch_bounds__(512, 2) void k_dec(
    const unsigned short* __restrict__ Wh,   // 1024x1024
    const unsigned short* __restrict__ Wc,   // 4096x2048 gate-interleaved
    const float* __restrict__ pre,           // [31][64][4096]
    const _Float16* __restrict__ proj16,     // [b*64+s][1024] fp16 (attn_b folded)
    const unsigned short* __restrict__ eoT,  // [b][h][t]
    const float* __restrict__ v,
    const float* __restrict__ cspill,
    unsigned short* __restrict__ hS,         // 32 slots x [64][1024] (slot0 = h_f)
    unsigned short* __restrict__ ctxS,       // 32 slots x [64][1024]
    float* __restrict__ qS,                  // 32 slots x [64][1024] f32
    unsigned short* __restrict__ fcin,       // (t*64+b) x 2048
    int* slots, int* gen)
{
    __shared__ float gs[64 * 16];
    __shared__ float qv[1024], vv[1024];
    __shared__ float sc[64], al[64];
    const int blk = blockIdx.x, tid = threadIdx.x;
    const int lane = tid & 63, wave = tid >> 6;
    const int rt = wave >> 1, kh = wave & 1;
    const int n0 = blk * 16;
    const int grow = (rt * 16 + (lane >> 4) * 4) * 16 + (lane & 15);
    const int pb = tid >> 1, pjl = (tid & 1) * 2;
    const int jg = blk * 4 + pjl;
    if (tid < 256) {
        float4 v4 = *(const float4*)(v + tid * 4);
        *(float4*)(vv + tid * 4) = v4;
    }
    float c0 = 0.f, c1 = 0.f;
    if (tid < 128) {
        c0 = cspill[(long)pb * 1024 + jg];
        c1 = cspill[(long)pb * 1024 + jg + 1];
    }
    __syncthreads();
    int bt = 0;
    for (int t = 0; t < 31; ++t) {
        const unsigned short* hSt   = hS   + (long)t * 65536;
        const unsigned short* ctxSt = ctxS + (long)t * 65536;
        float4 pr0 = {}, pr1 = {};
        if (tid < 128) {
            pr0 = *(const float4*)(pre + (long)t * 262144 + (long)pb * 4096 + n0 + pjl * 4);
            pr1 = *(const float4*)(pre + (long)t * 262144 + (long)pb * 4096 + n0 + pjl * 4 + 4);
        }
        // ---- phase 1: q = h_t @ Wh^T (64 n-tiles x 4 m-tiles; 8-way K split)
        {
            int nq = blk >> 2, mt = blk & 3;
            if (tid < 256) gs[tid] = 0.f;
            __syncthreads();
            const unsigned short* Ar = hSt + (long)(mt * 16 + (lane & 15)) * 1024
                                           + wave * 128 + (lane >> 4) * 8;
            const unsigned short* Bq = Wh + (long)(nq * 16 + (lane & 15)) * 1024
                                          + wave * 128 + (lane >> 4) * 8;
            f32x4 qa = {};
            mac4(Ar, Bq, qa);
#pragma unroll
            for (int q = 0; q < 4; ++q)
                atomicAdd(&gs[((lane >> 4) * 4 + q) * 16 + (lane & 15)], qa[q]);
            __syncthreads();
            if (tid < 256)
                stF(qS + (long)t * 65536 + (long)(mt * 16 + (tid >> 4)) * 1024
                        + nq * 16 + (tid & 15), gs[tid]);
        }
        gbar(slots, gen, ++bt);
        // ---- phase 2: attention (blocks 0..63: b = blk; 512 threads)
        if (blk < 64) {
            const int b = blk;
            if (tid < 256)
                *(float4*)(qv + tid * 4) =
                    *(const float4*)(qS + (long)t * 65536 + (long)b * 1024 + tid * 4);
            __syncthreads();
            int s = tid >> 3, part = tid & 7;
            const h16x8* pp = (const h16x8*)(proj16 + ((long)b * 64 + s) * 1024 + part * 128);
            float a_ = 0.f;
#pragma unroll 4
            for (int d = 0; d < 16; ++d) {
                h16x8 pv = pp[d];
                int h = part * 128 + d * 8;
#pragma unroll
                for (int j = 0; j < 8; ++j)
                    a_ += vv[h + j] * tanhfast(qv[h + j] + (float)pv[j]);
            }
            a_ += __shfl_xor(a_, 1);
            a_ += __shfl_xor(a_, 2);
            a_ += __shfl_xor(a_, 4);
            if (part == 0) sc[s] = a_;
            __syncthreads();
            if (tid < 64) {
                float x = sc[tid], mx = x;
                for (int o = 32; o; o >>= 1) mx = fmaxf(mx, __shfl_xor(mx, o));
                float e = __expf(x - mx), su = e;
                for (int o = 32; o; o >>= 1) su += __shfl_xor(su, o);
                al[tid] = e / su;
            }
            __syncthreads();
            int h0 = tid * 2;
            float cacc[2];
#pragma unroll
            for (int r = 0; r < 2; ++r) {
                const bf16x8* ep = (const bf16x8*)(eoT + ((long)b * 1024 + h0 + r) * 64);
                float s_ = 0.f;
#pragma unroll
                for (int c8 = 0; c8 < 8; ++c8) {
                    bf16x8 v8 = ep[c8];
#pragma unroll
                    for (int jj = 0; jj < 8; ++jj)
                        s_ += al[c8 * 8 + jj] * (float)v8[jj];
                }
                cacc[r] = s_;
            }
            unsigned pk0 = (unsigned)f2b(cacc[0]) | ((unsigned)f2b(cacc[1]) << 16);
            stU((unsigned*)(ctxS + (long)t * 65536 + (long)b * 1024 + h0), pk0);
            *(unsigned*)(fcin + ((long)t * 64 + b) * 2048 + 1024 + h0) = pk0;
        }
        gbar(slots, gen, ++bt);
        // ---- phase 3: gates (256 blocks x 16 cols; wave = (rt, kh); kh0=h, kh1=ctx)
        {
            const unsigned short* Asrc = (kh ? ctxSt : hSt)
                + (long)(rt * 16 + (lane & 15)) * 1024 + (lane >> 4) * 8;
            const unsigned short* Bw = Wc + (long)(n0 + (lane & 15)) * 2048
                                          + kh * 1024 + (lane >> 4) * 8;
            f32x4 acc = {};
            mac8(Asrc,       Bw,       acc);
            mac8(Asrc + 256, Bw + 256, acc);
            mac8(Asrc + 512, Bw + 512, acc);
            mac8(Asrc + 768, Bw + 768, acc);
            if (kh == 0) {
#pragma unroll
                for (int q = 0; q < 4; ++q) gs[grow + q * 16] = acc[q];
            }
            __syncthreads();
            if (kh == 1) {
#pragma unroll
                for (int q = 0; q < 4; ++q) atomicAdd(&gs[grow + q * 16], acc[q]);
            }
            __syncthreads();
            if (tid < 128) {
                float4 gA = *(const float4*)(gs + pb * 16 + pjl * 4);
                float4 gB = *(const float4*)(gs + pb * 16 + pjl * 4 + 4);
                float h0v, h1v;
                {
                    float gi = gA.x + pr0.x, gf = gA.y + pr0.y, gg = gA.z + pr0.z, go = gA.w + pr0.w;
                    float i_ = 1.f / (1.f + __expf(-gi)), f_ = 1.f / (1.f + __expf(-gf));
                    float g_ = tanhfast(gg), o_ = 1.f / (1.f + __expf(-go));
                    c0 = f_ * c0 + i_ * g_; h0v = o_ * tanhfast(c0);
                }
                {
                    float gi = gB.x + pr1.x, gf = gB.y + pr1.y, gg = gB.z + pr1.z, go = gB.w + pr1.w;
                    float i_ = 1.f / (1.f + __expf(-gi)), f_ = 1.f / (1.f + __expf(-gf));
                    float g_ = tanhfast(gg), o_ = 1.f / (1.f + __expf(-go));
                    c1 = f_ * c1 + i_ * g_; h1v = o_ * tanhfast(c1);
                }
                unsigned pk = (unsigned)f2b(h0v) | ((unsigned)f2b(h1v) << 16);
                stU((unsigned*)(hS + (long)(t + 1) * 65536 + (long)pb * 1024 + jg), pk);
                *(unsigned*)(fcin + ((long)t * 64 + pb) * 2048 + jg) = pk;
            }
        }
        gbar(slots, gen, ++bt);
    }
}

// ---------- launch ----------
extern "C" void kernel_launch(void* const* d_in, const int* in_sizes, int n_in,
                              void* d_out, int out_size, void* d_ws, size_t ws_size,
                              hipStream_t stream) {
    const int*   src     = (const int*)d_in[0];
    const int*   tgt     = (const int*)d_in[1];
    const float* enc_emb = (const float*)d_in[2];
    const float* dec_emb = (const float*)d_in[3];
    const float* enc_Wih = (const float*)d_in[4];
    const float* enc_Whh = (const float*)d_in[5];
    const float* enc_bih = (const float*)d_in[6];
    const float* enc_bhh = (const float*)d_in[7];
    const float* dec_Wih = (const float*)d_in[8];
    const float* dec_Whh = (const float*)d_in[9];
    const float* dec_bih = (const float*)d_in[10];
    const float* dec_bhh = (const float*)d_in[11];
    const float* attn_W  = (const float*)d_in[12];
    const float* attn_b  = (const float*)d_in[13];
    const float* vvec    = (const float*)d_in[14];
    const float* fc_W    = (const float*)d_in[15];
    const float* fc_b    = (const float*)d_in[16];
    float* out = (float*)d_out;

    char* ws = (char*)d_ws;
    size_t off = 0;
    auto alloc = [&](size_t bytes) -> char* {
        off = (off + 255) & ~(size_t)255;
        char* p = ws + off; off += bytes; return p;
    };
    unsigned short* wX      = (unsigned short*)alloc(4096UL * 512 * 2);
    unsigned short* weWih   = (unsigned short*)alloc(4096UL * 512 * 2);
    unsigned short* weWhh   = (unsigned short*)alloc(4096UL * 1024 * 2);
    float*          ebias   = (float*)alloc(4096UL * 4);
    float*          pre_enc = (float*)alloc(4096UL * 4096 * 4);
    unsigned short* enc_out = (unsigned short*)alloc(4096UL * 1024 * 2);
    unsigned short* eoT     = (unsigned short*)alloc(64UL * 1024 * 64 * 2);
    unsigned short* wWe     = (unsigned short*)alloc(1024UL * 1024 * 2);
    unsigned short* wWh     = (unsigned short*)alloc(1024UL * 1024 * 2);
    _Float16*       proj16  = (_Float16*)alloc(4096UL * 1024 * 2);
    float*          cbuf    = (float*)alloc(64UL * 1024 * 4);
    unsigned short* demb    = (unsigned short*)alloc(2048UL * 512 * 2);
    unsigned short* wDemb   = (unsigned short*)alloc(4096UL * 512 * 2);
    unsigned short* wCat    = (unsigned short*)alloc(4096UL * 2048 * 2);
    float*          dbias   = (float*)alloc(4096UL * 4);
    float*          pre_dec = (float*)alloc(2048UL * 4096 * 4);
    unsigned short* fcin    = (unsigned short*)alloc(2048UL * 2048 * 2);
    unsigned short* wFc     = (unsigned short*)alloc(32000UL * 2048 * 2);
    unsigned short* hslE    = (unsigned short*)alloc(65UL * 65536 * 2);
    unsigned short* hS      = (unsigned short*)alloc(32UL * 65536 * 2);
    unsigned short* ctxS    = (unsigned short*)alloc(32UL * 65536 * 2);
    float*          qS      = (float*)alloc(32UL * 65536 * 4);
    int*            bar     = (int*)alloc(65536);
    (void)ws_size; (void)in_sizes; (void)n_in; (void)out_size;

    int* slotsE = bar;            // 256 slots x 64B
    int* genE   = bar + 4096;
    int* slotsD = bar + 8192;
    int* genD   = bar + 12288;

    hipMemsetAsync(bar, 0, 65536, stream);
    hipMemsetAsync(hslE, 0, 65536UL * 2, stream);   // enc h slot 0 = zeros
    k_zero0<<<512, 256, 0, stream>>>(out);

    k_gather<<<2048, 256, 0, stream>>>(enc_emb, src, wX, 64, 64);
    k_gather<<<1024, 256, 0, stream>>>(dec_emb, tgt, demb, 31, 32);
    k_conv<<<2048, 256, 0, stream>>>(enc_Wih, weWih, 4096, 512, 512, 0, 512, 0, 1);
    k_conv<<<2048, 256, 0, stream>>>(enc_Whh, weWhh, 4096, 1024, 1024, 0, 1024, 0, 1);
    k_conv<<<2048, 256, 0, stream>>>(dec_Wih, wDemb, 4096, 512, 1536, 0, 512, 0, 1);
    k_conv<<<2048, 256, 0, stream>>>(dec_Whh, wCat, 4096, 1024, 1024, 0, 2048, 0, 1);
    k_conv<<<2048, 256, 0, stream>>>(dec_Wih, wCat, 4096, 1024, 1536, 512, 2048, 1024, 1);
    k_conv<<<2048, 256, 0, stream>>>(attn_W, wWh, 1024, 1024, 2048, 0, 1024, 0, 0);
    k_conv<<<2048, 256, 0, stream>>>(attn_W, wWe, 1024, 1024, 2048, 1024, 1024, 0, 0);
    k_conv<<<4096, 256, 0, stream>>>(fc_W, wFc, 32000, 2048, 2048, 0, 2048, 0, 0);
    k_bias<<<16, 256, 0, stream>>>(enc_bih, enc_bhh, ebias);
    k_bias<<<16, 256, 0, stream>>>(dec_bih, dec_bhh, dbias);

    // pre-gates GEMMs
    k_gemm<128,128,2,2,4,4,0><<<dim3(32, 32), 256, 0, stream>>>(
        wX, 512, weWih, 512, pre_enc, 4096, ebias, 4096, 4096, 512, 4096);
    k_gemm<128,128,2,2,4,4,0><<<dim3(32, 16), 256, 0, stream>>>(
        demb, 512, wDemb, 512, pre_dec, 4096, dbias, 2048, 4096, 512, 2048);

    // persistent encoder (256 blocks x 512 threads)
    k_enc<<<256, 512, 0, stream>>>(weWhh, pre_enc, hslE, enc_out, eoT,
                                   hS, cbuf, slotsE, genE);

    // enc_proj (+attn_b) -> fp16
    k_gemm<128,128,2,2,4,4,2><<<dim3(8, 32), 256, 0, stream>>>(
        enc_out, 1024, wWe, 1024, (float*)proj16, 1024, attn_b, 4096, 1024, 1024, 4096);

    // persistent decoder (256 blocks x 512 threads)
    k_dec<<<256, 512, 0, stream>>>(wWh, wCat, pre_dec, proj16, eoT, vvec, cbuf,
                                   hS, ctxS, qS, fcin, slotsD, genD);

    // batched fc GEMM -> out (XCD-grouped swizzle; rows b*32 zeroed by k_zero0)
    k_gemm<128,128,2,2,4,4,1><<<dim3(4096), 256, 0, stream>>>(
        fcin, 2048, wFc, 2048, out, 32000, fc_b, 2048, 32000, 2048, 1984);
}

// Round 10
// 2332.051 us; speedup vs baseline: 2.6209x; 1.1128x over previous
//
#include <hip/hip_runtime.h>
#include <hip/hip_bf16.h>

// ---------- types / helpers ----------
typedef __bf16 bf16x8 __attribute__((ext_vector_type(8)));
typedef float  f32x4  __attribute__((ext_vector_type(4)));
typedef _Float16 h16x8 __attribute__((ext_vector_type(8)));

__device__ __forceinline__ unsigned short f2b(float f) {
    union { float f; unsigned u; } w; w.f = f;
    unsigned u = w.u + 0x7FFF + ((w.u >> 16) & 1);
    return (unsigned short)(u >> 16);
}
__device__ __forceinline__ float tanhfast(float x) {
    float e = __expf(2.0f * x);
    return 1.0f - 2.0f / (e + 1.0f);
}

// AGENT-scope (device/L3-coherent) write-through stores for per-step state;
// readers use plain cached loads (fresh-slot discipline).
__device__ __forceinline__ void stU(unsigned* p, unsigned v) {
    __hip_atomic_store(p, v, __ATOMIC_RELAXED, __HIP_MEMORY_SCOPE_AGENT);
}
__device__ __forceinline__ void stF(float* p, float v) {
    __hip_atomic_store(p, v, __ATOMIC_RELAXED, __HIP_MEMORY_SCOPE_AGENT);
}
__device__ __forceinline__ int ldI(const int* p) {
    return __hip_atomic_load((int*)p, __ATOMIC_RELAXED, __HIP_MEMORY_SCOPE_AGENT);
}
__device__ __forceinline__ void stI(int* p, int v) {
    __hip_atomic_store(p, v, __ATOMIC_RELAXED, __HIP_MEMORY_SCOPE_AGENT);
}

#define GLD16(g, l) __builtin_amdgcn_global_load_lds( \
    (const __attribute__((address_space(1))) void*)(g), \
    (__attribute__((address_space(3))) void*)(l), 16, 0, 0)

#define SLOT_STRIDE 16   // ints -> 64B per slot
#define NPOLL 256        // grid size of persistent kernels

// contention-free tree grid barrier (256 blocks)
__device__ __forceinline__ void gbar(int* slots, int* gen, int target) {
    asm volatile("s_waitcnt vmcnt(0)" ::: "memory");
    __syncthreads();
    if (blockIdx.x == 0) {
        if (threadIdx.x == 0) stI(slots, target);
        if (threadIdx.x < NPOLL) {
            while (ldI(slots + threadIdx.x * SLOT_STRIDE) < target)
                __builtin_amdgcn_s_sleep(1);
        }
        __syncthreads();
        if (threadIdx.x == 0) stI(gen, target);
    } else {
        if (threadIdx.x == 0) {
            stI(slots + blockIdx.x * SLOT_STRIDE, target);
            while (ldI(gen) < target)
                __builtin_amdgcn_s_sleep(1);
        }
        __syncthreads();
    }
}

// MFMA batches: A from global (per-step state, L2), B from LDS (K-major:
// BL[chunk*16 + row], chunk advances 4 per kk step -> BL[kk*64])
__device__ __forceinline__ void mac8L(const unsigned short* A, const bf16x8* BL,
                                      f32x4& acc) {
    bf16x8 a[8];
#pragma unroll
    for (int kk = 0; kk < 8; ++kk) a[kk] = *(const bf16x8*)(A + kk * 32);
#pragma unroll
    for (int kk = 0; kk < 8; ++kk)
        acc = __builtin_amdgcn_mfma_f32_16x16x32_bf16(a[kk], BL[kk * 64], acc, 0, 0, 0);
}
__device__ __forceinline__ void mac4L(const unsigned short* A, const bf16x8* BL,
                                      f32x4& acc) {
    bf16x8 a[4];
#pragma unroll
    for (int kk = 0; kk < 4; ++kk) a[kk] = *(const bf16x8*)(A + kk * 32);
#pragma unroll
    for (int kk = 0; kk < 4; ++kk)
        acc = __builtin_amdgcn_mfma_f32_16x16x32_bf16(a[kk], BL[kk * 64], acc, 0, 0, 0);
}

// ---------- elementwise / conversion kernels ----------

__global__ void k_gather(const float* __restrict__ emb, const int* __restrict__ tok,
                         unsigned short* __restrict__ out, int L, int ldtok) {
    long total = (long)L * 64 * 128;
    for (long i = (long)blockIdx.x * blockDim.x + threadIdx.x; i < total;
         i += (long)gridDim.x * blockDim.x) {
        int  e4 = (int)(i & 127);
        long r  = i >> 7;
        int  t  = (int)(r >> 6), b = (int)(r & 63);
        int  tk = tok[b * ldtok + t];
        float4 v = *(const float4*)(emb + (long)tk * 512 + e4 * 4);
        ushort4 o; o.x = f2b(v.x); o.y = f2b(v.y); o.z = f2b(v.z); o.w = f2b(v.w);
        *(ushort4*)(out + r * 512 + e4 * 4) = o;
    }
}

__global__ void k_conv(const float* __restrict__ in, unsigned short* __restrict__ out,
                       long N_, int K_, int ldin, int col0, int ldout, int outcol0, int reorder) {
    long total = N_ * (K_ >> 2);
    int kq = K_ >> 2;
    for (long i = (long)blockIdx.x * blockDim.x + threadIdx.x; i < total;
         i += (long)gridDim.x * blockDim.x) {
        long n = i / kq;
        int  k4 = (int)(i - n * kq) * 4;
        long row = reorder ? (long)((n & 3) * 1024 + (n >> 2)) : n;
        float4 v = *(const float4*)(in + row * ldin + col0 + k4);
        ushort4 o; o.x = f2b(v.x); o.y = f2b(v.y); o.z = f2b(v.z); o.w = f2b(v.w);
        *(ushort4*)(out + n * ldout + outcol0 + k4) = o;
    }
}

__global__ void k_bias(const float* __restrict__ b1, const float* __restrict__ b2,
                       float* __restrict__ out) {
    int n = blockIdx.x * blockDim.x + threadIdx.x;
    if (n < 4096) {
        int row = (n & 3) * 1024 + (n >> 2);
        out[n] = b1[row] + b2[row];
    }
}

__global__ void k_zero0(float* __restrict__ out) {
    long total = 64L * 8000;
    for (long i = (long)blockIdx.x * blockDim.x + threadIdx.x; i < total;
         i += (long)gridDim.x * blockDim.x) {
        int b = (int)(i / 8000), q = (int)(i % 8000);
        float4 z = {0.f, 0.f, 0.f, 0.f};
        *(float4*)(out + (long)b * 1024000 + q * 4) = z;
    }
}

// ---------- big-GEMM (prep + fc), m97 structure ----------
template<int BM, int BN, int WGM, int WGN, int FM, int FN>
__device__ __forceinline__ void gemm_core(
    const unsigned short* __restrict__ A, int lda,
    const unsigned short* __restrict__ B, int ldb,
    long m0, long n0, int K,
    unsigned short* As, unsigned short* Bs,
    f32x4 (&acc)[FM][FN])
{
    const int tid  = threadIdx.x;
    const int lane = tid & 63;
    const int wave = tid >> 6;
    const int wm = wave / WGN;
    const int wn = wave % WGN;
    const int srow = lane >> 2;
    const int scol = (lane & 3) * 8;
    const int frow = lane & 15;
    const int fcol = (lane >> 4) * 8;

    for (int k0 = 0; k0 < K; k0 += 32) {
        __syncthreads();
        for (int c = wave; c < BM / 16; c += 4) {
            const unsigned short* g = A + (m0 + c * 16 + srow) * (long)lda + k0 + scol;
            GLD16(g, As + c * 512);
        }
        for (int c = wave; c < BN / 16; c += 4) {
            const unsigned short* g = B + (n0 + c * 16 + srow) * (long)ldb + k0 + scol;
            GLD16(g, Bs + c * 512);
        }
        __syncthreads();
        bf16x8 af[FM], bfr[FN];
#pragma unroll
        for (int m = 0; m < FM; ++m)
            af[m] = *(const bf16x8*)(As + ((wm * FM + m) * 16 + frow) * 32 + fcol);
#pragma unroll
        for (int n = 0; n < FN; ++n)
            bfr[n] = *(const bf16x8*)(Bs + ((wn * FN + n) * 16 + frow) * 32 + fcol);
#pragma unroll
        for (int m = 0; m < FM; ++m)
#pragma unroll
            for (int n = 0; n < FN; ++n)
                acc[m][n] = __builtin_amdgcn_mfma_f32_16x16x32_bf16(af[m], bfr[n], acc[m][n], 0, 0, 0);
    }
}

// MODE 0: f32 out. MODE 1: fc row-remap + XCD-grouped swizzled 1D grid.
// MODE 2: fp16 out.
template<int BM, int BN, int WGM, int WGN, int FM, int FN, int MODE>
__global__ __launch_bounds__(256) void k_gemm(
    const unsigned short* __restrict__ A, int lda,
    const unsigned short* __restrict__ B, int ldb,
    float* __restrict__ C, long ldc, const float* __restrict__ bias,
    int M, int N, int K, int Mreal)
{
    __shared__ __align__(16) unsigned short As[BM * 32];
    __shared__ __align__(16) unsigned short Bs[BN * 32];
    long m0, n0;
    if (MODE == 1) {
        int bid = blockIdx.x;
        int n = (bid & 7) * 32 + (bid >> 7);
        int m = (bid >> 3) & 15;
        if (n >= 250) return;
        m0 = (long)m * BM; n0 = (long)n * BN;
    } else {
        m0 = (long)blockIdx.y * BM; n0 = (long)blockIdx.x * BN;
    }
    f32x4 acc[FM][FN] = {};
    gemm_core<BM, BN, WGM, WGN, FM, FN>(A, lda, B, ldb, m0, n0, K, As, Bs, acc);

    const int lane = threadIdx.x & 63;
    const int wave = threadIdx.x >> 6;
    const int wm = wave / WGN, wn = wave % WGN;
#pragma unroll
    for (int n = 0; n < FN; ++n) {
        long col = n0 + wn * FN * 16 + n * 16 + (lane & 15);
        float bv = bias ? bias[col] : 0.0f;
#pragma unroll
        for (int m = 0; m < FM; ++m) {
            int rl = wm * FM * 16 + m * 16 + (lane >> 4) * 4;
#pragma unroll
            for (int q = 0; q < 4; ++q) {
                long r = m0 + rl + q;
                float val = acc[m][n][q] + bv;
                if (MODE == 0) {
                    C[r * ldc + col] = val;
                } else if (MODE == 2) {
                    ((_Float16*)C)[r * ldc + col] = (_Float16)val;
                } else {
                    if (r < Mreal) {
                        long orow = (r & 63) * 32 + (r >> 6) + 1;
                        C[orow * ldc + col] = val;
                    }
                }
            }
        }
    }
}

// ---------- persistent encoder: 256 blocks x 512 threads; W slice in LDS ----------
__global__ __launch_bounds__(512, 2) void k_enc(
    const unsigned short* __restrict__ W,    // weWhh 4096x1024 gate-interleaved
    const float* __restrict__ pre,           // [64][64][4096]
    unsigned short* __restrict__ hsl,        // 65 slots x [64][1024] (slot0 zeroed)
    unsigned short* __restrict__ enc_out,    // [b*64+t][1024]
    unsigned short* __restrict__ eoT,        // [b][h][t]
    unsigned short* __restrict__ hS0,        // dec h slot 0 (h_f)
    float* __restrict__ cspill,
    int* slots, int* gen)
{
    __shared__ __align__(16) unsigned short WL[16 * 1024];   // 32 KB, K-major [128][16][8]
    __shared__ float gs[64 * 16];
    const int blk = blockIdx.x, tid = threadIdx.x;
    const int lane = tid & 63, wave = tid >> 6;
    const int rt = wave >> 1, kh = wave & 1;
    const int n0 = blk * 16;
    const int grow = (rt * 16 + (lane >> 4) * 4) * 16 + (lane & 15);
    const int pb = tid >> 1, pjl = (tid & 1) * 2;    // active for tid<128
    const int jg = blk * 4 + pjl;
    // stage W slice (rows n0..n0+15), K-major
    for (int i = tid; i < 2048; i += 512) {
        int r = i & 15, k8 = i >> 4;
        ((bf16x8*)WL)[k8 * 16 + r] = *(const bf16x8*)(W + (long)(n0 + r) * 1024 + k8 * 8);
    }
    const bf16x8* BL = (const bf16x8*)WL + ((long)kh * 64 + (lane >> 4)) * 16 + (lane & 15);
    float c0 = 0.f, c1 = 0.f;
    float4 pr0 = {}, pr1 = {};
    if (tid < 128) {
        pr0 = *(const float4*)(pre + (long)pb * 4096 + n0 + pjl * 4);
        pr1 = *(const float4*)(pre + (long)pb * 4096 + n0 + pjl * 4 + 4);
    }
    __syncthreads();
    int bt = 0;
    for (int t = 0; t < 64; ++t) {
        const unsigned short* Ar = hsl + (long)t * 65536
            + (long)(rt * 16 + (lane & 15)) * 1024 + kh * 512 + (lane >> 4) * 8;
        f32x4 acc = {};
        mac8L(Ar,       BL,       acc);
        mac8L(Ar + 256, BL + 512, acc);
        if (kh == 0) {
#pragma unroll
            for (int q = 0; q < 4; ++q) gs[grow + q * 16] = acc[q];
        }
        __syncthreads();
        if (kh == 1) {
#pragma unroll
            for (int q = 0; q < 4; ++q) atomicAdd(&gs[grow + q * 16], acc[q]);
        }
        __syncthreads();
        if (tid < 128) {
            float4 gA = *(const float4*)(gs + pb * 16 + pjl * 4);
            float4 gB = *(const float4*)(gs + pb * 16 + pjl * 4 + 4);
            float h0v, h1v;
            {
                float gi = gA.x + pr0.x, gf = gA.y + pr0.y, gg = gA.z + pr0.z, go = gA.w + pr0.w;
                float i_ = 1.f / (1.f + __expf(-gi)), f_ = 1.f / (1.f + __expf(-gf));
                float g_ = tanhfast(gg), o_ = 1.f / (1.f + __expf(-go));
                c0 = f_ * c0 + i_ * g_; h0v = o_ * tanhfast(c0);
            }
            {
                float gi = gB.x + pr1.x, gf = gB.y + pr1.y, gg = gB.z + pr1.z, go = gB.w + pr1.w;
                float i_ = 1.f / (1.f + __expf(-gi)), f_ = 1.f / (1.f + __expf(-gf));
                float g_ = tanhfast(gg), o_ = 1.f / (1.f + __expf(-go));
                c1 = f_ * c1 + i_ * g_; h1v = o_ * tanhfast(c1);
            }
            unsigned short hb0 = f2b(h0v), hb1 = f2b(h1v);
            unsigned pk = (unsigned)hb0 | ((unsigned)hb1 << 16);
            stU((unsigned*)(hsl + (long)(t + 1) * 65536 + (long)pb * 1024 + jg), pk);
            *(unsigned*)(enc_out + ((long)pb * 64 + t) * 1024 + jg) = pk;
            eoT[((long)pb * 1024 + jg) * 64 + t]     = hb0;
            eoT[((long)pb * 1024 + jg + 1) * 64 + t] = hb1;
            if (t < 63) {
                pr0 = *(const float4*)(pre + (long)(t + 1) * 262144 + (long)pb * 4096 + n0 + pjl * 4);
                pr1 = *(const float4*)(pre + (long)(t + 1) * 262144 + (long)pb * 4096 + n0 + pjl * 4 + 4);
            } else {
                *(unsigned*)(hS0 + (long)pb * 1024 + jg) = pk;
                cspill[(long)pb * 1024 + jg]     = c0;
                cspill[(long)pb * 1024 + jg + 1] = c1;
            }
        }
        gbar(slots, gen, ++bt);
    }
}

// ---------- persistent decoder: Wc + Wh slices pinned in LDS ----------
__global__ __launch_bounds__(512, 1) void k_dec(
    const unsigned short* __restrict__ Wh,   // 1024x1024
    const unsigned short* __restrict__ Wc,   // 4096x2048 gate-interleaved
    const float* __restrict__ pre,           // [31][64][4096]
    const _Float16* __restrict__ proj16,     // [b*64+s][1024] fp16 (attn_b folded)
    const unsigned short* __restrict__ eoT,  // [b][h][t]
    const float* __restrict__ v,
    const float* __restrict__ cspill,
    unsigned short* __restrict__ hS,         // 32 slots x [64][1024] (slot0 = h_f)
    unsigned short* __restrict__ ctxS,       // 32 slots x [64][1024]
    float* __restrict__ qS,                  // 32 slots x [64][1024] f32
    unsigned short* __restrict__ fcin,       // (t*64+b) x 2048
    int* slots, int* gen)
{
    __shared__ __align__(16) unsigned short WcL[16 * 2048];  // 64 KB, K-major [256][16][8]
    __shared__ __align__(16) unsigned short WhL[16 * 1024];  // 32 KB, K-major [128][16][8]
    __shared__ float gs[64 * 16];
    __shared__ float qv[1024], vv[1024];
    __shared__ float sc[64], al[64];
    const int blk = blockIdx.x, tid = threadIdx.x;
    const int lane = tid & 63, wave = tid >> 6;
    const int rt = wave >> 1, kh = wave & 1;
    const int n0 = blk * 16;
    const int nq = blk >> 2, mt = blk & 3;
    const int grow = (rt * 16 + (lane >> 4) * 4) * 16 + (lane & 15);
    const int pb = tid >> 1, pjl = (tid & 1) * 2;
    const int jg = blk * 4 + pjl;
    // stage weight slices, K-major
    for (int i = tid; i < 4096; i += 512) {
        int r = i & 15, k8 = i >> 4;
        ((bf16x8*)WcL)[k8 * 16 + r] = *(const bf16x8*)(Wc + (long)(n0 + r) * 2048 + k8 * 8);
    }
    for (int i = tid; i < 2048; i += 512) {
        int r = i & 15, k8 = i >> 4;
        ((bf16x8*)WhL)[k8 * 16 + r] = *(const bf16x8*)(Wh + (long)(nq * 16 + r) * 1024 + k8 * 8);
    }
    const bf16x8* BLc = (const bf16x8*)WcL + ((long)kh * 128 + (lane >> 4)) * 16 + (lane & 15);
    const bf16x8* BLq = (const bf16x8*)WhL + ((long)wave * 16 + (lane >> 4)) * 16 + (lane & 15);
    if (tid < 256) {
        float4 v4 = *(const float4*)(v + tid * 4);
        *(float4*)(vv + tid * 4) = v4;
    }
    float c0 = 0.f, c1 = 0.f;
    if (tid < 128) {
        c0 = cspill[(long)pb * 1024 + jg];
        c1 = cspill[(long)pb * 1024 + jg + 1];
    }
    __syncthreads();
    int bt = 0;
    for (int t = 0; t < 31; ++t) {
        const unsigned short* hSt   = hS   + (long)t * 65536;
        const unsigned short* ctxSt = ctxS + (long)t * 65536;
        float4 pr0 = {}, pr1 = {};
        if (tid < 128) {
            pr0 = *(const float4*)(pre + (long)t * 262144 + (long)pb * 4096 + n0 + pjl * 4);
            pr1 = *(const float4*)(pre + (long)t * 262144 + (long)pb * 4096 + n0 + pjl * 4 + 4);
        }
        // ---- phase 1: q = h_t @ Wh^T (64 n-tiles x 4 m-tiles; 8-way K split)
        {
            if (tid < 256) gs[tid] = 0.f;
            __syncthreads();
            const unsigned short* Ar = hSt + (long)(mt * 16 + (lane & 15)) * 1024
                                           + wave * 128 + (lane >> 4) * 8;
            f32x4 qa = {};
            mac4L(Ar, BLq, qa);
#pragma unroll
            for (int q = 0; q < 4; ++q)
                atomicAdd(&gs[((lane >> 4) * 4 + q) * 16 + (lane & 15)], qa[q]);
            __syncthreads();
            if (tid < 256)
                stF(qS + (long)t * 65536 + (long)(mt * 16 + (tid >> 4)) * 1024
                        + nq * 16 + (tid & 15), gs[tid]);
        }
        gbar(slots, gen, ++bt);
        // ---- phase 2: attention (blocks 0..63: b = blk; 512 threads)
        if (blk < 64) {
            const int b = blk;
            if (tid < 256)
                *(float4*)(qv + tid * 4) =
                    *(const float4*)(qS + (long)t * 65536 + (long)b * 1024 + tid * 4);
            __syncthreads();
            int s = tid >> 3, part = tid & 7;
            const h16x8* pp = (const h16x8*)(proj16 + ((long)b * 64 + s) * 1024 + part * 128);
            float a_ = 0.f;
#pragma unroll 4
            for (int d = 0; d < 16; ++d) {
                h16x8 pv = pp[d];
                int h = part * 128 + d * 8;
#pragma unroll
                for (int j = 0; j < 8; ++j)
                    a_ += vv[h + j] * tanhfast(qv[h + j] + (float)pv[j]);
            }
            a_ += __shfl_xor(a_, 1);
            a_ += __shfl_xor(a_, 2);
            a_ += __shfl_xor(a_, 4);
            if (part == 0) sc[s] = a_;
            __syncthreads();
            if (tid < 64) {
                float x = sc[tid], mx = x;
                for (int o = 32; o; o >>= 1) mx = fmaxf(mx, __shfl_xor(mx, o));
                float e = __expf(x - mx), su = e;
                for (int o = 32; o; o >>= 1) su += __shfl_xor(su, o);
                al[tid] = e / su;
            }
            __syncthreads();
            int h0 = tid * 2;
            float cacc[2];
#pragma unroll
            for (int r = 0; r < 2; ++r) {
                const bf16x8* ep = (const bf16x8*)(eoT + ((long)b * 1024 + h0 + r) * 64);
                float s_ = 0.f;
#pragma unroll
                for (int c8 = 0; c8 < 8; ++c8) {
                    bf16x8 v8 = ep[c8];
#pragma unroll
                    for (int jj = 0; jj < 8; ++jj)
                        s_ += al[c8 * 8 + jj] * (float)v8[jj];
                }
                cacc[r] = s_;
            }
            unsigned pk0 = (unsigned)f2b(cacc[0]) | ((unsigned)f2b(cacc[1]) << 16);
            stU((unsigned*)(ctxS + (long)t * 65536 + (long)b * 1024 + h0), pk0);
            *(unsigned*)(fcin + ((long)t * 64 + b) * 2048 + 1024 + h0) = pk0;
        }
        gbar(slots, gen, ++bt);
        // ---- phase 3: gates (256 blocks x 16 cols; wave = (rt, kh); kh0=h, kh1=ctx)
        {
            const unsigned short* Asrc = (kh ? ctxSt : hSt)
                + (long)(rt * 16 + (lane & 15)) * 1024 + (lane >> 4) * 8;
            f32x4 acc = {};
            mac8L(Asrc,       BLc,        acc);
            mac8L(Asrc + 256, BLc + 512,  acc);
            mac8L(Asrc + 512, BLc + 1024, acc);
            mac8L(Asrc + 768, BLc + 1536, acc);
            if (kh == 0) {
#pragma unroll
                for (int q = 0; q < 4; ++q) gs[grow + q * 16] = acc[q];
            }
            __syncthreads();
            if (kh == 1) {
#pragma unroll
                for (int q = 0; q < 4; ++q) atomicAdd(&gs[grow + q * 16], acc[q]);
            }
            __syncthreads();
            if (tid < 128) {
                float4 gA = *(const float4*)(gs + pb * 16 + pjl * 4);
                float4 gB = *(const float4*)(gs + pb * 16 + pjl * 4 + 4);
                float h0v, h1v;
                {
                    float gi = gA.x + pr0.x, gf = gA.y + pr0.y, gg = gA.z + pr0.z, go = gA.w + pr0.w;
                    float i_ = 1.f / (1.f + __expf(-gi)), f_ = 1.f / (1.f + __expf(-gf));
                    float g_ = tanhfast(gg), o_ = 1.f / (1.f + __expf(-go));
                    c0 = f_ * c0 + i_ * g_; h0v = o_ * tanhfast(c0);
                }
                {
                    float gi = gB.x + pr1.x, gf = gB.y + pr1.y, gg = gB.z + pr1.z, go = gB.w + pr1.w;
                    float i_ = 1.f / (1.f + __expf(-gi)), f_ = 1.f / (1.f + __expf(-gf));
                    float g_ = tanhfast(gg), o_ = 1.f / (1.f + __expf(-go));
                    c1 = f_ * c1 + i_ * g_; h1v = o_ * tanhfast(c1);
                }
                unsigned pk = (unsigned)f2b(h0v) | ((unsigned)f2b(h1v) << 16);
                stU((unsigned*)(hS + (long)(t + 1) * 65536 + (long)pb * 1024 + jg), pk);
                *(unsigned*)(fcin + ((long)t * 64 + pb) * 2048 + jg) = pk;
            }
        }
        gbar(slots, gen, ++bt);
    }
}

// ---------- launch ----------
extern "C" void kernel_launch(void* const* d_in, const int* in_sizes, int n_in,
                              void* d_out, int out_size, void* d_ws, size_t ws_size,
                              hipStream_t stream) {
    const int*   src     = (const int*)d_in[0];
    const int*   tgt     = (const int*)d_in[1];
    const float* enc_emb = (const float*)d_in[2];
    const float* dec_emb = (const float*)d_in[3];
    const float* enc_Wih = (const float*)d_in[4];
    const float* enc_Whh = (const float*)d_in[5];
    const float* enc_bih = (const float*)d_in[6];
    const float* enc_bhh = (const float*)d_in[7];
    const float* dec_Wih = (const float*)d_in[8];
    const float* dec_Whh = (const float*)d_in[9];
    const float* dec_bih = (const float*)d_in[10];
    const float* dec_bhh = (const float*)d_in[11];
    const float* attn_W  = (const float*)d_in[12];
    const float* attn_b  = (const float*)d_in[13];
    const float* vvec    = (const float*)d_in[14];
    const float* fc_W    = (const float*)d_in[15];
    const float* fc_b    = (const float*)d_in[16];
    float* out = (float*)d_out;

    char* ws = (char*)d_ws;
    size_t off = 0;
    auto alloc = [&](size_t bytes) -> char* {
        off = (off + 255) & ~(size_t)255;
        char* p = ws + off; off += bytes; return p;
    };
    unsigned short* wX      = (unsigned short*)alloc(4096UL * 512 * 2);
    unsigned short* weWih   = (unsigned short*)alloc(4096UL * 512 * 2);
    unsigned short* weWhh   = (unsigned short*)alloc(4096UL * 1024 * 2);
    float*          ebias   = (float*)alloc(4096UL * 4);
    float*          pre_enc = (float*)alloc(4096UL * 4096 * 4);
    unsigned short* enc_out = (unsigned short*)alloc(4096UL * 1024 * 2);
    unsigned short* eoT     = (unsigned short*)alloc(64UL * 1024 * 64 * 2);
    unsigned short* wWe     = (unsigned short*)alloc(1024UL * 1024 * 2);
    unsigned short* wWh     = (unsigned short*)alloc(1024UL * 1024 * 2);
    _Float16*       proj16  = (_Float16*)alloc(4096UL * 1024 * 2);
    float*          cbuf    = (float*)alloc(64UL * 1024 * 4);
    unsigned short* demb    = (unsigned short*)alloc(2048UL * 512 * 2);
    unsigned short* wDemb   = (unsigned short*)alloc(4096UL * 512 * 2);
    unsigned short* wCat    = (unsigned short*)alloc(4096UL * 2048 * 2);
    float*          dbias   = (float*)alloc(4096UL * 4);
    float*          pre_dec = (float*)alloc(2048UL * 4096 * 4);
    unsigned short* fcin    = (unsigned short*)alloc(2048UL * 2048 * 2);
    unsigned short* wFc     = (unsigned short*)alloc(32000UL * 2048 * 2);
    unsigned short* hslE    = (unsigned short*)alloc(65UL * 65536 * 2);
    unsigned short* hS      = (unsigned short*)alloc(32UL * 65536 * 2);
    unsigned short* ctxS    = (unsigned short*)alloc(32UL * 65536 * 2);
    float*          qS      = (float*)alloc(32UL * 65536 * 4);
    int*            bar     = (int*)alloc(65536);
    (void)ws_size; (void)in_sizes; (void)n_in; (void)out_size;

    int* slotsE = bar;            // 256 slots x 64B
    int* genE   = bar + 4096;
    int* slotsD = bar + 8192;
    int* genD   = bar + 12288;

    hipMemsetAsync(bar, 0, 65536, stream);
    hipMemsetAsync(hslE, 0, 65536UL * 2, stream);   // enc h slot 0 = zeros
    k_zero0<<<512, 256, 0, stream>>>(out);

    k_gather<<<2048, 256, 0, stream>>>(enc_emb, src, wX, 64, 64);
    k_gather<<<1024, 256, 0, stream>>>(dec_emb, tgt, demb, 31, 32);
    k_conv<<<2048, 256, 0, stream>>>(enc_Wih, weWih, 4096, 512, 512, 0, 512, 0, 1);
    k_conv<<<2048, 256, 0, stream>>>(enc_Whh, weWhh, 4096, 1024, 1024, 0, 1024, 0, 1);
    k_conv<<<2048, 256, 0, stream>>>(dec_Wih, wDemb, 4096, 512, 1536, 0, 512, 0, 1);
    k_conv<<<2048, 256, 0, stream>>>(dec_Whh, wCat, 4096, 1024, 1024, 0, 2048, 0, 1);
    k_conv<<<2048, 256, 0, stream>>>(dec_Wih, wCat, 4096, 1024, 1536, 512, 2048, 1024, 1);
    k_conv<<<2048, 256, 0, stream>>>(attn_W, wWh, 1024, 1024, 2048, 0, 1024, 0, 0);
    k_conv<<<2048, 256, 0, stream>>>(attn_W, wWe, 1024, 1024, 2048, 1024, 1024, 0, 0);
    k_conv<<<4096, 256, 0, stream>>>(fc_W, wFc, 32000, 2048, 2048, 0, 2048, 0, 0);
    k_bias<<<16, 256, 0, stream>>>(enc_bih, enc_bhh, ebias);
    k_bias<<<16, 256, 0, stream>>>(dec_bih, dec_bhh, dbias);

    // pre-gates GEMMs
    k_gemm<128,128,2,2,4,4,0><<<dim3(32, 32), 256, 0, stream>>>(
        wX, 512, weWih, 512, pre_enc, 4096, ebias, 4096, 4096, 512, 4096);
    k_gemm<128,128,2,2,4,4,0><<<dim3(32, 16), 256, 0, stream>>>(
        demb, 512, wDemb, 512, pre_dec, 4096, dbias, 2048, 4096, 512, 2048);

    // persistent encoder (256 blocks x 512 threads)
    k_enc<<<256, 512, 0, stream>>>(weWhh, pre_enc, hslE, enc_out, eoT,
                                   hS, cbuf, slotsE, genE);

    // enc_proj (+attn_b) -> fp16
    k_gemm<128,128,2,2,4,4,2><<<dim3(8, 32), 256, 0, stream>>>(
        enc_out, 1024, wWe, 1024, (float*)proj16, 1024, attn_b, 4096, 1024, 1024, 4096);

    // persistent decoder (256 blocks x 512 threads, weights in LDS)
    k_dec<<<256, 512, 0, stream>>>(wWh, wCat, pre_dec, proj16, eoT, vvec, cbuf,
                                   hS, ctxS, qS, fcin, slotsD, genD);

    // batched fc GEMM -> out (XCD-grouped swizzle; rows b*32 zeroed by k_zero0)
    k_gemm<128,128,2,2,4,4,1><<<dim3(4096), 256, 0, stream>>>(
        fcin, 2048, wFc, 2048, out, 32000, fc_b, 2048, 32000, 2048, 1984);
}